// Round 2
// baseline (6702.163 us; speedup 1.0000x reference)
//
#include <hip/hip_runtime.h>
#include <cstddef>
#include <cstdint>

#define BSZ 512
#define SEQ 100
#define DI 1024

__device__ __forceinline__ float sigmoidf_(float v){ return 1.f/(1.f + __expf(-v)); }
__device__ __forceinline__ float siluf_(float v){ return v * sigmoidf_(v); }
__device__ __forceinline__ float softplusf_(float v){ return (v > 20.f) ? v : log1pf(__expf(v)); }

// ---------------------------------------------------------------------------
// Front-end: id-embed (2 LayerNorms) -> comb[..., 0:256]
//            conv1(22->128,k3,p1)+relu -> conv2(128->256,k3,p1)+relu -> comb[..., 256:512]
// One block per batch element (relative to chunk base).
// ---------------------------------------------------------------------------
__global__ __launch_bounds__(256) void frontend_kernel(
    const float* __restrict__ x,                     // (Bc, 100, 23) chunk base
    const float* __restrict__ fe_w, const float* __restrict__ fe_b,
    const float* __restrict__ g1, const float* __restrict__ b1,
    const float* __restrict__ g2, const float* __restrict__ b2,
    const float* __restrict__ c1w, const float* __restrict__ c1b,   // (128,22,3),(128)
    const float* __restrict__ c2w, const float* __restrict__ c2b,   // (256,128,3),(256)
    float* __restrict__ comb)                        // (Bc, 100, 512)
{
    const int b = blockIdx.x;
    const int t = threadIdx.x;
    const int wv = t >> 6, lane = t & 63;

    // ---- phase A: id embedding ----
    float few[4], feb[4], lg1[4], lb1[4], lg2[4], lb2[4];
    #pragma unroll
    for (int q = 0; q < 4; ++q){
        int j = lane + 64*q;
        few[q] = fe_w[j]; feb[q] = fe_b[j];
        lg1[q] = g1[j];  lb1[q] = b1[j];
        lg2[q] = g2[j];  lb2[q] = b2[j];
    }
    for (int l = wv; l < SEQ; l += 4){
        float m = fabsf(x[(size_t)(b*SEQ + l)*23]);
        float e[4];
        float s1 = 0.f, s2 = 0.f;
        #pragma unroll
        for (int q = 0; q < 4; ++q){ e[q] = m*few[q] + feb[q]; s1 += e[q]; s2 += e[q]*e[q]; }
        #pragma unroll
        for (int off = 32; off > 0; off >>= 1){ s1 += __shfl_xor(s1, off); s2 += __shfl_xor(s2, off); }
        float mean = s1 * (1.f/256.f);
        float rstd = rsqrtf(s2*(1.f/256.f) - mean*mean + 1e-5f);
        s1 = 0.f; s2 = 0.f;
        #pragma unroll
        for (int q = 0; q < 4; ++q){
            e[q] = fmaxf((e[q]-mean)*rstd*lg1[q] + lb1[q], 0.f);
            s1 += e[q]; s2 += e[q]*e[q];
        }
        #pragma unroll
        for (int off = 32; off > 0; off >>= 1){ s1 += __shfl_xor(s1, off); s2 += __shfl_xor(s2, off); }
        mean = s1 * (1.f/256.f);
        rstd = rsqrtf(s2*(1.f/256.f) - mean*mean + 1e-5f);
        #pragma unroll
        for (int q = 0; q < 4; ++q){
            float v = fmaxf((e[q]-mean)*rstd*lg2[q] + lb2[q], 0.f);
            comb[(size_t)(b*SEQ + l)*512 + lane + 64*q] = v;
        }
    }

    // ---- phase B: conv stack ----
    __shared__ float sdata[22*104];   // data with +1 zero-pad offset in l
    __shared__ float sf1[128*104];    // f1 with +1 zero-pad offset in l
    for (int idx = t; idx < 22*SEQ; idx += 256){
        int c = idx / SEQ, l = idx - c*SEQ;
        sdata[c*104 + l + 1] = x[(size_t)(b*SEQ + l)*23 + 1 + c];
    }
    if (t < 22){ sdata[t*104 + 0] = 0.f; sdata[t*104 + 101] = 0.f; }
    __syncthreads();

    {   // f1: 128 channels x 100, each thread does one channel-half
        int o = t >> 1, half = t & 1;
        int lbase = half * 50;
        for (int lc = 0; lc < 50; lc += 10){
            int lofs = lbase + lc;
            float a[10];
            float bia = c1b[o];
            #pragma unroll
            for (int i = 0; i < 10; ++i) a[i] = bia;
            for (int c = 0; c < 22; ++c){
                float w0 = c1w[(o*22 + c)*3 + 0];
                float w1 = c1w[(o*22 + c)*3 + 1];
                float w2 = c1w[(o*22 + c)*3 + 2];
                float s0 = sdata[c*104 + lofs];
                float sc = sdata[c*104 + lofs + 1];
                #pragma unroll
                for (int i = 0; i < 10; ++i){
                    float sn = sdata[c*104 + lofs + i + 2];
                    a[i] += w0*s0 + w1*sc + w2*sn;
                    s0 = sc; sc = sn;
                }
            }
            #pragma unroll
            for (int i = 0; i < 10; ++i) sf1[o*104 + lofs + i + 1] = fmaxf(a[i], 0.f);
        }
        if (t < 128){ sf1[t*104 + 0] = 0.f; sf1[t*104 + 101] = 0.f; }
    }
    __syncthreads();

    {   // f2: 256 channels x 100; thread t = output channel
        int o = t;
        for (int lc = 0; lc < SEQ; lc += 20){
            float a[20];
            float bia = c2b[o];
            #pragma unroll
            for (int i = 0; i < 20; ++i) a[i] = bia;
            for (int c = 0; c < 128; ++c){
                float w0 = c2w[(o*128 + c)*3 + 0];
                float w1 = c2w[(o*128 + c)*3 + 1];
                float w2 = c2w[(o*128 + c)*3 + 2];
                float s0 = sf1[c*104 + lc];
                float sc = sf1[c*104 + lc + 1];
                #pragma unroll
                for (int i = 0; i < 20; ++i){
                    float sn = sf1[c*104 + lc + i + 2];
                    a[i] += w0*s0 + w1*sc + w2*sn;
                    s0 = sc; sc = sn;
                }
            }
            #pragma unroll
            for (int i = 0; i < 20; ++i)
                comb[(size_t)(b*SEQ + lc + i)*512 + 256 + o] = fmaxf(a[i], 0.f);
        }
    }
}

// ---------------------------------------------------------------------------
// Generic fp32 GEMM: C[m,n] (+)= sum_k A[m,k] * W[n,k]
// A: (M, K) row stride lda; W: (N, K) row-major; C: row stride ldc.
// 64x64 tile, BK=16, 4x4 per thread, 256 threads. M%64==0, K%16==0; N ragged ok.
// ---------------------------------------------------------------------------
__global__ __launch_bounds__(256) void gemm64_kernel(
    const float* __restrict__ A, int lda,
    const float* __restrict__ W, int K, int N,
    float* __restrict__ C, int ldc, int accumulate)
{
    __shared__ float As[16][68];
    __shared__ float Ws[16][68];
    const int t = threadIdx.x;
    const int m0 = blockIdx.x * 64, n0 = blockIdx.y * 64;
    const int tx = t & 15, ty = t >> 4;
    const int lr = t >> 2;           // 0..63 tile row
    const int lk = (t & 3) * 4;      // 0,4,8,12
    const float* Aptr = A + (size_t)(m0 + lr)*lda + lk;
    const float* Wptr = W + (size_t)(n0 + lr)*K + lk;
    const bool wvalid = (n0 + lr) < N;
    float acc[4][4] = {};
    for (int k0 = 0; k0 < K; k0 += 16){
        float4 av = *(const float4*)(Aptr + k0);
        float4 wv = wvalid ? *(const float4*)(Wptr + k0) : make_float4(0.f,0.f,0.f,0.f);
        __syncthreads();
        As[lk+0][lr] = av.x; As[lk+1][lr] = av.y; As[lk+2][lr] = av.z; As[lk+3][lr] = av.w;
        Ws[lk+0][lr] = wv.x; Ws[lk+1][lr] = wv.y; Ws[lk+2][lr] = wv.z; Ws[lk+3][lr] = wv.w;
        __syncthreads();
        #pragma unroll
        for (int k = 0; k < 16; ++k){
            float4 a4 = *(const float4*)&As[k][ty*4];
            float4 w4 = *(const float4*)&Ws[k][tx*4];
            float av4[4] = {a4.x, a4.y, a4.z, a4.w};
            float wv4[4] = {w4.x, w4.y, w4.z, w4.w};
            #pragma unroll
            for (int i = 0; i < 4; ++i)
                #pragma unroll
                for (int j = 0; j < 4; ++j)
                    acc[i][j] += av4[i]*wv4[j];
        }
    }
    #pragma unroll
    for (int i = 0; i < 4; ++i){
        size_t row = (size_t)(m0 + ty*4 + i)*ldc;
        #pragma unroll
        for (int j = 0; j < 4; ++j){
            int n = n0 + tx*4 + j;
            if (n < N){
                float v = acc[i][j];
                if (accumulate) v += C[row + n];
                C[row + n] = v;
            }
        }
    }
}

// ---------------------------------------------------------------------------
// Depthwise causal conv (kernel DC) + bias + silu, in place on the x-half of xz.
// REV=false: out[l] = sum_k x[l-(DC-1)+k] * w[k]   (causal)
// REV=true : out[l] = sum_k x[l+(DC-1)-k] * w[k]   (anti-causal = reversed causal)
// One thread per (b, d) within the chunk; rolling register window -> in-place safe.
// ---------------------------------------------------------------------------
template<int DC, bool REV>
__global__ __launch_bounds__(256) void conv_silu_kernel(
    float* __restrict__ xz, const float* __restrict__ cw, const float* __restrict__ cb)
{
    const int gid = blockIdx.x*256 + threadIdx.x;   // Bc*DI threads
    const int b = gid >> 10, d = gid & 1023;
    float w[DC];
    #pragma unroll
    for (int k = 0; k < DC; ++k) w[k] = cw[d*DC + k];
    const float bias = cb[d];
    float hist[DC-1];
    #pragma unroll
    for (int k = 0; k < DC-1; ++k) hist[k] = 0.f;
    float* base = xz + (size_t)b*SEQ*2048 + d;
    for (int tt = 0; tt < SEQ; ++tt){
        const int l = REV ? (SEQ-1-tt) : tt;
        float cur = base[(size_t)l*2048];
        float a = bias + w[DC-1]*cur;
        #pragma unroll
        for (int j = 1; j < DC; ++j) a += w[DC-1-j]*hist[j-1];
        #pragma unroll
        for (int j = DC-2; j >= 1; --j) hist[j] = hist[j-1];
        hist[0] = cur;
        base[(size_t)l*2048] = siluf_(a);
    }
}

// ---------------------------------------------------------------------------
// Selective scan, fused with dt projection (softplus(xdb[:,:32] @ dt_w^T + dt_b)),
// + x*D skip, * silu(z), writes y in place into the x-half of xz.
// One thread per (b, d); h[DS] state in registers; xdb row broadcast via LDS.
// ---------------------------------------------------------------------------
template<int DS, bool REV>
__global__ __launch_bounds__(256) void scan_kernel(
    float* __restrict__ xz,              // (Bc*L, 2048): x in [0,1024), z in [1024,2048)
    const float* __restrict__ xdb,       // (Bc*L, 64): [0:32]=dt_in, [32:32+DS]=B, [32+DS:32+2DS]=C
    const float* __restrict__ dt_w,      // (1024, 32)
    const float* __restrict__ dt_b,      // (1024)
    const float* __restrict__ Alog,      // (1024, DS)
    const float* __restrict__ Dp)        // (1024)
{
    const int b = blockIdx.x >> 2;
    const int d = ((blockIdx.x & 3) << 8) + threadIdx.x;
    float w[32];
    #pragma unroll
    for (int r = 0; r < 32; ++r) w[r] = dt_w[d*32 + r];
    const float dtb = dt_b[d];
    const float Dd = Dp[d];
    float Av[DS], h[DS];
    #pragma unroll
    for (int s = 0; s < DS; ++s){ Av[s] = -__expf(Alog[d*DS + s]); h[s] = 0.f; }
    __shared__ float sx[64];
    float* xbase = xz + (size_t)b*SEQ*2048;
    const float* xdbase = xdb + (size_t)b*SEQ*64;
    for (int tt = 0; tt < SEQ; ++tt){
        const int l = REV ? (SEQ-1-tt) : tt;
        __syncthreads();
        if (threadIdx.x < 32 + 2*DS) sx[threadIdx.x] = xdbase[l*64 + threadIdx.x];
        __syncthreads();
        float dacc = dtb;
        #pragma unroll
        for (int r = 0; r < 32; ++r) dacc += w[r]*sx[r];
        const float dtv = softplusf_(dacc);
        const float xv = xbase[(size_t)l*2048 + d];
        const float zv = xbase[(size_t)l*2048 + 1024 + d];
        const float dtx = dtv * xv;
        float yv = 0.f;
        #pragma unroll
        for (int s = 0; s < DS; ++s){
            h[s] = __expf(dtv*Av[s])*h[s] + dtx*sx[32+s];
            yv += h[s]*sx[32+DS+s];
        }
        yv += xv*Dd;
        yv *= siluf_(zv);
        xbase[(size_t)l*2048 + d] = yv;
    }
}

// ---------------------------------------------------------------------------
// Head: max-pool over L, LayerNorm(512), fc1(512->128)+relu, fc2(128->4)
// ---------------------------------------------------------------------------
__global__ __launch_bounds__(256) void head_kernel(
    const float* __restrict__ acc,   // (Bc, L, 512)
    const float* __restrict__ ng, const float* __restrict__ nb,
    const float* __restrict__ w1, const float* __restrict__ b1,   // (128,512),(128)
    const float* __restrict__ w2, const float* __restrict__ b2,   // (4,128),(4)
    float* __restrict__ out)         // (Bc, 4) chunk base
{
    const int b = blockIdx.x, t = threadIdx.x;
    __shared__ float sp[512];
    __shared__ float sh[128];
    __shared__ float red1[4], red2[4];
    const float* base = acc + (size_t)b*SEQ*512;
    for (int o = t; o < 512; o += 256){
        float m = -3.4e38f;
        for (int l = 0; l < SEQ; ++l) m = fmaxf(m, base[(size_t)l*512 + o]);
        sp[o] = m;
    }
    __syncthreads();
    float s1 = 0.f, s2 = 0.f;
    for (int o = t; o < 512; o += 256){ float v = sp[o]; s1 += v; s2 += v*v; }
    #pragma unroll
    for (int off = 32; off > 0; off >>= 1){ s1 += __shfl_xor(s1, off); s2 += __shfl_xor(s2, off); }
    const int wv = t >> 6, lane = t & 63;
    if (lane == 0){ red1[wv] = s1; red2[wv] = s2; }
    __syncthreads();
    if (t == 0){
        float a = 0.f, c = 0.f;
        for (int i = 0; i < 4; ++i){ a += red1[i]; c += red2[i]; }
        float mean = a * (1.f/512.f);
        float var = c * (1.f/512.f) - mean*mean;
        red1[0] = mean; red2[0] = rsqrtf(var + 1e-5f);
    }
    __syncthreads();
    const float mean = red1[0], rstd = red2[0];
    for (int o = t; o < 512; o += 256) sp[o] = (sp[o]-mean)*rstd*ng[o] + nb[o];
    __syncthreads();
    if (t < 128){
        float a = b1[t];
        for (int o = 0; o < 512; ++o) a += sp[o]*w1[t*512 + o];
        sh[t] = fmaxf(a, 0.f);
    }
    __syncthreads();
    if (t < 4){
        float a = b2[t];
        for (int j = 0; j < 128; ++j) a += sh[j]*w2[t*128 + j];
        out[b*4 + t] = a;
    }
}

// ---------------------------------------------------------------------------
extern "C" void kernel_launch(void* const* d_in, const int* in_sizes, int n_in,
                              void* d_out, int out_size, void* d_ws, size_t ws_size,
                              hipStream_t stream)
{
    (void)in_sizes; (void)n_in; (void)out_size;
    const float* x        = (const float*)d_in[0];
    const float* fe_w     = (const float*)d_in[1];
    const float* fe_b     = (const float*)d_in[2];
    const float* fe_ln_g  = (const float*)d_in[3];
    const float* fe_ln_b  = (const float*)d_in[4];
    const float* emb_ln_g = (const float*)d_in[5];
    const float* emb_ln_b = (const float*)d_in[6];
    const float* conv1_w  = (const float*)d_in[7];
    const float* conv1_b  = (const float*)d_in[8];
    const float* conv2_w  = (const float*)d_in[9];
    const float* conv2_b  = (const float*)d_in[10];
    const float* mf_in_w  = (const float*)d_in[11];
    const float* mf_conv_w= (const float*)d_in[12];
    const float* mf_conv_b= (const float*)d_in[13];
    const float* mf_xproj = (const float*)d_in[14];
    const float* mf_dt_w  = (const float*)d_in[15];
    const float* mf_dt_b  = (const float*)d_in[16];
    const float* mf_Alog  = (const float*)d_in[17];
    const float* mf_D     = (const float*)d_in[18];
    const float* mf_out_w = (const float*)d_in[19];
    const float* mb_in_w  = (const float*)d_in[20];
    const float* mb_conv_w= (const float*)d_in[21];
    const float* mb_conv_b= (const float*)d_in[22];
    const float* mb_xproj = (const float*)d_in[23];
    const float* mb_dt_w  = (const float*)d_in[24];
    const float* mb_dt_b  = (const float*)d_in[25];
    const float* mb_Alog  = (const float*)d_in[26];
    const float* mb_D     = (const float*)d_in[27];
    const float* mb_out_w = (const float*)d_in[28];
    const float* norm_g   = (const float*)d_in[29];
    const float* norm_b   = (const float*)d_in[30];
    const float* fc1_w    = (const float*)d_in[31];
    const float* fc1_b    = (const float*)d_in[32];
    const float* fc2_w    = (const float*)d_in[33];
    const float* fc2_b    = (const float*)d_in[34];
    float* out = (float*)d_out;

    // ---- workspace-adaptive batch chunking ----
    // per-batch footprint (floats): comb 100*512 + xz 100*2048 + xdb 100*64 + acc 100*512
    const size_t per_b = (size_t)SEQ * (512 + 2048 + 64 + 512);   // 313,600 floats = 1.2 MB
    const size_t budget = ws_size / sizeof(float);
    int Bc = BSZ;
    while (Bc > 16 && (size_t)Bc * per_b > budget) Bc >>= 1;

    float* comb = (float*)d_ws;                       // Bc*100*512
    float* xz   = comb + (size_t)Bc*SEQ*512;          // Bc*100*2048
    float* xdb  = xz   + (size_t)Bc*SEQ*2048;         // Bc*100*64
    float* accb = xdb  + (size_t)Bc*SEQ*64;           // Bc*100*512

    const int nch = BSZ / Bc;
    const int M = Bc * SEQ;                           // multiple of 64 for Bc>=16

    for (int c = 0; c < nch; ++c){
        const size_t b0 = (size_t)c * Bc;

        frontend_kernel<<<Bc, 256, 0, stream>>>(x + b0*SEQ*23, fe_w, fe_b,
            fe_ln_g, fe_ln_b, emb_ln_g, emb_ln_b, conv1_w, conv1_b, conv2_w, conv2_b, comb);

        // ---- forward mamba (d_state=16, d_conv=4) ----
        gemm64_kernel<<<dim3(M/64, 32), 256, 0, stream>>>(comb, 512, mf_in_w, 512, 2048, xz, 2048, 0);
        conv_silu_kernel<4, false><<<Bc*DI/256, 256, 0, stream>>>(xz, mf_conv_w, mf_conv_b);
        gemm64_kernel<<<dim3(M/64, 1), 256, 0, stream>>>(xz, 2048, mf_xproj, 1024, 64, xdb, 64, 0);
        scan_kernel<16, false><<<Bc*4, 256, 0, stream>>>(xz, xdb, mf_dt_w, mf_dt_b, mf_Alog, mf_D);
        gemm64_kernel<<<dim3(M/64, 8), 256, 0, stream>>>(xz, 2048, mf_out_w, 1024, 512, accb, 512, 0);

        // ---- backward mamba (d_state=8, d_conv=2), time-reversed in place ----
        gemm64_kernel<<<dim3(M/64, 32), 256, 0, stream>>>(comb, 512, mb_in_w, 512, 2048, xz, 2048, 0);
        conv_silu_kernel<2, true><<<Bc*DI/256, 256, 0, stream>>>(xz, mb_conv_w, mb_conv_b);
        gemm64_kernel<<<dim3(M/64, 1), 256, 0, stream>>>(xz, 2048, mb_xproj, 1024, 48, xdb, 64, 0);
        scan_kernel<8, true><<<Bc*4, 256, 0, stream>>>(xz, xdb, mb_dt_w, mb_dt_b, mb_Alog, mb_D);
        gemm64_kernel<<<dim3(M/64, 8), 256, 0, stream>>>(xz, 2048, mb_out_w, 1024, 512, accb, 512, 1);

        head_kernel<<<Bc, 256, 0, stream>>>(accb, norm_g, norm_b, fc1_w, fc1_b, fc2_w, fc2_b,
                                            out + b0*4);
    }
}

// Round 3
// 3368.930 us; speedup vs baseline: 1.9894x; 1.9894x over previous
//
#include <hip/hip_runtime.h>
#include <cstddef>
#include <cstdint>

#define BSZ 512
#define SEQ 100
#define DI 1024

typedef __bf16 bf16_t;
typedef __attribute__((ext_vector_type(8))) __bf16 bf16x8;
typedef __attribute__((ext_vector_type(4))) float f32x4;

__device__ __forceinline__ float sigmoidf_(float v){ return 1.f/(1.f + __expf(-v)); }
__device__ __forceinline__ float siluf_(float v){ return v * sigmoidf_(v); }
__device__ __forceinline__ float softplusf_(float v){ return (v > 20.f) ? v : log1pf(__expf(v)); }

// ---------------------------------------------------------------------------
// fp32 -> bf16 converter (weights), once per call
// ---------------------------------------------------------------------------
__global__ __launch_bounds__(256) void cvt_bf16_kernel(
    const float* __restrict__ src, bf16_t* __restrict__ dst, int n)
{
    int i = blockIdx.x*256 + threadIdx.x;
    if (i < n) dst[i] = (bf16_t)src[i];
}

// ---------------------------------------------------------------------------
// Front-end: id-embed (2 LayerNorms) -> comb[..., 0:256] (bf16)
//            conv1(22->128,k3,p1)+relu -> conv2(128->256,k3,p1)+relu -> comb[..., 256:512]
// One block per batch element (relative to chunk base).
// ---------------------------------------------------------------------------
__global__ __launch_bounds__(256) void frontend_kernel(
    const float* __restrict__ x,                     // (Bc, 100, 23) chunk base
    const float* __restrict__ fe_w, const float* __restrict__ fe_b,
    const float* __restrict__ g1, const float* __restrict__ b1,
    const float* __restrict__ g2, const float* __restrict__ b2,
    const float* __restrict__ c1w, const float* __restrict__ c1b,   // (128,22,3),(128)
    const float* __restrict__ c2w, const float* __restrict__ c2b,   // (256,128,3),(256)
    bf16_t* __restrict__ comb)                       // (Bc, 100, 512) bf16
{
    const int b = blockIdx.x;
    const int t = threadIdx.x;
    const int wv = t >> 6, lane = t & 63;

    // ---- phase A: id embedding ----
    float few[4], feb[4], lg1[4], lb1[4], lg2[4], lb2[4];
    #pragma unroll
    for (int q = 0; q < 4; ++q){
        int j = lane + 64*q;
        few[q] = fe_w[j]; feb[q] = fe_b[j];
        lg1[q] = g1[j];  lb1[q] = b1[j];
        lg2[q] = g2[j];  lb2[q] = b2[j];
    }
    for (int l = wv; l < SEQ; l += 4){
        float m = fabsf(x[(size_t)(b*SEQ + l)*23]);
        float e[4];
        float s1 = 0.f, s2 = 0.f;
        #pragma unroll
        for (int q = 0; q < 4; ++q){ e[q] = m*few[q] + feb[q]; s1 += e[q]; s2 += e[q]*e[q]; }
        #pragma unroll
        for (int off = 32; off > 0; off >>= 1){ s1 += __shfl_xor(s1, off); s2 += __shfl_xor(s2, off); }
        float mean = s1 * (1.f/256.f);
        float rstd = rsqrtf(s2*(1.f/256.f) - mean*mean + 1e-5f);
        s1 = 0.f; s2 = 0.f;
        #pragma unroll
        for (int q = 0; q < 4; ++q){
            e[q] = fmaxf((e[q]-mean)*rstd*lg1[q] + lb1[q], 0.f);
            s1 += e[q]; s2 += e[q]*e[q];
        }
        #pragma unroll
        for (int off = 32; off > 0; off >>= 1){ s1 += __shfl_xor(s1, off); s2 += __shfl_xor(s2, off); }
        mean = s1 * (1.f/256.f);
        rstd = rsqrtf(s2*(1.f/256.f) - mean*mean + 1e-5f);
        #pragma unroll
        for (int q = 0; q < 4; ++q){
            float v = fmaxf((e[q]-mean)*rstd*lg2[q] + lb2[q], 0.f);
            comb[(size_t)(b*SEQ + l)*512 + lane + 64*q] = (bf16_t)v;
        }
    }

    // ---- phase B: conv stack ----
    __shared__ float sdata[22*104];   // data with +1 zero-pad offset in l
    __shared__ float sf1[128*104];    // f1 with +1 zero-pad offset in l
    for (int idx = t; idx < 22*SEQ; idx += 256){
        int c = idx / SEQ, l = idx - c*SEQ;
        sdata[c*104 + l + 1] = x[(size_t)(b*SEQ + l)*23 + 1 + c];
    }
    if (t < 22){ sdata[t*104 + 0] = 0.f; sdata[t*104 + 101] = 0.f; }
    __syncthreads();

    {   // f1: 128 channels x 100, each thread does one channel-half
        int o = t >> 1, half = t & 1;
        int lbase = half * 50;
        for (int lc = 0; lc < 50; lc += 10){
            int lofs = lbase + lc;
            float a[10];
            float bia = c1b[o];
            #pragma unroll
            for (int i = 0; i < 10; ++i) a[i] = bia;
            for (int c = 0; c < 22; ++c){
                float w0 = c1w[(o*22 + c)*3 + 0];
                float w1 = c1w[(o*22 + c)*3 + 1];
                float w2 = c1w[(o*22 + c)*3 + 2];
                float s0 = sdata[c*104 + lofs];
                float sc = sdata[c*104 + lofs + 1];
                #pragma unroll
                for (int i = 0; i < 10; ++i){
                    float sn = sdata[c*104 + lofs + i + 2];
                    a[i] += w0*s0 + w1*sc + w2*sn;
                    s0 = sc; sc = sn;
                }
            }
            #pragma unroll
            for (int i = 0; i < 10; ++i) sf1[o*104 + lofs + i + 1] = fmaxf(a[i], 0.f);
        }
        if (t < 128){ sf1[t*104 + 0] = 0.f; sf1[t*104 + 101] = 0.f; }
    }
    __syncthreads();

    {   // f2: 256 channels x 100; thread t = output channel
        int o = t;
        for (int lc = 0; lc < SEQ; lc += 20){
            float a[20];
            float bia = c2b[o];
            #pragma unroll
            for (int i = 0; i < 20; ++i) a[i] = bia;
            for (int c = 0; c < 128; ++c){
                float w0 = c2w[(o*128 + c)*3 + 0];
                float w1 = c2w[(o*128 + c)*3 + 1];
                float w2 = c2w[(o*128 + c)*3 + 2];
                float s0 = sf1[c*104 + lc];
                float sc = sf1[c*104 + lc + 1];
                #pragma unroll
                for (int i = 0; i < 20; ++i){
                    float sn = sf1[c*104 + lc + i + 2];
                    a[i] += w0*s0 + w1*sc + w2*sn;
                    s0 = sc; sc = sn;
                }
            }
            #pragma unroll
            for (int i = 0; i < 20; ++i)
                comb[(size_t)(b*SEQ + lc + i)*512 + 256 + o] = (bf16_t)fmaxf(a[i], 0.f);
        }
    }
}

// ---------------------------------------------------------------------------
// bf16 MFMA GEMM: C[m,n] (+)= sum_k A[m,k]*W[n,k], fp32 accumulate.
// A:(Mtot,lda) bf16 K-contig; W:(N,K) bf16 row-major; C fp32 (ldc).
// 128x128 tile, BK=32, 256 threads = 4 waves, each wave 64x64 via 4x4 MFMA
// 16x16x32. Staging: global_load_lds 16B/lane with XOR-swizzled k-chunks
// (phys = logical ^ ((row>>1)&3)) so unpadded ds_read_b128 frag reads are
// bank-uniform. Requires N%128==0, K%32==0; M ragged OK (clamped loads,
// guarded stores).
// ---------------------------------------------------------------------------
__global__ __launch_bounds__(256) void gemm_bf16_kernel(
    const bf16_t* __restrict__ A, int lda, int Mtot,
    const bf16_t* __restrict__ W, int K, int N,
    float* __restrict__ C, int ldc, int accumulate)
{
    __shared__ bf16_t As[128*32];
    __shared__ bf16_t Ws[128*32];
    const int t = threadIdx.x;
    const int lane = t & 63, w = t >> 6;
    const int m0 = blockIdx.x * 128, n0 = blockIdx.y * 128;
    const int rsub = lane >> 2, csub = lane & 3;
    const int col = lane & 15, quad = lane >> 4;
    const int wOffM = (w & 1) * 64, wOffN = (w >> 1) * 64;

    f32x4 acc[4][4];
    #pragma unroll
    for (int i = 0; i < 4; ++i)
        #pragma unroll
        for (int j = 0; j < 4; ++j)
            acc[i][j] = (f32x4){0.f, 0.f, 0.f, 0.f};

    for (int k0 = 0; k0 < K; k0 += 32){
        __syncthreads();   // previous iter's readers done before DMA overwrite
        #pragma unroll
        for (int q = 0; q < 2; ++q){
            const int rt = w*32 + q*16 + rsub;          // tile row 0..127
            const int lq = csub ^ ((rt >> 1) & 3);      // logical 16B k-chunk fetched
            int ra = m0 + rt; ra = (ra < Mtot) ? ra : (Mtot - 1);
            const bf16_t* ga = A + (size_t)ra*lda + k0 + lq*8;
            __builtin_amdgcn_global_load_lds(
                (const __attribute__((address_space(1))) void*)ga,
                (__attribute__((address_space(3))) void*)&As[(w*32 + q*16)*32], 16, 0, 0);
            const bf16_t* gw = W + (size_t)(n0 + rt)*K + k0 + lq*8;
            __builtin_amdgcn_global_load_lds(
                (const __attribute__((address_space(1))) void*)gw,
                (__attribute__((address_space(3))) void*)&Ws[(w*32 + q*16)*32], 16, 0, 0);
        }
        __syncthreads();

        bf16x8 af[4], bfv[4];
        #pragma unroll
        for (int i = 0; i < 4; ++i){
            const int ra = wOffM + i*16 + col;
            af[i]  = *(const bf16x8*)&As[ra*32 + (quad ^ ((ra >> 1) & 3))*8];
            const int rb = wOffN + i*16 + col;
            bfv[i] = *(const bf16x8*)&Ws[rb*32 + (quad ^ ((rb >> 1) & 3))*8];
        }
        #pragma unroll
        for (int i = 0; i < 4; ++i)
            #pragma unroll
            for (int j = 0; j < 4; ++j)
                acc[i][j] = __builtin_amdgcn_mfma_f32_16x16x32_bf16(af[i], bfv[j], acc[i][j], 0, 0, 0);
    }

    // C/D layout: col=lane&15, row=(lane>>4)*4+reg  [m89-verified]
    #pragma unroll
    for (int i = 0; i < 4; ++i){
        const int gmb = m0 + wOffM + i*16 + quad*4;
        #pragma unroll
        for (int j = 0; j < 4; ++j){
            const int gn = n0 + wOffN + j*16 + col;
            #pragma unroll
            for (int r = 0; r < 4; ++r){
                const int gm = gmb + r;
                if (gm < Mtot){
                    float v = acc[i][j][r];
                    size_t off = (size_t)gm*ldc + gn;
                    if (accumulate) v += C[off];
                    C[off] = v;
                }
            }
        }
    }
}

// ---------------------------------------------------------------------------
// fp32 GEMM (kept for the small x-proj): C[m,n] = sum_k A[m,k]*W[n,k]
// ---------------------------------------------------------------------------
__global__ __launch_bounds__(256) void gemm64_kernel(
    const float* __restrict__ A, int lda,
    const float* __restrict__ W, int K, int N,
    float* __restrict__ C, int ldc)
{
    __shared__ float As[16][68];
    __shared__ float Ws[16][68];
    const int t = threadIdx.x;
    const int m0 = blockIdx.x * 64, n0 = blockIdx.y * 64;
    const int tx = t & 15, ty = t >> 4;
    const int lr = t >> 2;
    const int lk = (t & 3) * 4;
    const float* Aptr = A + (size_t)(m0 + lr)*lda + lk;
    const float* Wptr = W + (size_t)(n0 + lr)*K + lk;
    const bool wvalid = (n0 + lr) < N;
    float acc[4][4] = {};
    for (int k0 = 0; k0 < K; k0 += 16){
        float4 av = *(const float4*)(Aptr + k0);
        float4 wv = wvalid ? *(const float4*)(Wptr + k0) : make_float4(0.f,0.f,0.f,0.f);
        __syncthreads();
        As[lk+0][lr] = av.x; As[lk+1][lr] = av.y; As[lk+2][lr] = av.z; As[lk+3][lr] = av.w;
        Ws[lk+0][lr] = wv.x; Ws[lk+1][lr] = wv.y; Ws[lk+2][lr] = wv.z; Ws[lk+3][lr] = wv.w;
        __syncthreads();
        #pragma unroll
        for (int k = 0; k < 16; ++k){
            float4 a4 = *(const float4*)&As[k][ty*4];
            float4 w4 = *(const float4*)&Ws[k][tx*4];
            float av4[4] = {a4.x, a4.y, a4.z, a4.w};
            float wv4[4] = {w4.x, w4.y, w4.z, w4.w};
            #pragma unroll
            for (int i = 0; i < 4; ++i)
                #pragma unroll
                for (int j = 0; j < 4; ++j)
                    acc[i][j] += av4[i]*wv4[j];
        }
    }
    #pragma unroll
    for (int i = 0; i < 4; ++i){
        size_t row = (size_t)(m0 + ty*4 + i)*ldc;
        #pragma unroll
        for (int j = 0; j < 4; ++j){
            int n = n0 + tx*4 + j;
            if (n < N) C[row + n] = acc[i][j];
        }
    }
}

// ---------------------------------------------------------------------------
// Depthwise causal conv + bias + silu, in place on the x-half of xz.
// ---------------------------------------------------------------------------
template<int DC, bool REV>
__global__ __launch_bounds__(256) void conv_silu_kernel(
    float* __restrict__ xz, const float* __restrict__ cw, const float* __restrict__ cb)
{
    const int gid = blockIdx.x*256 + threadIdx.x;   // Bc*DI threads
    const int b = gid >> 10, d = gid & 1023;
    float w[DC];
    #pragma unroll
    for (int k = 0; k < DC; ++k) w[k] = cw[d*DC + k];
    const float bias = cb[d];
    float hist[DC-1];
    #pragma unroll
    for (int k = 0; k < DC-1; ++k) hist[k] = 0.f;
    float* base = xz + (size_t)b*SEQ*2048 + d;
    for (int tt = 0; tt < SEQ; ++tt){
        const int l = REV ? (SEQ-1-tt) : tt;
        float cur = base[(size_t)l*2048];
        float a = bias + w[DC-1]*cur;
        #pragma unroll
        for (int j = 1; j < DC; ++j) a += w[DC-1-j]*hist[j-1];
        #pragma unroll
        for (int j = DC-2; j >= 1; --j) hist[j] = hist[j-1];
        hist[0] = cur;
        base[(size_t)l*2048] = siluf_(a);
    }
}

// ---------------------------------------------------------------------------
// Selective scan fused with dt projection; writes y as bf16 to ybf (M,1024).
// ---------------------------------------------------------------------------
template<int DS, bool REV>
__global__ __launch_bounds__(256) void scan_kernel(
    const float* __restrict__ xz,        // (Bc*L, 2048): x [0,1024), z [1024,2048)
    const float* __restrict__ xdb,       // (Bc*L, 64): [0:32]=dt_in, [32:32+DS]=B, [32+DS:+DS]=C
    const float* __restrict__ dt_w,      // (1024, 32)
    const float* __restrict__ dt_b,      // (1024)
    const float* __restrict__ Alog,      // (1024, DS)
    const float* __restrict__ Dp,        // (1024)
    bf16_t* __restrict__ ybf)            // (Bc*L, 1024) bf16
{
    const int b = blockIdx.x >> 2;
    const int d = ((blockIdx.x & 3) << 8) + threadIdx.x;
    float w[32];
    #pragma unroll
    for (int r = 0; r < 32; ++r) w[r] = dt_w[d*32 + r];
    const float dtb = dt_b[d];
    const float Dd = Dp[d];
    float Av[DS], h[DS];
    #pragma unroll
    for (int s = 0; s < DS; ++s){ Av[s] = -__expf(Alog[d*DS + s]); h[s] = 0.f; }
    __shared__ float sx[64];
    const float* xbase = xz + (size_t)b*SEQ*2048;
    const float* xdbase = xdb + (size_t)b*SEQ*64;
    bf16_t* ybase = ybf + (size_t)b*SEQ*1024;
    for (int tt = 0; tt < SEQ; ++tt){
        const int l = REV ? (SEQ-1-tt) : tt;
        __syncthreads();
        if (threadIdx.x < 32 + 2*DS) sx[threadIdx.x] = xdbase[l*64 + threadIdx.x];
        __syncthreads();
        float dacc = dtb;
        #pragma unroll
        for (int r = 0; r < 32; ++r) dacc += w[r]*sx[r];
        const float dtv = softplusf_(dacc);
        const float xv = xbase[(size_t)l*2048 + d];
        const float zv = xbase[(size_t)l*2048 + 1024 + d];
        const float dtx = dtv * xv;
        float yv = 0.f;
        #pragma unroll
        for (int s = 0; s < DS; ++s){
            h[s] = __expf(dtv*Av[s])*h[s] + dtx*sx[32+s];
            yv += h[s]*sx[32+DS+s];
        }
        yv += xv*Dd;
        yv *= siluf_(zv);
        ybase[(size_t)l*1024 + d] = (bf16_t)yv;
    }
}

// ---------------------------------------------------------------------------
// Head: max-pool over L, LayerNorm(512), fc1(512->128)+relu, fc2(128->4)
// ---------------------------------------------------------------------------
__global__ __launch_bounds__(256) void head_kernel(
    const float* __restrict__ acc,   // (Bc, L, 512)
    const float* __restrict__ ng, const float* __restrict__ nb,
    const float* __restrict__ w1, const float* __restrict__ b1,
    const float* __restrict__ w2, const float* __restrict__ b2,
    float* __restrict__ out)         // (Bc, 4) chunk base
{
    const int b = blockIdx.x, t = threadIdx.x;
    __shared__ float sp[512];
    __shared__ float sh[128];
    __shared__ float red1[4], red2[4];
    const float* base = acc + (size_t)b*SEQ*512;
    for (int o = t; o < 512; o += 256){
        float m = -3.4e38f;
        for (int l = 0; l < SEQ; ++l) m = fmaxf(m, base[(size_t)l*512 + o]);
        sp[o] = m;
    }
    __syncthreads();
    float s1 = 0.f, s2 = 0.f;
    for (int o = t; o < 512; o += 256){ float v = sp[o]; s1 += v; s2 += v*v; }
    #pragma unroll
    for (int off = 32; off > 0; off >>= 1){ s1 += __shfl_xor(s1, off); s2 += __shfl_xor(s2, off); }
    const int wv = t >> 6, lane = t & 63;
    if (lane == 0){ red1[wv] = s1; red2[wv] = s2; }
    __syncthreads();
    if (t == 0){
        float a = 0.f, c = 0.f;
        for (int i = 0; i < 4; ++i){ a += red1[i]; c += red2[i]; }
        float mean = a * (1.f/512.f);
        float var = c * (1.f/512.f) - mean*mean;
        red1[0] = mean; red2[0] = rsqrtf(var + 1e-5f);
    }
    __syncthreads();
    const float mean = red1[0], rstd = red2[0];
    for (int o = t; o < 512; o += 256) sp[o] = (sp[o]-mean)*rstd*ng[o] + nb[o];
    __syncthreads();
    if (t < 128){
        float a = b1[t];
        for (int o = 0; o < 512; ++o) a += sp[o]*w1[t*512 + o];
        sh[t] = fmaxf(a, 0.f);
    }
    __syncthreads();
    if (t < 4){
        float a = b2[t];
        for (int j = 0; j < 128; ++j) a += sh[j]*w2[t*128 + j];
        out[b*4 + t] = a;
    }
}

// ---------------------------------------------------------------------------
extern "C" void kernel_launch(void* const* d_in, const int* in_sizes, int n_in,
                              void* d_out, int out_size, void* d_ws, size_t ws_size,
                              hipStream_t stream)
{
    (void)in_sizes; (void)n_in; (void)out_size;
    const float* x        = (const float*)d_in[0];
    const float* fe_w     = (const float*)d_in[1];
    const float* fe_b     = (const float*)d_in[2];
    const float* fe_ln_g  = (const float*)d_in[3];
    const float* fe_ln_b  = (const float*)d_in[4];
    const float* emb_ln_g = (const float*)d_in[5];
    const float* emb_ln_b = (const float*)d_in[6];
    const float* conv1_w  = (const float*)d_in[7];
    const float* conv1_b  = (const float*)d_in[8];
    const float* conv2_w  = (const float*)d_in[9];
    const float* conv2_b  = (const float*)d_in[10];
    const float* mf_in_w  = (const float*)d_in[11];
    const float* mf_conv_w= (const float*)d_in[12];
    const float* mf_conv_b= (const float*)d_in[13];
    const float* mf_xproj = (const float*)d_in[14];
    const float* mf_dt_w  = (const float*)d_in[15];
    const float* mf_dt_b  = (const float*)d_in[16];
    const float* mf_Alog  = (const float*)d_in[17];
    const float* mf_D     = (const float*)d_in[18];
    const float* mf_out_w = (const float*)d_in[19];
    const float* mb_in_w  = (const float*)d_in[20];
    const float* mb_conv_w= (const float*)d_in[21];
    const float* mb_conv_b= (const float*)d_in[22];
    const float* mb_xproj = (const float*)d_in[23];
    const float* mb_dt_w  = (const float*)d_in[24];
    const float* mb_dt_b  = (const float*)d_in[25];
    const float* mb_Alog  = (const float*)d_in[26];
    const float* mb_D     = (const float*)d_in[27];
    const float* mb_out_w = (const float*)d_in[28];
    const float* norm_g   = (const float*)d_in[29];
    const float* norm_b   = (const float*)d_in[30];
    const float* fc1_w    = (const float*)d_in[31];
    const float* fc1_b    = (const float*)d_in[32];
    const float* fc2_w    = (const float*)d_in[33];
    const float* fc2_b    = (const float*)d_in[34];
    float* out = (float*)d_out;

    // ---- workspace carve: bf16 weights first (constant), then chunk buffers ----
    char* p = (char*)d_ws;
    bf16_t* w_inf  = (bf16_t*)p; p += (size_t)2048*512*sizeof(bf16_t);
    bf16_t* w_inb  = (bf16_t*)p; p += (size_t)2048*512*sizeof(bf16_t);
    bf16_t* w_outf = (bf16_t*)p; p += (size_t)512*1024*sizeof(bf16_t);
    bf16_t* w_outb = (bf16_t*)p; p += (size_t)512*1024*sizeof(bf16_t);
    const size_t wbytes = (size_t)(p - (char*)d_ws);

    // per-batch bytes: comb bf16 100*512*2 + xz f32 100*2048*4 + ybf 100*1024*2
    //                + xdb f32 100*64*4 + acc f32 100*512*4 = 1,356,800
    const size_t per_b = (size_t)SEQ * (512*2 + 2048*4 + 1024*2 + 64*4 + 512*4);
    const size_t budget = (ws_size > wbytes) ? (ws_size - wbytes) : 0;
    int Bc = BSZ;
    while (Bc > 16 && (size_t)Bc * per_b > budget) Bc >>= 1;
    const int nch = BSZ / Bc;
    const int M = Bc * SEQ;

    bf16_t* comb = (bf16_t*)p;               p += (size_t)M*512*sizeof(bf16_t);
    float*  xz   = (float*)p;                p += (size_t)M*2048*sizeof(float);
    bf16_t* ybf  = (bf16_t*)p;               p += (size_t)M*1024*sizeof(bf16_t);
    float*  xdb  = (float*)p;                p += (size_t)M*64*sizeof(float);
    float*  accb = (float*)p;

    // ---- weight conversions (once per call) ----
    cvt_bf16_kernel<<<(2048*512+255)/256, 256, 0, stream>>>(mf_in_w,  w_inf,  2048*512);
    cvt_bf16_kernel<<<(2048*512+255)/256, 256, 0, stream>>>(mb_in_w,  w_inb,  2048*512);
    cvt_bf16_kernel<<<(512*1024+255)/256, 256, 0, stream>>>(mf_out_w, w_outf, 512*1024);
    cvt_bf16_kernel<<<(512*1024+255)/256, 256, 0, stream>>>(mb_out_w, w_outb, 512*1024);

    const int gm128 = (M + 127) / 128;

    for (int c = 0; c < nch; ++c){
        const size_t b0 = (size_t)c * Bc;

        frontend_kernel<<<Bc, 256, 0, stream>>>(x + b0*SEQ*23, fe_w, fe_b,
            fe_ln_g, fe_ln_b, emb_ln_g, emb_ln_b, conv1_w, conv1_b, conv2_w, conv2_b, comb);

        // ---- forward mamba (d_state=16, d_conv=4) ----
        gemm_bf16_kernel<<<dim3(gm128, 16), 256, 0, stream>>>(comb, 512, M, w_inf, 512, 2048, xz, 2048, 0);
        conv_silu_kernel<4, false><<<Bc*DI/256, 256, 0, stream>>>(xz, mf_conv_w, mf_conv_b);
        gemm64_kernel<<<dim3(M/64, 1), 256, 0, stream>>>(xz, 2048, mf_xproj, 1024, 64, xdb, 64);
        scan_kernel<16, false><<<Bc*4, 256, 0, stream>>>(xz, xdb, mf_dt_w, mf_dt_b, mf_Alog, mf_D, ybf);
        gemm_bf16_kernel<<<dim3(gm128, 4), 256, 0, stream>>>(ybf, 1024, M, w_outf, 1024, 512, accb, 512, 0);

        // ---- backward mamba (d_state=8, d_conv=2), time-reversed in place ----
        gemm_bf16_kernel<<<dim3(gm128, 16), 256, 0, stream>>>(comb, 512, M, w_inb, 512, 2048, xz, 2048, 0);
        conv_silu_kernel<2, true><<<Bc*DI/256, 256, 0, stream>>>(xz, mb_conv_w, mb_conv_b);
        gemm64_kernel<<<dim3(M/64, 1), 256, 0, stream>>>(xz, 2048, mb_xproj, 1024, 48, xdb, 64);
        scan_kernel<8, true><<<Bc*4, 256, 0, stream>>>(xz, xdb, mb_dt_w, mb_dt_b, mb_Alog, mb_D, ybf);
        gemm_bf16_kernel<<<dim3(gm128, 4), 256, 0, stream>>>(ybf, 1024, M, w_outb, 1024, 512, accb, 512, 1);

        head_kernel<<<Bc, 256, 0, stream>>>(accb, norm_g, norm_b, fc1_w, fc1_b, fc2_w, fc2_b,
                                            out + b0*4);
    }
}

// Round 4
// 2818.209 us; speedup vs baseline: 2.3782x; 1.1954x over previous
//
#include <hip/hip_runtime.h>
#include <cstddef>
#include <cstdint>

#define BSZ 512
#define SEQ 100
#define DI 1024

typedef __bf16 bf16_t;
typedef __attribute__((ext_vector_type(8))) __bf16 bf16x8;
typedef __attribute__((ext_vector_type(4))) float f32x4;

__device__ __forceinline__ float sigmoidf_(float v){ return 1.f/(1.f + __expf(-v)); }
__device__ __forceinline__ float siluf_(float v){ return v * sigmoidf_(v); }
__device__ __forceinline__ float softplusf_(float v){ return (v > 20.f) ? v : log1pf(__expf(v)); }

// ---------------------------------------------------------------------------
// fp32 -> bf16 converter (weights), once per call
// ---------------------------------------------------------------------------
__global__ __launch_bounds__(256) void cvt_bf16_kernel(
    const float* __restrict__ src, bf16_t* __restrict__ dst, int n)
{
    int i = blockIdx.x*256 + threadIdx.x;
    if (i < n) dst[i] = (bf16_t)src[i];
}

// ---------------------------------------------------------------------------
// Front-end (ALL batches, once): id-embed (2 LN) -> comb[...,0:256] (bf16)
//            conv1(22->128,k3,p1)+relu -> conv2(128->256,k3,p1)+relu -> comb[...,256:512]
// One block per batch element; grid = 512 = 2 blocks/CU at 62 KB LDS.
// ---------------------------------------------------------------------------
__global__ __launch_bounds__(256) void frontend_kernel(
    const float* __restrict__ x,                     // (512, 100, 23)
    const float* __restrict__ fe_w, const float* __restrict__ fe_b,
    const float* __restrict__ g1, const float* __restrict__ b1,
    const float* __restrict__ g2, const float* __restrict__ b2,
    const float* __restrict__ c1w, const float* __restrict__ c1b,   // (128,22,3),(128)
    const float* __restrict__ c2w, const float* __restrict__ c2b,   // (256,128,3),(256)
    bf16_t* __restrict__ comb)                       // (512, 100, 512) bf16
{
    const int b = blockIdx.x;
    const int t = threadIdx.x;
    const int wv = t >> 6, lane = t & 63;

    // ---- phase A: id embedding ----
    float few[4], feb[4], lg1[4], lb1[4], lg2[4], lb2[4];
    #pragma unroll
    for (int q = 0; q < 4; ++q){
        int j = lane + 64*q;
        few[q] = fe_w[j]; feb[q] = fe_b[j];
        lg1[q] = g1[j];  lb1[q] = b1[j];
        lg2[q] = g2[j];  lb2[q] = b2[j];
    }
    for (int l = wv; l < SEQ; l += 4){
        float m = fabsf(x[(size_t)(b*SEQ + l)*23]);
        float e[4];
        float s1 = 0.f, s2 = 0.f;
        #pragma unroll
        for (int q = 0; q < 4; ++q){ e[q] = m*few[q] + feb[q]; s1 += e[q]; s2 += e[q]*e[q]; }
        #pragma unroll
        for (int off = 32; off > 0; off >>= 1){ s1 += __shfl_xor(s1, off); s2 += __shfl_xor(s2, off); }
        float mean = s1 * (1.f/256.f);
        float rstd = rsqrtf(s2*(1.f/256.f) - mean*mean + 1e-5f);
        s1 = 0.f; s2 = 0.f;
        #pragma unroll
        for (int q = 0; q < 4; ++q){
            e[q] = fmaxf((e[q]-mean)*rstd*lg1[q] + lb1[q], 0.f);
            s1 += e[q]; s2 += e[q]*e[q];
        }
        #pragma unroll
        for (int off = 32; off > 0; off >>= 1){ s1 += __shfl_xor(s1, off); s2 += __shfl_xor(s2, off); }
        mean = s1 * (1.f/256.f);
        rstd = rsqrtf(s2*(1.f/256.f) - mean*mean + 1e-5f);
        #pragma unroll
        for (int q = 0; q < 4; ++q){
            float v = fmaxf((e[q]-mean)*rstd*lg2[q] + lb2[q], 0.f);
            comb[(size_t)(b*SEQ + l)*512 + lane + 64*q] = (bf16_t)v;
        }
    }

    // ---- phase B: conv stack ----
    __shared__ float sdata[22*104];   // data with +1 zero-pad offset in l
    __shared__ float sf1[128*104];    // f1 with +1 zero-pad offset in l
    for (int idx = t; idx < 22*SEQ; idx += 256){
        int c = idx / SEQ, l = idx - c*SEQ;
        sdata[c*104 + l + 1] = x[(size_t)(b*SEQ + l)*23 + 1 + c];
    }
    if (t < 22){ sdata[t*104 + 0] = 0.f; sdata[t*104 + 101] = 0.f; }
    __syncthreads();

    {   // f1: 128 channels x 100, each thread does one channel-half
        int o = t >> 1, half = t & 1;
        int lbase = half * 50;
        for (int lc = 0; lc < 50; lc += 10){
            int lofs = lbase + lc;
            float a[10];
            float bia = c1b[o];
            #pragma unroll
            for (int i = 0; i < 10; ++i) a[i] = bia;
            for (int c = 0; c < 22; ++c){
                float w0 = c1w[(o*22 + c)*3 + 0];
                float w1 = c1w[(o*22 + c)*3 + 1];
                float w2 = c1w[(o*22 + c)*3 + 2];
                float s0 = sdata[c*104 + lofs];
                float sc = sdata[c*104 + lofs + 1];
                #pragma unroll
                for (int i = 0; i < 10; ++i){
                    float sn = sdata[c*104 + lofs + i + 2];
                    a[i] += w0*s0 + w1*sc + w2*sn;
                    s0 = sc; sc = sn;
                }
            }
            #pragma unroll
            for (int i = 0; i < 10; ++i) sf1[o*104 + lofs + i + 1] = fmaxf(a[i], 0.f);
        }
        if (t < 128){ sf1[t*104 + 0] = 0.f; sf1[t*104 + 101] = 0.f; }
    }
    __syncthreads();

    {   // f2: 256 channels x 100; thread t = output channel
        int o = t;
        for (int lc = 0; lc < SEQ; lc += 20){
            float a[20];
            float bia = c2b[o];
            #pragma unroll
            for (int i = 0; i < 20; ++i) a[i] = bia;
            for (int c = 0; c < 128; ++c){
                float w0 = c2w[(o*128 + c)*3 + 0];
                float w1 = c2w[(o*128 + c)*3 + 1];
                float w2 = c2w[(o*128 + c)*3 + 2];
                float s0 = sf1[c*104 + lc];
                float sc = sf1[c*104 + lc + 1];
                #pragma unroll
                for (int i = 0; i < 20; ++i){
                    float sn = sf1[c*104 + lc + i + 2];
                    a[i] += w0*s0 + w1*sc + w2*sn;
                    s0 = sc; sc = sn;
                }
            }
            #pragma unroll
            for (int i = 0; i < 20; ++i)
                comb[(size_t)(b*SEQ + lc + i)*512 + 256 + o] = (bf16_t)fmaxf(a[i], 0.f);
        }
    }
}

// ---------------------------------------------------------------------------
// bf16 MFMA GEMM: C[m,n] (+)= sum_k A[m,k]*W[n,k], fp32 accumulate.
// 128x128 tile, BK=32, 4 waves, each 64x64 via 4x4 mfma_f32_16x16x32_bf16.
// global_load_lds 16B staging with XOR-swizzled k-chunks (no LDS padding).
// Requires N%128==0, K%32==0, M%128==0 (callers guarantee).
// ---------------------------------------------------------------------------
__global__ __launch_bounds__(256) void gemm_bf16_kernel(
    const bf16_t* __restrict__ A, int lda, int Mtot,
    const bf16_t* __restrict__ W, int K, int N,
    float* __restrict__ C, int ldc, int accumulate)
{
    __shared__ bf16_t As[128*32];
    __shared__ bf16_t Ws[128*32];
    const int t = threadIdx.x;
    const int lane = t & 63, w = t >> 6;
    const int m0 = blockIdx.x * 128, n0 = blockIdx.y * 128;
    const int rsub = lane >> 2, csub = lane & 3;
    const int col = lane & 15, quad = lane >> 4;
    const int wOffM = (w & 1) * 64, wOffN = (w >> 1) * 64;

    f32x4 acc[4][4];
    #pragma unroll
    for (int i = 0; i < 4; ++i)
        #pragma unroll
        for (int j = 0; j < 4; ++j)
            acc[i][j] = (f32x4){0.f, 0.f, 0.f, 0.f};

    for (int k0 = 0; k0 < K; k0 += 32){
        __syncthreads();
        #pragma unroll
        for (int q = 0; q < 2; ++q){
            const int rt = w*32 + q*16 + rsub;          // tile row 0..127
            const int lq = csub ^ ((rt >> 1) & 3);      // logical 16B k-chunk fetched
            int ra = m0 + rt; ra = (ra < Mtot) ? ra : (Mtot - 1);
            const bf16_t* ga = A + (size_t)ra*lda + k0 + lq*8;
            __builtin_amdgcn_global_load_lds(
                (const __attribute__((address_space(1))) void*)ga,
                (__attribute__((address_space(3))) void*)&As[(w*32 + q*16)*32], 16, 0, 0);
            const bf16_t* gw = W + (size_t)(n0 + rt)*K + k0 + lq*8;
            __builtin_amdgcn_global_load_lds(
                (const __attribute__((address_space(1))) void*)gw,
                (__attribute__((address_space(3))) void*)&Ws[(w*32 + q*16)*32], 16, 0, 0);
        }
        __syncthreads();

        bf16x8 af[4], bfv[4];
        #pragma unroll
        for (int i = 0; i < 4; ++i){
            const int ra = wOffM + i*16 + col;
            af[i]  = *(const bf16x8*)&As[ra*32 + (quad ^ ((ra >> 1) & 3))*8];
            const int rb = wOffN + i*16 + col;
            bfv[i] = *(const bf16x8*)&Ws[rb*32 + (quad ^ ((rb >> 1) & 3))*8];
        }
        #pragma unroll
        for (int i = 0; i < 4; ++i)
            #pragma unroll
            for (int j = 0; j < 4; ++j)
                acc[i][j] = __builtin_amdgcn_mfma_f32_16x16x32_bf16(af[i], bfv[j], acc[i][j], 0, 0, 0);
    }

    // C/D layout: col=lane&15, row=(lane>>4)*4+reg  [m89-verified]
    #pragma unroll
    for (int i = 0; i < 4; ++i){
        const int gmb = m0 + wOffM + i*16 + quad*4;
        #pragma unroll
        for (int j = 0; j < 4; ++j){
            const int gn = n0 + wOffN + j*16 + col;
            #pragma unroll
            for (int r = 0; r < 4; ++r){
                const int gm = gmb + r;
                if (gm < Mtot){
                    float v = acc[i][j][r];
                    size_t off = (size_t)gm*ldc + gn;
                    if (accumulate) v += C[off];
                    C[off] = v;
                }
            }
        }
    }
}

// ---------------------------------------------------------------------------
// bf16 MFMA GEMM, narrow-N (x-proj): C[m,n] = sum_k A[m,k]*W[n,k], N<=64.
// 256x64 tile, BK=32, 4 waves: wave w covers rows w*64..w*64+63, all 64 cols.
// A:(M,K) bf16 contig; W:(N,K) bf16 (N-ragged rows clamped); C fp32 ldc=64.
// Requires M%256==0, K%32==0.
// ---------------------------------------------------------------------------
__global__ __launch_bounds__(256) void gemm_bf16_n64_kernel(
    const bf16_t* __restrict__ A, const bf16_t* __restrict__ W,
    int K, int N, float* __restrict__ C)
{
    __shared__ bf16_t As[256*32];
    __shared__ bf16_t Ws[64*32];
    const int t = threadIdx.x;
    const int lane = t & 63, w = t >> 6;
    const int m0 = blockIdx.x * 256;
    const int rsub = lane >> 2, csub = lane & 3;
    const int col = lane & 15, quad = lane >> 4;

    f32x4 acc[4][4];
    #pragma unroll
    for (int i = 0; i < 4; ++i)
        #pragma unroll
        for (int j = 0; j < 4; ++j)
            acc[i][j] = (f32x4){0.f, 0.f, 0.f, 0.f};

    for (int k0 = 0; k0 < K; k0 += 32){
        __syncthreads();
        #pragma unroll
        for (int q = 0; q < 4; ++q){                    // A rows: q*64 + w*16 + rsub
            const int rt = q*64 + w*16 + rsub;
            const int lq = csub ^ ((rt >> 1) & 3);
            const bf16_t* ga = A + (size_t)(m0 + rt)*K + k0 + lq*8;
            __builtin_amdgcn_global_load_lds(
                (const __attribute__((address_space(1))) void*)ga,
                (__attribute__((address_space(3))) void*)&As[(q*64 + w*16)*32], 16, 0, 0);
        }
        {                                               // W rows: w*16 + rsub (clamped)
            const int rt = w*16 + rsub;
            const int lq = csub ^ ((rt >> 1) & 3);
            int rw = (rt < N) ? rt : (N - 1);
            const bf16_t* gw = W + (size_t)rw*K + k0 + lq*8;
            __builtin_amdgcn_global_load_lds(
                (const __attribute__((address_space(1))) void*)gw,
                (__attribute__((address_space(3))) void*)&Ws[(w*16)*32], 16, 0, 0);
        }
        __syncthreads();

        bf16x8 af[4], bfv[4];
        #pragma unroll
        for (int i = 0; i < 4; ++i){
            const int ra = w*64 + i*16 + col;
            af[i]  = *(const bf16x8*)&As[ra*32 + (quad ^ ((ra >> 1) & 3))*8];
            const int rb = i*16 + col;
            bfv[i] = *(const bf16x8*)&Ws[rb*32 + (quad ^ ((rb >> 1) & 3))*8];
        }
        #pragma unroll
        for (int i = 0; i < 4; ++i)
            #pragma unroll
            for (int j = 0; j < 4; ++j)
                acc[i][j] = __builtin_amdgcn_mfma_f32_16x16x32_bf16(af[i], bfv[j], acc[i][j], 0, 0, 0);
    }

    #pragma unroll
    for (int i = 0; i < 4; ++i){
        const int gmb = m0 + w*64 + i*16 + quad*4;
        #pragma unroll
        for (int j = 0; j < 4; ++j){
            const int gn = j*16 + col;
            if (gn < N){
                #pragma unroll
                for (int r = 0; r < 4; ++r)
                    C[(size_t)(gmb + r)*64 + gn] = acc[i][j][r];
            }
        }
    }
}

// ---------------------------------------------------------------------------
// Depthwise causal conv + bias + silu, in place on the x-half of xz;
// also emits a bf16 copy (for the x-proj MFMA).
// ---------------------------------------------------------------------------
template<int DC, bool REV>
__global__ __launch_bounds__(256) void conv_silu_kernel(
    float* __restrict__ xz, const float* __restrict__ cw, const float* __restrict__ cb,
    bf16_t* __restrict__ xbf)            // (Bc*L, 1024) bf16
{
    const int gid = blockIdx.x*256 + threadIdx.x;   // Bc*DI threads
    const int b = gid >> 10, d = gid & 1023;
    float w[DC];
    #pragma unroll
    for (int k = 0; k < DC; ++k) w[k] = cw[d*DC + k];
    const float bias = cb[d];
    float hist[DC-1];
    #pragma unroll
    for (int k = 0; k < DC-1; ++k) hist[k] = 0.f;
    float* base = xz + (size_t)b*SEQ*2048 + d;
    bf16_t* bbase = xbf + (size_t)b*SEQ*1024 + d;
    for (int tt = 0; tt < SEQ; ++tt){
        const int l = REV ? (SEQ-1-tt) : tt;
        float cur = base[(size_t)l*2048];
        float a = bias + w[DC-1]*cur;
        #pragma unroll
        for (int j = 1; j < DC; ++j) a += w[DC-1-j]*hist[j-1];
        #pragma unroll
        for (int j = DC-2; j >= 1; --j) hist[j] = hist[j-1];
        hist[0] = cur;
        float s = siluf_(a);
        base[(size_t)l*2048] = s;
        bbase[(size_t)l*1024] = (bf16_t)s;
    }
}

// ---------------------------------------------------------------------------
// Selective scan fused with dt projection; writes y as bf16 to ybf (M,1024).
// ybf may alias xbf (xbf is dead once x-proj has run).
// ---------------------------------------------------------------------------
template<int DS, bool REV>
__global__ __launch_bounds__(256) void scan_kernel(
    const float* __restrict__ xz,        // (Bc*L, 2048): x [0,1024), z [1024,2048)
    const float* __restrict__ xdb,       // (Bc*L, 64): [0:32]=dt_in, [32:+DS]=B, [32+DS:+DS]=C
    const float* __restrict__ dt_w,      // (1024, 32)
    const float* __restrict__ dt_b,      // (1024)
    const float* __restrict__ Alog,      // (1024, DS)
    const float* __restrict__ Dp,        // (1024)
    bf16_t* __restrict__ ybf)            // (Bc*L, 1024) bf16
{
    const int b = blockIdx.x >> 2;
    const int d = ((blockIdx.x & 3) << 8) + threadIdx.x;
    float w[32];
    #pragma unroll
    for (int r = 0; r < 32; ++r) w[r] = dt_w[d*32 + r];
    const float dtb = dt_b[d];
    const float Dd = Dp[d];
    float Av[DS], h[DS];
    #pragma unroll
    for (int s = 0; s < DS; ++s){ Av[s] = -__expf(Alog[d*DS + s]); h[s] = 0.f; }
    __shared__ float sx[64];
    const float* xbase = xz + (size_t)b*SEQ*2048;
    const float* xdbase = xdb + (size_t)b*SEQ*64;
    bf16_t* ybase = ybf + (size_t)b*SEQ*1024;
    for (int tt = 0; tt < SEQ; ++tt){
        const int l = REV ? (SEQ-1-tt) : tt;
        __syncthreads();
        if (threadIdx.x < 32 + 2*DS) sx[threadIdx.x] = xdbase[l*64 + threadIdx.x];
        __syncthreads();
        float dacc = dtb;
        #pragma unroll
        for (int r = 0; r < 32; ++r) dacc += w[r]*sx[r];
        const float dtv = softplusf_(dacc);
        const float xv = xbase[(size_t)l*2048 + d];
        const float zv = xbase[(size_t)l*2048 + 1024 + d];
        const float dtx = dtv * xv;
        float yv = 0.f;
        #pragma unroll
        for (int s = 0; s < DS; ++s){
            h[s] = __expf(dtv*Av[s])*h[s] + dtx*sx[32+s];
            yv += h[s]*sx[32+DS+s];
        }
        yv += xv*Dd;
        yv *= siluf_(zv);
        ybase[(size_t)l*1024 + d] = (bf16_t)yv;
    }
}

// ---------------------------------------------------------------------------
// Head: max-pool over L, LayerNorm(512), fc1(512->128)+relu, fc2(128->4)
// ---------------------------------------------------------------------------
__global__ __launch_bounds__(256) void head_kernel(
    const float* __restrict__ acc,   // (Bc, L, 512)
    const float* __restrict__ ng, const float* __restrict__ nb,
    const float* __restrict__ w1, const float* __restrict__ b1,
    const float* __restrict__ w2, const float* __restrict__ b2,
    float* __restrict__ out)         // (Bc, 4) chunk base
{
    const int b = blockIdx.x, t = threadIdx.x;
    __shared__ float sp[512];
    __shared__ float sh[128];
    __shared__ float red1[4], red2[4];
    const float* base = acc + (size_t)b*SEQ*512;
    for (int o = t; o < 512; o += 256){
        float m = -3.4e38f;
        for (int l = 0; l < SEQ; ++l) m = fmaxf(m, base[(size_t)l*512 + o]);
        sp[o] = m;
    }
    __syncthreads();
    float s1 = 0.f, s2 = 0.f;
    for (int o = t; o < 512; o += 256){ float v = sp[o]; s1 += v; s2 += v*v; }
    #pragma unroll
    for (int off = 32; off > 0; off >>= 1){ s1 += __shfl_xor(s1, off); s2 += __shfl_xor(s2, off); }
    const int wv = t >> 6, lane = t & 63;
    if (lane == 0){ red1[wv] = s1; red2[wv] = s2; }
    __syncthreads();
    if (t == 0){
        float a = 0.f, c = 0.f;
        for (int i = 0; i < 4; ++i){ a += red1[i]; c += red2[i]; }
        float mean = a * (1.f/512.f);
        float var = c * (1.f/512.f) - mean*mean;
        red1[0] = mean; red2[0] = rsqrtf(var + 1e-5f);
    }
    __syncthreads();
    const float mean = red1[0], rstd = red2[0];
    for (int o = t; o < 512; o += 256) sp[o] = (sp[o]-mean)*rstd*ng[o] + nb[o];
    __syncthreads();
    if (t < 128){
        float a = b1[t];
        for (int o = 0; o < 512; ++o) a += sp[o]*w1[t*512 + o];
        sh[t] = fmaxf(a, 0.f);
    }
    __syncthreads();
    if (t < 4){
        float a = b2[t];
        for (int j = 0; j < 128; ++j) a += sh[j]*w2[t*128 + j];
        out[b*4 + t] = a;
    }
}

// ---------------------------------------------------------------------------
extern "C" void kernel_launch(void* const* d_in, const int* in_sizes, int n_in,
                              void* d_out, int out_size, void* d_ws, size_t ws_size,
                              hipStream_t stream)
{
    (void)in_sizes; (void)n_in; (void)out_size;
    const float* x        = (const float*)d_in[0];
    const float* fe_w     = (const float*)d_in[1];
    const float* fe_b     = (const float*)d_in[2];
    const float* fe_ln_g  = (const float*)d_in[3];
    const float* fe_ln_b  = (const float*)d_in[4];
    const float* emb_ln_g = (const float*)d_in[5];
    const float* emb_ln_b = (const float*)d_in[6];
    const float* conv1_w  = (const float*)d_in[7];
    const float* conv1_b  = (const float*)d_in[8];
    const float* conv2_w  = (const float*)d_in[9];
    const float* conv2_b  = (const float*)d_in[10];
    const float* mf_in_w  = (const float*)d_in[11];
    const float* mf_conv_w= (const float*)d_in[12];
    const float* mf_conv_b= (const float*)d_in[13];
    const float* mf_xproj = (const float*)d_in[14];
    const float* mf_dt_w  = (const float*)d_in[15];
    const float* mf_dt_b  = (const float*)d_in[16];
    const float* mf_Alog  = (const float*)d_in[17];
    const float* mf_D     = (const float*)d_in[18];
    const float* mf_out_w = (const float*)d_in[19];
    const float* mb_in_w  = (const float*)d_in[20];
    const float* mb_conv_w= (const float*)d_in[21];
    const float* mb_conv_b= (const float*)d_in[22];
    const float* mb_xproj = (const float*)d_in[23];
    const float* mb_dt_w  = (const float*)d_in[24];
    const float* mb_dt_b  = (const float*)d_in[25];
    const float* mb_Alog  = (const float*)d_in[26];
    const float* mb_D     = (const float*)d_in[27];
    const float* mb_out_w = (const float*)d_in[28];
    const float* norm_g   = (const float*)d_in[29];
    const float* norm_b   = (const float*)d_in[30];
    const float* fc1_w    = (const float*)d_in[31];
    const float* fc1_b    = (const float*)d_in[32];
    const float* fc2_w    = (const float*)d_in[33];
    const float* fc2_b    = (const float*)d_in[34];
    float* out = (float*)d_out;

    // ---- fixed workspace region: bf16 weights + all-batch comb ----
    char* p = (char*)d_ws;
    bf16_t* w_inf  = (bf16_t*)p; p += (size_t)2048*512*sizeof(bf16_t);
    bf16_t* w_inb  = (bf16_t*)p; p += (size_t)2048*512*sizeof(bf16_t);
    bf16_t* w_outf = (bf16_t*)p; p += (size_t)512*1024*sizeof(bf16_t);
    bf16_t* w_outb = (bf16_t*)p; p += (size_t)512*1024*sizeof(bf16_t);
    bf16_t* w_xpf  = (bf16_t*)p; p += (size_t)64*1024*sizeof(bf16_t);
    bf16_t* w_xpb  = (bf16_t*)p; p += (size_t)48*1024*sizeof(bf16_t);
    bf16_t* comb_all = (bf16_t*)p; p += (size_t)BSZ*SEQ*512*sizeof(bf16_t);
    const size_t fixed_bytes = (size_t)(p - (char*)d_ws);

    // ---- chunk region: xz f32 (M,2048) + ybf/xbf bf16 (M,1024) + xdb f32 (M,64)
    //      + acc f32 (M,512). per-batch = 1,254,400 B.
    const size_t per_b = (size_t)SEQ * (2048*4 + 1024*2 + 64*4 + 512*4);
    const size_t budget = (ws_size > fixed_bytes) ? (ws_size - fixed_bytes) : 0;
    int Bc = BSZ;
    while (Bc > 64 && (size_t)Bc * per_b > budget) Bc >>= 1;   // Bc in {512,256,128,64}; M%256==0
    const int nch = BSZ / Bc;
    const int M = Bc * SEQ;

    float*  xz   = (float*)p;                p += (size_t)M*2048*sizeof(float);
    bf16_t* ybf  = (bf16_t*)p;               p += (size_t)M*1024*sizeof(bf16_t);
    float*  xdb  = (float*)p;                p += (size_t)M*64*sizeof(float);
    float*  accb = (float*)p;

    // ---- weight conversions (once per call) ----
    cvt_bf16_kernel<<<(2048*512+255)/256, 256, 0, stream>>>(mf_in_w,  w_inf,  2048*512);
    cvt_bf16_kernel<<<(2048*512+255)/256, 256, 0, stream>>>(mb_in_w,  w_inb,  2048*512);
    cvt_bf16_kernel<<<(512*1024+255)/256, 256, 0, stream>>>(mf_out_w, w_outf, 512*1024);
    cvt_bf16_kernel<<<(512*1024+255)/256, 256, 0, stream>>>(mb_out_w, w_outb, 512*1024);
    cvt_bf16_kernel<<<(64*1024+255)/256,  256, 0, stream>>>(mf_xproj, w_xpf,  64*1024);
    cvt_bf16_kernel<<<(48*1024+255)/256,  256, 0, stream>>>(mb_xproj, w_xpb,  48*1024);

    // ---- front-end once over all batches ----
    frontend_kernel<<<BSZ, 256, 0, stream>>>(x, fe_w, fe_b,
        fe_ln_g, fe_ln_b, emb_ln_g, emb_ln_b, conv1_w, conv1_b, conv2_w, conv2_b, comb_all);

    const int gm128 = M / 128;
    const int gm256 = M / 256;

    for (int c = 0; c < nch; ++c){
        const size_t b0 = (size_t)c * Bc;
        const bf16_t* comb = comb_all + b0*SEQ*512;

        // ---- forward mamba (d_state=16, d_conv=4) ----
        gemm_bf16_kernel<<<dim3(gm128, 16), 256, 0, stream>>>(comb, 512, M, w_inf, 512, 2048, xz, 2048, 0);
        conv_silu_kernel<4, false><<<Bc*DI/256, 256, 0, stream>>>(xz, mf_conv_w, mf_conv_b, ybf);
        gemm_bf16_n64_kernel<<<gm256, 256, 0, stream>>>(ybf, w_xpf, 1024, 64, xdb);
        scan_kernel<16, false><<<Bc*4, 256, 0, stream>>>(xz, xdb, mf_dt_w, mf_dt_b, mf_Alog, mf_D, ybf);
        gemm_bf16_kernel<<<dim3(gm128, 4), 256, 0, stream>>>(ybf, 1024, M, w_outf, 1024, 512, accb, 512, 0);

        // ---- backward mamba (d_state=8, d_conv=2), time-reversed in place ----
        gemm_bf16_kernel<<<dim3(gm128, 16), 256, 0, stream>>>(comb, 512, M, w_inb, 512, 2048, xz, 2048, 0);
        conv_silu_kernel<2, true><<<Bc*DI/256, 256, 0, stream>>>(xz, mb_conv_w, mb_conv_b, ybf);
        gemm_bf16_n64_kernel<<<gm256, 256, 0, stream>>>(ybf, w_xpb, 1024, 48, xdb);
        scan_kernel<8, true><<<Bc*4, 256, 0, stream>>>(xz, xdb, mb_dt_w, mb_dt_b, mb_Alog, mb_D, ybf);
        gemm_bf16_kernel<<<dim3(gm128, 4), 256, 0, stream>>>(ybf, 1024, M, w_outb, 1024, 512, accb, 512, 1);

        head_kernel<<<Bc, 256, 0, stream>>>(accb, norm_g, norm_b, fc1_w, fc1_b, fc2_w, fc2_b,
                                            out + b0*4);
    }
}

// Round 5
// 2654.848 us; speedup vs baseline: 2.5245x; 1.0615x over previous
//
#include <hip/hip_runtime.h>
#include <cstddef>
#include <cstdint>

#define BSZ 512
#define SEQ 100
#define DI 1024

typedef __bf16 bf16_t;
typedef __attribute__((ext_vector_type(8))) __bf16 bf16x8;
typedef __attribute__((ext_vector_type(4))) float f32x4;

__device__ __forceinline__ float sigmoidf_(float v){ return 1.f/(1.f + __expf(-v)); }
__device__ __forceinline__ float siluf_(float v){ return v * sigmoidf_(v); }
__device__ __forceinline__ float softplusf_(float v){ return (v > 20.f) ? v : log1pf(__expf(v)); }

// ---------------------------------------------------------------------------
// fp32 -> bf16 converter (weights), once per call
// ---------------------------------------------------------------------------
__global__ __launch_bounds__(256) void cvt_bf16_kernel(
    const float* __restrict__ src, bf16_t* __restrict__ dst, int n)
{
    int i = blockIdx.x*256 + threadIdx.x;
    if (i < n) dst[i] = (bf16_t)src[i];
}

// ---------------------------------------------------------------------------
// Front-end (ALL batches, once): id-embed (2 LN) -> comb[...,0:256] (bf16)
//   conv1(22->128,k3,p1)+relu -> conv2(128->256,k3,p1)+relu -> comb[...,256:512]
// Grid (512, 2): y-block splits conv2 output channels; f1 recomputed by both
// (1.7 GF total, cheap). Phase A (id-embed) runs in y==0 only.
// ---------------------------------------------------------------------------
__global__ __launch_bounds__(256) void frontend_kernel(
    const float* __restrict__ x,                     // (512, 100, 23)
    const float* __restrict__ fe_w, const float* __restrict__ fe_b,
    const float* __restrict__ g1, const float* __restrict__ b1,
    const float* __restrict__ g2, const float* __restrict__ b2,
    const float* __restrict__ c1w, const float* __restrict__ c1b,   // (128,22,3),(128)
    const float* __restrict__ c2w, const float* __restrict__ c2b,   // (256,128,3),(256)
    bf16_t* __restrict__ comb)                       // (512, 100, 512) bf16
{
    const int b = blockIdx.x;
    const int half_o = blockIdx.y;                   // 0 or 1: conv2 channel half
    const int t = threadIdx.x;
    const int wv = t >> 6, lane = t & 63;

    // ---- phase A: id embedding (y==0 blocks only) ----
    if (half_o == 0){
        float few[4], feb[4], lg1[4], lb1[4], lg2[4], lb2[4];
        #pragma unroll
        for (int q = 0; q < 4; ++q){
            int j = lane + 64*q;
            few[q] = fe_w[j]; feb[q] = fe_b[j];
            lg1[q] = g1[j];  lb1[q] = b1[j];
            lg2[q] = g2[j];  lb2[q] = b2[j];
        }
        for (int l = wv; l < SEQ; l += 4){
            float m = fabsf(x[(size_t)(b*SEQ + l)*23]);
            float e[4];
            float s1 = 0.f, s2 = 0.f;
            #pragma unroll
            for (int q = 0; q < 4; ++q){ e[q] = m*few[q] + feb[q]; s1 += e[q]; s2 += e[q]*e[q]; }
            #pragma unroll
            for (int off = 32; off > 0; off >>= 1){ s1 += __shfl_xor(s1, off); s2 += __shfl_xor(s2, off); }
            float mean = s1 * (1.f/256.f);
            float rstd = rsqrtf(s2*(1.f/256.f) - mean*mean + 1e-5f);
            s1 = 0.f; s2 = 0.f;
            #pragma unroll
            for (int q = 0; q < 4; ++q){
                e[q] = fmaxf((e[q]-mean)*rstd*lg1[q] + lb1[q], 0.f);
                s1 += e[q]; s2 += e[q]*e[q];
            }
            #pragma unroll
            for (int off = 32; off > 0; off >>= 1){ s1 += __shfl_xor(s1, off); s2 += __shfl_xor(s2, off); }
            mean = s1 * (1.f/256.f);
            rstd = rsqrtf(s2*(1.f/256.f) - mean*mean + 1e-5f);
            #pragma unroll
            for (int q = 0; q < 4; ++q){
                float v = fmaxf((e[q]-mean)*rstd*lg2[q] + lb2[q], 0.f);
                comb[(size_t)(b*SEQ + l)*512 + lane + 64*q] = (bf16_t)v;
            }
        }
    }

    // ---- phase B: conv stack ----
    __shared__ float sdata[22*104];   // data with +1 zero-pad offset in l
    __shared__ float sf1[128*104];    // f1 with +1 zero-pad offset in l
    for (int idx = t; idx < 22*SEQ; idx += 256){
        int c = idx / SEQ, l = idx - c*SEQ;
        sdata[c*104 + l + 1] = x[(size_t)(b*SEQ + l)*23 + 1 + c];
    }
    if (t < 22){ sdata[t*104 + 0] = 0.f; sdata[t*104 + 101] = 0.f; }
    __syncthreads();

    {   // f1: 128 channels x 100, each thread one channel-half
        int o = t >> 1, half = t & 1;
        int lbase = half * 50;
        for (int lc = 0; lc < 50; lc += 10){
            int lofs = lbase + lc;
            float a[10];
            float bia = c1b[o];
            #pragma unroll
            for (int i = 0; i < 10; ++i) a[i] = bia;
            for (int c = 0; c < 22; ++c){
                float w0 = c1w[(o*22 + c)*3 + 0];
                float w1 = c1w[(o*22 + c)*3 + 1];
                float w2 = c1w[(o*22 + c)*3 + 2];
                float s0 = sdata[c*104 + lofs];
                float sc = sdata[c*104 + lofs + 1];
                #pragma unroll
                for (int i = 0; i < 10; ++i){
                    float sn = sdata[c*104 + lofs + i + 2];
                    a[i] += w0*s0 + w1*sc + w2*sn;
                    s0 = sc; sc = sn;
                }
            }
            #pragma unroll
            for (int i = 0; i < 10; ++i) sf1[o*104 + lofs + i + 1] = fmaxf(a[i], 0.f);
        }
        if (t < 128){ sf1[t*104 + 0] = 0.f; sf1[t*104 + 101] = 0.f; }
    }
    __syncthreads();

    {   // f2: this block covers output channels [half_o*128, half_o*128+128)
        int o128 = t >> 1, half = t & 1;
        int o = half_o*128 + o128;
        int lbase = half * 50;
        for (int lc = 0; lc < 50; lc += 10){
            int lofs = lbase + lc;
            float a[10];
            float bia = c2b[o];
            #pragma unroll
            for (int i = 0; i < 10; ++i) a[i] = bia;
            for (int c = 0; c < 128; ++c){
                float w0 = c2w[(o*128 + c)*3 + 0];
                float w1 = c2w[(o*128 + c)*3 + 1];
                float w2 = c2w[(o*128 + c)*3 + 2];
                float s0 = sf1[c*104 + lofs];
                float sc = sf1[c*104 + lofs + 1];
                #pragma unroll
                for (int i = 0; i < 10; ++i){
                    float sn = sf1[c*104 + lofs + i + 2];
                    a[i] += w0*s0 + w1*sc + w2*sn;
                    s0 = sc; sc = sn;
                }
            }
            #pragma unroll
            for (int i = 0; i < 10; ++i)
                comb[(size_t)(b*SEQ + lofs + i)*512 + 256 + o] = (bf16_t)fmaxf(a[i], 0.f);
        }
    }
}

// ---------------------------------------------------------------------------
// bf16 MFMA GEMM: C[m,n] (+)= sum_k A[m,k]*W[n,k], fp32 accumulate.
// 128x128 tile, BK=32, 4 waves, each 64x64 via 4x4 mfma_f32_16x16x32_bf16.
// global_load_lds 16B staging with XOR-swizzled k-chunks (no LDS padding).
// ---------------------------------------------------------------------------
__global__ __launch_bounds__(256) void gemm_bf16_kernel(
    const bf16_t* __restrict__ A, int lda, int Mtot,
    const bf16_t* __restrict__ W, int K, int N,
    float* __restrict__ C, int ldc, int accumulate)
{
    __shared__ bf16_t As[128*32];
    __shared__ bf16_t Ws[128*32];
    const int t = threadIdx.x;
    const int lane = t & 63, w = t >> 6;
    const int m0 = blockIdx.x * 128, n0 = blockIdx.y * 128;
    const int rsub = lane >> 2, csub = lane & 3;
    const int col = lane & 15, quad = lane >> 4;
    const int wOffM = (w & 1) * 64, wOffN = (w >> 1) * 64;

    f32x4 acc[4][4];
    #pragma unroll
    for (int i = 0; i < 4; ++i)
        #pragma unroll
        for (int j = 0; j < 4; ++j)
            acc[i][j] = (f32x4){0.f, 0.f, 0.f, 0.f};

    for (int k0 = 0; k0 < K; k0 += 32){
        __syncthreads();
        #pragma unroll
        for (int q = 0; q < 2; ++q){
            const int rt = w*32 + q*16 + rsub;
            const int lq = csub ^ ((rt >> 1) & 3);
            int ra = m0 + rt; ra = (ra < Mtot) ? ra : (Mtot - 1);
            const bf16_t* ga = A + (size_t)ra*lda + k0 + lq*8;
            __builtin_amdgcn_global_load_lds(
                (const __attribute__((address_space(1))) void*)ga,
                (__attribute__((address_space(3))) void*)&As[(w*32 + q*16)*32], 16, 0, 0);
            const bf16_t* gw = W + (size_t)(n0 + rt)*K + k0 + lq*8;
            __builtin_amdgcn_global_load_lds(
                (const __attribute__((address_space(1))) void*)gw,
                (__attribute__((address_space(3))) void*)&Ws[(w*32 + q*16)*32], 16, 0, 0);
        }
        __syncthreads();

        bf16x8 af[4], bfv[4];
        #pragma unroll
        for (int i = 0; i < 4; ++i){
            const int ra = wOffM + i*16 + col;
            af[i]  = *(const bf16x8*)&As[ra*32 + (quad ^ ((ra >> 1) & 3))*8];
            const int rb = wOffN + i*16 + col;
            bfv[i] = *(const bf16x8*)&Ws[rb*32 + (quad ^ ((rb >> 1) & 3))*8];
        }
        #pragma unroll
        for (int i = 0; i < 4; ++i)
            #pragma unroll
            for (int j = 0; j < 4; ++j)
                acc[i][j] = __builtin_amdgcn_mfma_f32_16x16x32_bf16(af[i], bfv[j], acc[i][j], 0, 0, 0);
    }

    // C/D layout: col=lane&15, row=(lane>>4)*4+reg  [m89-verified]
    #pragma unroll
    for (int i = 0; i < 4; ++i){
        const int gmb = m0 + wOffM + i*16 + quad*4;
        #pragma unroll
        for (int j = 0; j < 4; ++j){
            const int gn = n0 + wOffN + j*16 + col;
            #pragma unroll
            for (int r = 0; r < 4; ++r){
                const int gm = gmb + r;
                if (gm < Mtot){
                    float v = acc[i][j][r];
                    size_t off = (size_t)gm*ldc + gn;
                    if (accumulate) v += C[off];
                    C[off] = v;
                }
            }
        }
    }
}

// ---------------------------------------------------------------------------
// bf16 MFMA GEMM, narrow-N (x-proj): C[m,n] = sum_k A[m,k]*W[n,k], N<=64.
// 256x64 tile, BK=32, 4 waves. Requires M%256==0, K%32==0.
// ---------------------------------------------------------------------------
__global__ __launch_bounds__(256) void gemm_bf16_n64_kernel(
    const bf16_t* __restrict__ A, const bf16_t* __restrict__ W,
    int K, int N, float* __restrict__ C)
{
    __shared__ bf16_t As[256*32];
    __shared__ bf16_t Ws[64*32];
    const int t = threadIdx.x;
    const int lane = t & 63, w = t >> 6;
    const int m0 = blockIdx.x * 256;
    const int rsub = lane >> 2, csub = lane & 3;
    const int col = lane & 15, quad = lane >> 4;

    f32x4 acc[4][4];
    #pragma unroll
    for (int i = 0; i < 4; ++i)
        #pragma unroll
        for (int j = 0; j < 4; ++j)
            acc[i][j] = (f32x4){0.f, 0.f, 0.f, 0.f};

    for (int k0 = 0; k0 < K; k0 += 32){
        __syncthreads();
        #pragma unroll
        for (int q = 0; q < 4; ++q){
            const int rt = q*64 + w*16 + rsub;
            const int lq = csub ^ ((rt >> 1) & 3);
            const bf16_t* ga = A + (size_t)(m0 + rt)*K + k0 + lq*8;
            __builtin_amdgcn_global_load_lds(
                (const __attribute__((address_space(1))) void*)ga,
                (__attribute__((address_space(3))) void*)&As[(q*64 + w*16)*32], 16, 0, 0);
        }
        {
            const int rt = w*16 + rsub;
            const int lq = csub ^ ((rt >> 1) & 3);
            int rw = (rt < N) ? rt : (N - 1);
            const bf16_t* gw = W + (size_t)rw*K + k0 + lq*8;
            __builtin_amdgcn_global_load_lds(
                (const __attribute__((address_space(1))) void*)gw,
                (__attribute__((address_space(3))) void*)&Ws[(w*16)*32], 16, 0, 0);
        }
        __syncthreads();

        bf16x8 af[4], bfv[4];
        #pragma unroll
        for (int i = 0; i < 4; ++i){
            const int ra = w*64 + i*16 + col;
            af[i]  = *(const bf16x8*)&As[ra*32 + (quad ^ ((ra >> 1) & 3))*8];
            const int rb = i*16 + col;
            bfv[i] = *(const bf16x8*)&Ws[rb*32 + (quad ^ ((rb >> 1) & 3))*8];
        }
        #pragma unroll
        for (int i = 0; i < 4; ++i)
            #pragma unroll
            for (int j = 0; j < 4; ++j)
                acc[i][j] = __builtin_amdgcn_mfma_f32_16x16x32_bf16(af[i], bfv[j], acc[i][j], 0, 0, 0);
    }

    #pragma unroll
    for (int i = 0; i < 4; ++i){
        const int gmb = m0 + w*64 + i*16 + quad*4;
        #pragma unroll
        for (int j = 0; j < 4; ++j){
            const int gn = j*16 + col;
            if (gn < N){
                #pragma unroll
                for (int r = 0; r < 4; ++r)
                    C[(size_t)(gmb + r)*64 + gn] = acc[i][j][r];
            }
        }
    }
}

// ---------------------------------------------------------------------------
// Depthwise causal conv + bias + silu, in place on the x-half of xz, plus a
// bf16 copy. Batched: 10 independent loads -> compute -> 10 stores per block
// of timesteps (one vmcnt wait per 10 steps instead of per step).
// ---------------------------------------------------------------------------
template<int DC, bool REV>
__global__ __launch_bounds__(256) void conv_silu_kernel(
    float* __restrict__ xz, const float* __restrict__ cw, const float* __restrict__ cb,
    bf16_t* __restrict__ xbf)            // (Bc*L, 1024) bf16
{
    const int gid = blockIdx.x*256 + threadIdx.x;   // Bc*DI threads
    const int b = gid >> 10, d = gid & 1023;
    float w[DC];
    #pragma unroll
    for (int k = 0; k < DC; ++k) w[k] = cw[d*DC + k];
    const float bias = cb[d];
    float hist[DC-1];
    #pragma unroll
    for (int k = 0; k < DC-1; ++k) hist[k] = 0.f;
    float* base = xz + (size_t)b*SEQ*2048 + d;
    bf16_t* bbase = xbf + (size_t)b*SEQ*1024 + d;
    const int step = REV ? -1 : 1;
    int l = REV ? (SEQ-1) : 0;
    for (int t0 = 0; t0 < SEQ; t0 += 10){
        float v[10];
        #pragma unroll
        for (int i = 0; i < 10; ++i) v[i] = base[(size_t)(l + step*i)*2048];
        float o[10];
        #pragma unroll
        for (int i = 0; i < 10; ++i){
            float a = bias + w[DC-1]*v[i];
            #pragma unroll
            for (int j = 1; j < DC; ++j) a += w[DC-1-j]*hist[j-1];
            #pragma unroll
            for (int j = DC-2; j >= 1; --j) hist[j] = hist[j-1];
            hist[0] = v[i];
            o[i] = siluf_(a);
        }
        #pragma unroll
        for (int i = 0; i < 10; ++i){
            base[(size_t)(l + step*i)*2048] = o[i];
            bbase[(size_t)(l + step*i)*1024] = (bf16_t)o[i];
        }
        l += step*10;
    }
}

// ---------------------------------------------------------------------------
// Selective scan fused with dt projection. xdb slab for the whole batch
// (100x64 fp32 = 25.6 KB) is preloaded into LDS once -> no barriers in the
// time loop. x/z are software-pipelined with clamped next-step prefetch.
// Writes y as bf16 to ybf (may alias xbf; xbf dead after x-proj).
// ---------------------------------------------------------------------------
template<int DS, bool REV>
__global__ __launch_bounds__(256) void scan_kernel(
    const float* __restrict__ xz,        // (Bc*L, 2048): x [0,1024), z [1024,2048)
    const float* __restrict__ xdb,       // (Bc*L, 64): [0:32]=dt_in, [32:+DS]=B, [32+DS:+DS]=C
    const float* __restrict__ dt_w,      // (1024, 32)
    const float* __restrict__ dt_b,      // (1024)
    const float* __restrict__ Alog,      // (1024, DS)
    const float* __restrict__ Dp,        // (1024)
    bf16_t* __restrict__ ybf)            // (Bc*L, 1024) bf16
{
    const int b = blockIdx.x >> 2;
    const int d = ((blockIdx.x & 3) << 8) + threadIdx.x;

    __shared__ float sx[SEQ*64];         // 25.6 KB
    {   // cooperative slab load: 6400 floats = 1600 float4, fully coalesced
        const float4* src = (const float4*)(xdb + (size_t)b*SEQ*64);
        float4* dst = (float4*)sx;
        for (int i = threadIdx.x; i < SEQ*16; i += 256) dst[i] = src[i];
    }

    float w[32];
    #pragma unroll
    for (int r = 0; r < 32; ++r) w[r] = dt_w[d*32 + r];
    const float dtb = dt_b[d];
    const float Dd = Dp[d];
    float Av[DS], h[DS];
    #pragma unroll
    for (int s = 0; s < DS; ++s){ Av[s] = -__expf(Alog[d*DS + s]); h[s] = 0.f; }

    __syncthreads();                     // slab ready; no barriers after this

    const float* xbase = xz + (size_t)b*SEQ*2048 + d;
    bf16_t* ybase = ybf + (size_t)b*SEQ*1024 + d;
    const int step = REV ? -1 : 1;
    int l = REV ? (SEQ-1) : 0;

    float xv = xbase[(size_t)l*2048];
    float zv = xbase[(size_t)l*2048 + 1024];

    for (int tt = 0; tt < SEQ; ++tt){
        // prefetch next step's x/z (clamped; result discarded on last iter)
        int ln = l + step;
        ln = (ln < 0) ? 0 : ((ln > SEQ-1) ? (SEQ-1) : ln);
        const float xn = xbase[(size_t)ln*2048];
        const float zn = xbase[(size_t)ln*2048 + 1024];

        const float4* sxl4 = (const float4*)&sx[l*64];
        float dacc = dtb;
        #pragma unroll
        for (int r4 = 0; r4 < 8; ++r4){
            float4 v = sxl4[r4];
            dacc += w[r4*4+0]*v.x + w[r4*4+1]*v.y + w[r4*4+2]*v.z + w[r4*4+3]*v.w;
        }
        const float dtv = softplusf_(dacc);
        const float dtx = dtv * xv;
        float yv = 0.f;
        #pragma unroll
        for (int s4 = 0; s4 < DS/4; ++s4){
            float4 Bv = sxl4[8 + s4];
            float4 Cv = sxl4[8 + DS/4 + s4];
            h[s4*4+0] = __expf(dtv*Av[s4*4+0])*h[s4*4+0] + dtx*Bv.x;
            h[s4*4+1] = __expf(dtv*Av[s4*4+1])*h[s4*4+1] + dtx*Bv.y;
            h[s4*4+2] = __expf(dtv*Av[s4*4+2])*h[s4*4+2] + dtx*Bv.z;
            h[s4*4+3] = __expf(dtv*Av[s4*4+3])*h[s4*4+3] + dtx*Bv.w;
            yv += h[s4*4+0]*Cv.x + h[s4*4+1]*Cv.y + h[s4*4+2]*Cv.z + h[s4*4+3]*Cv.w;
        }
        yv += xv*Dd;
        yv *= siluf_(zv);
        ybase[(size_t)l*1024] = (bf16_t)yv;

        xv = xn; zv = zn; l += step;
    }
}

// ---------------------------------------------------------------------------
// Head: max-pool over L, LayerNorm(512), fc1(512->128)+relu, fc2(128->4)
// ---------------------------------------------------------------------------
__global__ __launch_bounds__(256) void head_kernel(
    const float* __restrict__ acc,   // (Bc, L, 512)
    const float* __restrict__ ng, const float* __restrict__ nb,
    const float* __restrict__ w1, const float* __restrict__ b1,
    const float* __restrict__ w2, const float* __restrict__ b2,
    float* __restrict__ out)         // (Bc, 4) chunk base
{
    const int b = blockIdx.x, t = threadIdx.x;
    __shared__ float sp[512];
    __shared__ float sh[128];
    __shared__ float red1[4], red2[4];
    const float* base = acc + (size_t)b*SEQ*512;
    for (int o = t; o < 512; o += 256){
        float m = -3.4e38f;
        for (int l = 0; l < SEQ; ++l) m = fmaxf(m, base[(size_t)l*512 + o]);
        sp[o] = m;
    }
    __syncthreads();
    float s1 = 0.f, s2 = 0.f;
    for (int o = t; o < 512; o += 256){ float v = sp[o]; s1 += v; s2 += v*v; }
    #pragma unroll
    for (int off = 32; off > 0; off >>= 1){ s1 += __shfl_xor(s1, off); s2 += __shfl_xor(s2, off); }
    const int wv = t >> 6, lane = t & 63;
    if (lane == 0){ red1[wv] = s1; red2[wv] = s2; }
    __syncthreads();
    if (t == 0){
        float a = 0.f, c = 0.f;
        for (int i = 0; i < 4; ++i){ a += red1[i]; c += red2[i]; }
        float mean = a * (1.f/512.f);
        float var = c * (1.f/512.f) - mean*mean;
        red1[0] = mean; red2[0] = rsqrtf(var + 1e-5f);
    }
    __syncthreads();
    const float mean = red1[0], rstd = red2[0];
    for (int o = t; o < 512; o += 256) sp[o] = (sp[o]-mean)*rstd*ng[o] + nb[o];
    __syncthreads();
    if (t < 128){
        float a = b1[t];
        for (int o = 0; o < 512; ++o) a += sp[o]*w1[t*512 + o];
        sh[t] = fmaxf(a, 0.f);
    }
    __syncthreads();
    if (t < 4){
        float a = b2[t];
        for (int j = 0; j < 128; ++j) a += sh[j]*w2[t*128 + j];
        out[b*4 + t] = a;
    }
}

// ---------------------------------------------------------------------------
extern "C" void kernel_launch(void* const* d_in, const int* in_sizes, int n_in,
                              void* d_out, int out_size, void* d_ws, size_t ws_size,
                              hipStream_t stream)
{
    (void)in_sizes; (void)n_in; (void)out_size;
    const float* x        = (const float*)d_in[0];
    const float* fe_w     = (const float*)d_in[1];
    const float* fe_b     = (const float*)d_in[2];
    const float* fe_ln_g  = (const float*)d_in[3];
    const float* fe_ln_b  = (const float*)d_in[4];
    const float* emb_ln_g = (const float*)d_in[5];
    const float* emb_ln_b = (const float*)d_in[6];
    const float* conv1_w  = (const float*)d_in[7];
    const float* conv1_b  = (const float*)d_in[8];
    const float* conv2_w  = (const float*)d_in[9];
    const float* conv2_b  = (const float*)d_in[10];
    const float* mf_in_w  = (const float*)d_in[11];
    const float* mf_conv_w= (const float*)d_in[12];
    const float* mf_conv_b= (const float*)d_in[13];
    const float* mf_xproj = (const float*)d_in[14];
    const float* mf_dt_w  = (const float*)d_in[15];
    const float* mf_dt_b  = (const float*)d_in[16];
    const float* mf_Alog  = (const float*)d_in[17];
    const float* mf_D     = (const float*)d_in[18];
    const float* mf_out_w = (const float*)d_in[19];
    const float* mb_in_w  = (const float*)d_in[20];
    const float* mb_conv_w= (const float*)d_in[21];
    const float* mb_conv_b= (const float*)d_in[22];
    const float* mb_xproj = (const float*)d_in[23];
    const float* mb_dt_w  = (const float*)d_in[24];
    const float* mb_dt_b  = (const float*)d_in[25];
    const float* mb_Alog  = (const float*)d_in[26];
    const float* mb_D     = (const float*)d_in[27];
    const float* mb_out_w = (const float*)d_in[28];
    const float* norm_g   = (const float*)d_in[29];
    const float* norm_b   = (const float*)d_in[30];
    const float* fc1_w    = (const float*)d_in[31];
    const float* fc1_b    = (const float*)d_in[32];
    const float* fc2_w    = (const float*)d_in[33];
    const float* fc2_b    = (const float*)d_in[34];
    float* out = (float*)d_out;

    // ---- fixed workspace region: bf16 weights + all-batch comb ----
    char* p = (char*)d_ws;
    bf16_t* w_inf  = (bf16_t*)p; p += (size_t)2048*512*sizeof(bf16_t);
    bf16_t* w_inb  = (bf16_t*)p; p += (size_t)2048*512*sizeof(bf16_t);
    bf16_t* w_outf = (bf16_t*)p; p += (size_t)512*1024*sizeof(bf16_t);
    bf16_t* w_outb = (bf16_t*)p; p += (size_t)512*1024*sizeof(bf16_t);
    bf16_t* w_xpf  = (bf16_t*)p; p += (size_t)64*1024*sizeof(bf16_t);
    bf16_t* w_xpb  = (bf16_t*)p; p += (size_t)48*1024*sizeof(bf16_t);
    bf16_t* comb_all = (bf16_t*)p; p += (size_t)BSZ*SEQ*512*sizeof(bf16_t);
    const size_t fixed_bytes = (size_t)(p - (char*)d_ws);

    // ---- chunk region: xz f32 (M,2048) + ybf/xbf bf16 (M,1024) + xdb f32 (M,64)
    //      + acc f32 (M,512). per-batch = 1,254,400 B.
    const size_t per_b = (size_t)SEQ * (2048*4 + 1024*2 + 64*4 + 512*4);
    const size_t budget = (ws_size > fixed_bytes) ? (ws_size - fixed_bytes) : 0;
    int Bc = BSZ;
    while (Bc > 64 && (size_t)Bc * per_b > budget) Bc >>= 1;   // Bc in {512,256,128,64}
    const int nch = BSZ / Bc;
    const int M = Bc * SEQ;

    float*  xz   = (float*)p;                p += (size_t)M*2048*sizeof(float);
    bf16_t* ybf  = (bf16_t*)p;               p += (size_t)M*1024*sizeof(bf16_t);
    float*  xdb  = (float*)p;                p += (size_t)M*64*sizeof(float);
    float*  accb = (float*)p;

    // ---- weight conversions (once per call) ----
    cvt_bf16_kernel<<<(2048*512+255)/256, 256, 0, stream>>>(mf_in_w,  w_inf,  2048*512);
    cvt_bf16_kernel<<<(2048*512+255)/256, 256, 0, stream>>>(mb_in_w,  w_inb,  2048*512);
    cvt_bf16_kernel<<<(512*1024+255)/256, 256, 0, stream>>>(mf_out_w, w_outf, 512*1024);
    cvt_bf16_kernel<<<(512*1024+255)/256, 256, 0, stream>>>(mb_out_w, w_outb, 512*1024);
    cvt_bf16_kernel<<<(64*1024+255)/256,  256, 0, stream>>>(mf_xproj, w_xpf,  64*1024);
    cvt_bf16_kernel<<<(48*1024+255)/256,  256, 0, stream>>>(mb_xproj, w_xpb,  48*1024);

    // ---- front-end once over all batches ----
    frontend_kernel<<<dim3(BSZ, 2), 256, 0, stream>>>(x, fe_w, fe_b,
        fe_ln_g, fe_ln_b, emb_ln_g, emb_ln_b, conv1_w, conv1_b, conv2_w, conv2_b, comb_all);

    const int gm128 = M / 128;
    const int gm256 = M / 256;

    for (int c = 0; c < nch; ++c){
        const size_t b0 = (size_t)c * Bc;
        const bf16_t* comb = comb_all + b0*SEQ*512;

        // ---- forward mamba (d_state=16, d_conv=4) ----
        gemm_bf16_kernel<<<dim3(gm128, 16), 256, 0, stream>>>(comb, 512, M, w_inf, 512, 2048, xz, 2048, 0);
        conv_silu_kernel<4, false><<<Bc*DI/256, 256, 0, stream>>>(xz, mf_conv_w, mf_conv_b, ybf);
        gemm_bf16_n64_kernel<<<gm256, 256, 0, stream>>>(ybf, w_xpf, 1024, 64, xdb);
        scan_kernel<16, false><<<Bc*4, 256, 0, stream>>>(xz, xdb, mf_dt_w, mf_dt_b, mf_Alog, mf_D, ybf);
        gemm_bf16_kernel<<<dim3(gm128, 4), 256, 0, stream>>>(ybf, 1024, M, w_outf, 1024, 512, accb, 512, 0);

        // ---- backward mamba (d_state=8, d_conv=2), time-reversed in place ----
        gemm_bf16_kernel<<<dim3(gm128, 16), 256, 0, stream>>>(comb, 512, M, w_inb, 512, 2048, xz, 2048, 0);
        conv_silu_kernel<2, true><<<Bc*DI/256, 256, 0, stream>>>(xz, mb_conv_w, mb_conv_b, ybf);
        gemm_bf16_n64_kernel<<<gm256, 256, 0, stream>>>(ybf, w_xpb, 1024, 48, xdb);
        scan_kernel<8, true><<<Bc*4, 256, 0, stream>>>(xz, xdb, mb_dt_w, mb_dt_b, mb_Alog, mb_D, ybf);
        gemm_bf16_kernel<<<dim3(gm128, 4), 256, 0, stream>>>(ybf, 1024, M, w_outb, 1024, 512, accb, 512, 1);

        head_kernel<<<Bc, 256, 0, stream>>>(accb, norm_g, norm_b, fc1_w, fc1_b, fc2_w, fc2_b,
                                            out + b0*4);
    }
}

// Round 6
// 2266.440 us; speedup vs baseline: 2.9571x; 1.1714x over previous
//
#include <hip/hip_runtime.h>
#include <cstddef>
#include <cstdint>

#define BSZ 512
#define SEQ 100
#define DI 1024

typedef __bf16 bf16_t;
typedef __attribute__((ext_vector_type(8))) __bf16 bf16x8;
typedef __attribute__((ext_vector_type(4))) float f32x4;

__device__ __forceinline__ float sigmoidf_(float v){ return 1.f/(1.f + __expf(-v)); }
__device__ __forceinline__ float siluf_(float v){ return v * sigmoidf_(v); }
__device__ __forceinline__ float softplusf_(float v){ return (v > 20.f) ? v : log1pf(__expf(v)); }

// ---------------------------------------------------------------------------
// fp32 -> bf16 converter (weights), once per call
// ---------------------------------------------------------------------------
__global__ __launch_bounds__(256) void cvt_bf16_kernel(
    const float* __restrict__ src, bf16_t* __restrict__ dst, int n)
{
    int i = blockIdx.x*256 + threadIdx.x;
    if (i < n) dst[i] = (bf16_t)src[i];
}

// ---------------------------------------------------------------------------
// Conv-weight rearrange for conv-as-GEMM:
//   W1p[o, k*32 + c]  = conv1_w[o, c, k]  (c<22, else 0)   o<128, K'=96
//   W2p[o, k*128 + c] = conv2_w[o, c, k]                   o<256, K'=384
// ---------------------------------------------------------------------------
__global__ __launch_bounds__(256) void prep_convw_kernel(
    const float* __restrict__ c1w, const float* __restrict__ c2w,
    bf16_t* __restrict__ W1p, bf16_t* __restrict__ W2p)
{
    int i = blockIdx.x*256 + threadIdx.x;
    if (i < 128*96){
        int o = i / 96, kk = i - o*96, k = kk >> 5, c = kk & 31;
        W1p[i] = (c < 22) ? (bf16_t)c1w[(o*22 + c)*3 + k] : (bf16_t)0.f;
    }
    if (i < 256*384){
        int o = i / 384, kk = i - o*384, k = kk >> 7, c = kk & 127;
        W2p[i] = (bf16_t)c2w[(o*128 + c)*3 + k];
    }
}

// ---------------------------------------------------------------------------
// FE0: id-embed (2 LayerNorms) -> comb[...,0:256] (bf16); build F0pad bf16
// [b,102,32] (rows 1..100 = x[...,1:23], rows 0/101 + cols 22..31 = 0);
// zero F1pad boundary rows 0,101. One block per batch element.
// ---------------------------------------------------------------------------
__global__ __launch_bounds__(256) void fe0_kernel(
    const float* __restrict__ x,                     // (512, 100, 23)
    const float* __restrict__ fe_w, const float* __restrict__ fe_b,
    const float* __restrict__ g1, const float* __restrict__ b1,
    const float* __restrict__ g2, const float* __restrict__ b2,
    bf16_t* __restrict__ comb,                       // (512, 100, 512) bf16
    bf16_t* __restrict__ F0pad,                      // (512, 102, 32) bf16
    bf16_t* __restrict__ F1pad)                      // (512, 102, 128) bf16
{
    const int b = blockIdx.x;
    const int t = threadIdx.x;
    const int wv = t >> 6, lane = t & 63;

    // ---- id embedding ----
    float few[4], feb[4], lg1[4], lb1[4], lg2[4], lb2[4];
    #pragma unroll
    for (int q = 0; q < 4; ++q){
        int j = lane + 64*q;
        few[q] = fe_w[j]; feb[q] = fe_b[j];
        lg1[q] = g1[j];  lb1[q] = b1[j];
        lg2[q] = g2[j];  lb2[q] = b2[j];
    }
    for (int l = wv; l < SEQ; l += 4){
        float m = fabsf(x[(size_t)(b*SEQ + l)*23]);
        float e[4];
        float s1 = 0.f, s2 = 0.f;
        #pragma unroll
        for (int q = 0; q < 4; ++q){ e[q] = m*few[q] + feb[q]; s1 += e[q]; s2 += e[q]*e[q]; }
        #pragma unroll
        for (int off = 32; off > 0; off >>= 1){ s1 += __shfl_xor(s1, off); s2 += __shfl_xor(s2, off); }
        float mean = s1 * (1.f/256.f);
        float rstd = rsqrtf(s2*(1.f/256.f) - mean*mean + 1e-5f);
        s1 = 0.f; s2 = 0.f;
        #pragma unroll
        for (int q = 0; q < 4; ++q){
            e[q] = fmaxf((e[q]-mean)*rstd*lg1[q] + lb1[q], 0.f);
            s1 += e[q]; s2 += e[q]*e[q];
        }
        #pragma unroll
        for (int off = 32; off > 0; off >>= 1){ s1 += __shfl_xor(s1, off); s2 += __shfl_xor(s2, off); }
        mean = s1 * (1.f/256.f);
        rstd = rsqrtf(s2*(1.f/256.f) - mean*mean + 1e-5f);
        #pragma unroll
        for (int q = 0; q < 4; ++q){
            float v = fmaxf((e[q]-mean)*rstd*lg2[q] + lb2[q], 0.f);
            comb[(size_t)(b*SEQ + l)*512 + lane + 64*q] = (bf16_t)v;
        }
    }

    // ---- F0pad build ----
    for (int idx = t; idx < 102*32; idx += 256){
        int r = idx >> 5, c = idx & 31;
        float v = 0.f;
        if (r >= 1 && r <= SEQ && c < 22) v = x[(size_t)(b*SEQ + r - 1)*23 + 1 + c];
        F0pad[(size_t)(b*102 + r)*32 + c] = (bf16_t)v;
    }
    // ---- F1pad boundary rows ----
    if (t < 128) F1pad[(size_t)(b*102 + 0)*128 + t] = (bf16_t)0.f;
    else F1pad[(size_t)(b*102 + 101)*128 + (t - 128)] = (bf16_t)0.f;
}

// ---------------------------------------------------------------------------
// Conv-as-GEMM (z-batched): C[m,n] = relu(sum_k A_z[m*lda + k]*W[n,k] + bias[n])
// A_z = Abase + z*Az; K spans lda-rows (im2col via contiguity). bf16 out.
// 128x128 tile, BK=32, XOR-swizzled global_load_lds staging.
// ---------------------------------------------------------------------------
__global__ __launch_bounds__(256) void gemm_conv_kernel(
    const bf16_t* __restrict__ Abase, int lda, int Az,
    const bf16_t* __restrict__ W, int K, int N,
    const float* __restrict__ bias,
    bf16_t* __restrict__ Cbase, int ldc, int Cb, int coff, int noff, int Mtot)
{
    __shared__ bf16_t As[128*32];
    __shared__ bf16_t Ws[128*32];
    const bf16_t* A = Abase + (size_t)blockIdx.z * Az;
    const int t = threadIdx.x;
    const int lane = t & 63, w = t >> 6;
    const int n0 = blockIdx.y * 128;
    const int rsub = lane >> 2, csub = lane & 3;
    const int col = lane & 15, quad = lane >> 4;
    const int wOffM = (w & 1) * 64, wOffN = (w >> 1) * 64;

    f32x4 acc[4][4];
    #pragma unroll
    for (int i = 0; i < 4; ++i)
        #pragma unroll
        for (int j = 0; j < 4; ++j)
            acc[i][j] = (f32x4){0.f, 0.f, 0.f, 0.f};

    for (int k0 = 0; k0 < K; k0 += 32){
        __syncthreads();
        #pragma unroll
        for (int q = 0; q < 2; ++q){
            const int rt = w*32 + q*16 + rsub;
            const int lq = csub ^ ((rt >> 1) & 3);
            int ra = (rt < Mtot) ? rt : (Mtot - 1);
            const bf16_t* ga = A + (size_t)ra*lda + k0 + lq*8;
            __builtin_amdgcn_global_load_lds(
                (const __attribute__((address_space(1))) void*)ga,
                (__attribute__((address_space(3))) void*)&As[(w*32 + q*16)*32], 16, 0, 0);
            const bf16_t* gw = W + (size_t)(n0 + rt)*K + k0 + lq*8;
            __builtin_amdgcn_global_load_lds(
                (const __attribute__((address_space(1))) void*)gw,
                (__attribute__((address_space(3))) void*)&Ws[(w*32 + q*16)*32], 16, 0, 0);
        }
        __syncthreads();

        bf16x8 af[4], bfv[4];
        #pragma unroll
        for (int i = 0; i < 4; ++i){
            const int ra = wOffM + i*16 + col;
            af[i]  = *(const bf16x8*)&As[ra*32 + (quad ^ ((ra >> 1) & 3))*8];
            const int rb = wOffN + i*16 + col;
            bfv[i] = *(const bf16x8*)&Ws[rb*32 + (quad ^ ((rb >> 1) & 3))*8];
        }
        #pragma unroll
        for (int i = 0; i < 4; ++i)
            #pragma unroll
            for (int j = 0; j < 4; ++j)
                acc[i][j] = __builtin_amdgcn_mfma_f32_16x16x32_bf16(af[i], bfv[j], acc[i][j], 0, 0, 0);
    }

    #pragma unroll
    for (int i = 0; i < 4; ++i){
        const int gmb = wOffM + i*16 + quad*4;
        #pragma unroll
        for (int j = 0; j < 4; ++j){
            const int gn = n0 + wOffN + j*16 + col;
            const float bb = bias[gn];
            #pragma unroll
            for (int r = 0; r < 4; ++r){
                const int gm = gmb + r;
                if (gm < Mtot){
                    float v = fmaxf(acc[i][j][r] + bb, 0.f);
                    Cbase[((size_t)blockIdx.z*Cb + coff + gm)*ldc + noff + gn] = (bf16_t)v;
                }
            }
        }
    }
}

// ---------------------------------------------------------------------------
// bf16 MFMA GEMM: C[m,n] (+)= sum_k A[m,k]*W[n,k], fp32 accumulate.
// 128x128 tile, BK=32, XOR-swizzled global_load_lds staging (no LDS padding).
// ---------------------------------------------------------------------------
__global__ __launch_bounds__(256) void gemm_bf16_kernel(
    const bf16_t* __restrict__ A, int lda, int Mtot,
    const bf16_t* __restrict__ W, int K, int N,
    float* __restrict__ C, int ldc, int accumulate)
{
    __shared__ bf16_t As[128*32];
    __shared__ bf16_t Ws[128*32];
    const int t = threadIdx.x;
    const int lane = t & 63, w = t >> 6;
    const int m0 = blockIdx.x * 128, n0 = blockIdx.y * 128;
    const int rsub = lane >> 2, csub = lane & 3;
    const int col = lane & 15, quad = lane >> 4;
    const int wOffM = (w & 1) * 64, wOffN = (w >> 1) * 64;

    f32x4 acc[4][4];
    #pragma unroll
    for (int i = 0; i < 4; ++i)
        #pragma unroll
        for (int j = 0; j < 4; ++j)
            acc[i][j] = (f32x4){0.f, 0.f, 0.f, 0.f};

    for (int k0 = 0; k0 < K; k0 += 32){
        __syncthreads();
        #pragma unroll
        for (int q = 0; q < 2; ++q){
            const int rt = w*32 + q*16 + rsub;
            const int lq = csub ^ ((rt >> 1) & 3);
            int ra = m0 + rt; ra = (ra < Mtot) ? ra : (Mtot - 1);
            const bf16_t* ga = A + (size_t)ra*lda + k0 + lq*8;
            __builtin_amdgcn_global_load_lds(
                (const __attribute__((address_space(1))) void*)ga,
                (__attribute__((address_space(3))) void*)&As[(w*32 + q*16)*32], 16, 0, 0);
            const bf16_t* gw = W + (size_t)(n0 + rt)*K + k0 + lq*8;
            __builtin_amdgcn_global_load_lds(
                (const __attribute__((address_space(1))) void*)gw,
                (__attribute__((address_space(3))) void*)&Ws[(w*32 + q*16)*32], 16, 0, 0);
        }
        __syncthreads();

        bf16x8 af[4], bfv[4];
        #pragma unroll
        for (int i = 0; i < 4; ++i){
            const int ra = wOffM + i*16 + col;
            af[i]  = *(const bf16x8*)&As[ra*32 + (quad ^ ((ra >> 1) & 3))*8];
            const int rb = wOffN + i*16 + col;
            bfv[i] = *(const bf16x8*)&Ws[rb*32 + (quad ^ ((rb >> 1) & 3))*8];
        }
        #pragma unroll
        for (int i = 0; i < 4; ++i)
            #pragma unroll
            for (int j = 0; j < 4; ++j)
                acc[i][j] = __builtin_amdgcn_mfma_f32_16x16x32_bf16(af[i], bfv[j], acc[i][j], 0, 0, 0);
    }

    #pragma unroll
    for (int i = 0; i < 4; ++i){
        const int gmb = m0 + wOffM + i*16 + quad*4;
        #pragma unroll
        for (int j = 0; j < 4; ++j){
            const int gn = n0 + wOffN + j*16 + col;
            #pragma unroll
            for (int r = 0; r < 4; ++r){
                const int gm = gmb + r;
                if (gm < Mtot){
                    float v = acc[i][j][r];
                    size_t off = (size_t)gm*ldc + gn;
                    if (accumulate) v += C[off];
                    C[off] = v;
                }
            }
        }
    }
}

// ---------------------------------------------------------------------------
// bf16 MFMA GEMM, x-proj: C[m,n] = sum_k A[m,k]*W[n,k], N<=64, ldc=64.
// 128x64 tile, BK=32, 4 waves; wave w covers rows w*32..w*32+31 (2x4 mfma).
// Requires M%128==0, K%32==0.
// ---------------------------------------------------------------------------
__global__ __launch_bounds__(256) void gemm_bf16_x_kernel(
    const bf16_t* __restrict__ A, const bf16_t* __restrict__ W,
    int K, int N, float* __restrict__ C)
{
    __shared__ bf16_t As[128*32];
    __shared__ bf16_t Ws[64*32];
    const int t = threadIdx.x;
    const int lane = t & 63, w = t >> 6;
    const int m0 = blockIdx.x * 128;
    const int rsub = lane >> 2, csub = lane & 3;
    const int col = lane & 15, quad = lane >> 4;

    f32x4 acc[2][4];
    #pragma unroll
    for (int i = 0; i < 2; ++i)
        #pragma unroll
        for (int j = 0; j < 4; ++j)
            acc[i][j] = (f32x4){0.f, 0.f, 0.f, 0.f};

    for (int k0 = 0; k0 < K; k0 += 32){
        __syncthreads();
        #pragma unroll
        for (int q = 0; q < 2; ++q){
            const int rt = q*64 + w*16 + rsub;
            const int lq = csub ^ ((rt >> 1) & 3);
            const bf16_t* ga = A + (size_t)(m0 + rt)*K + k0 + lq*8;
            __builtin_amdgcn_global_load_lds(
                (const __attribute__((address_space(1))) void*)ga,
                (__attribute__((address_space(3))) void*)&As[(q*64 + w*16)*32], 16, 0, 0);
        }
        {
            const int rt = w*16 + rsub;
            const int lq = csub ^ ((rt >> 1) & 3);
            int rw = (rt < N) ? rt : (N - 1);
            const bf16_t* gw = W + (size_t)rw*K + k0 + lq*8;
            __builtin_amdgcn_global_load_lds(
                (const __attribute__((address_space(1))) void*)gw,
                (__attribute__((address_space(3))) void*)&Ws[(w*16)*32], 16, 0, 0);
        }
        __syncthreads();

        bf16x8 af[2], bfv[4];
        #pragma unroll
        for (int i = 0; i < 2; ++i){
            const int ra = w*32 + i*16 + col;
            af[i]  = *(const bf16x8*)&As[ra*32 + (quad ^ ((ra >> 1) & 3))*8];
        }
        #pragma unroll
        for (int j = 0; j < 4; ++j){
            const int rb = j*16 + col;
            bfv[j] = *(const bf16x8*)&Ws[rb*32 + (quad ^ ((rb >> 1) & 3))*8];
        }
        #pragma unroll
        for (int i = 0; i < 2; ++i)
            #pragma unroll
            for (int j = 0; j < 4; ++j)
                acc[i][j] = __builtin_amdgcn_mfma_f32_16x16x32_bf16(af[i], bfv[j], acc[i][j], 0, 0, 0);
    }

    #pragma unroll
    for (int i = 0; i < 2; ++i){
        const int gmb = m0 + w*32 + i*16 + quad*4;
        #pragma unroll
        for (int j = 0; j < 4; ++j){
            const int gn = j*16 + col;
            if (gn < N){
                #pragma unroll
                for (int r = 0; r < 4; ++r)
                    C[(size_t)(gmb + r)*64 + gn] = acc[i][j][r];
            }
        }
    }
}

// ---------------------------------------------------------------------------
// Depthwise causal conv + bias + silu, in place on the x-half of xz, plus a
// bf16 copy. Batched 10 timesteps per load/compute/store group.
// ---------------------------------------------------------------------------
template<int DC, bool REV>
__global__ __launch_bounds__(256) void conv_silu_kernel(
    float* __restrict__ xz, const float* __restrict__ cw, const float* __restrict__ cb,
    bf16_t* __restrict__ xbf)            // (Bc*L, 1024) bf16
{
    const int gid = blockIdx.x*256 + threadIdx.x;   // Bc*DI threads
    const int b = gid >> 10, d = gid & 1023;
    float w[DC];
    #pragma unroll
    for (int k = 0; k < DC; ++k) w[k] = cw[d*DC + k];
    const float bias = cb[d];
    float hist[DC-1];
    #pragma unroll
    for (int k = 0; k < DC-1; ++k) hist[k] = 0.f;
    float* base = xz + (size_t)b*SEQ*2048 + d;
    bf16_t* bbase = xbf + (size_t)b*SEQ*1024 + d;
    const int step = REV ? -1 : 1;
    int l = REV ? (SEQ-1) : 0;
    for (int t0 = 0; t0 < SEQ; t0 += 10){
        float v[10];
        #pragma unroll
        for (int i = 0; i < 10; ++i) v[i] = base[(size_t)(l + step*i)*2048];
        float o[10];
        #pragma unroll
        for (int i = 0; i < 10; ++i){
            float a = bias + w[DC-1]*v[i];
            #pragma unroll
            for (int j = 1; j < DC; ++j) a += w[DC-1-j]*hist[j-1];
            #pragma unroll
            for (int j = DC-2; j >= 1; --j) hist[j] = hist[j-1];
            hist[0] = v[i];
            o[i] = siluf_(a);
        }
        #pragma unroll
        for (int i = 0; i < 10; ++i){
            base[(size_t)(l + step*i)*2048] = o[i];
            bbase[(size_t)(l + step*i)*1024] = (bf16_t)o[i];
        }
        l += step*10;
    }
}

// ---------------------------------------------------------------------------
// Selective scan fused with dt projection. xdb slab preloaded into LDS once;
// x/z loads batched 10 timesteps deep. Writes y as bf16 to ybf.
// ---------------------------------------------------------------------------
template<int DS, bool REV>
__global__ __launch_bounds__(256) void scan_kernel(
    const float* __restrict__ xz,        // (Bc*L, 2048): x [0,1024), z [1024,2048)
    const float* __restrict__ xdb,       // (Bc*L, 64)
    const float* __restrict__ dt_w,      // (1024, 32)
    const float* __restrict__ dt_b,      // (1024)
    const float* __restrict__ Alog,      // (1024, DS)
    const float* __restrict__ Dp,        // (1024)
    bf16_t* __restrict__ ybf)            // (Bc*L, 1024) bf16
{
    const int b = blockIdx.x >> 2;
    const int d = ((blockIdx.x & 3) << 8) + threadIdx.x;

    __shared__ float sx[SEQ*64];         // 25.6 KB
    {
        const float4* src = (const float4*)(xdb + (size_t)b*SEQ*64);
        float4* dst = (float4*)sx;
        for (int i = threadIdx.x; i < SEQ*16; i += 256) dst[i] = src[i];
    }

    float w[32];
    #pragma unroll
    for (int r = 0; r < 32; ++r) w[r] = dt_w[d*32 + r];
    const float dtb = dt_b[d];
    const float Dd = Dp[d];
    float Av[DS], h[DS];
    #pragma unroll
    for (int s = 0; s < DS; ++s){ Av[s] = -__expf(Alog[d*DS + s]); h[s] = 0.f; }

    __syncthreads();

    const float* xbase = xz + (size_t)b*SEQ*2048 + d;
    bf16_t* ybase = ybf + (size_t)b*SEQ*1024 + d;
    const int step = REV ? -1 : 1;
    int l = REV ? (SEQ-1) : 0;

    for (int t0 = 0; t0 < SEQ; t0 += 10){
        float xr[10], zr[10];
        #pragma unroll
        for (int i = 0; i < 10; ++i){
            const int li = l + step*i;
            xr[i] = xbase[(size_t)li*2048];
            zr[i] = xbase[(size_t)li*2048 + 1024];
        }
        #pragma unroll
        for (int i = 0; i < 10; ++i){
            const int li = l + step*i;
            const float4* sxl4 = (const float4*)&sx[li*64];
            float dacc = dtb;
            #pragma unroll
            for (int r4 = 0; r4 < 8; ++r4){
                float4 v = sxl4[r4];
                dacc += w[r4*4+0]*v.x + w[r4*4+1]*v.y + w[r4*4+2]*v.z + w[r4*4+3]*v.w;
            }
            const float dtv = softplusf_(dacc);
            const float dtx = dtv * xr[i];
            float yv = 0.f;
            #pragma unroll
            for (int s4 = 0; s4 < DS/4; ++s4){
                float4 Bv = sxl4[8 + s4];
                float4 Cv = sxl4[8 + DS/4 + s4];
                h[s4*4+0] = __expf(dtv*Av[s4*4+0])*h[s4*4+0] + dtx*Bv.x;
                h[s4*4+1] = __expf(dtv*Av[s4*4+1])*h[s4*4+1] + dtx*Bv.y;
                h[s4*4+2] = __expf(dtv*Av[s4*4+2])*h[s4*4+2] + dtx*Bv.z;
                h[s4*4+3] = __expf(dtv*Av[s4*4+3])*h[s4*4+3] + dtx*Bv.w;
                yv += h[s4*4+0]*Cv.x + h[s4*4+1]*Cv.y + h[s4*4+2]*Cv.z + h[s4*4+3]*Cv.w;
            }
            yv += xr[i]*Dd;
            yv *= siluf_(zr[i]);
            ybase[(size_t)li*1024] = (bf16_t)yv;
        }
        l += step*10;
    }
}

// ---------------------------------------------------------------------------
// Head: max-pool over L (float4 cols, L split over thread halves), LN(512),
// fc1(512->128, 2 threads/output, float4 w1), relu, fc2(128->4)
// ---------------------------------------------------------------------------
__global__ __launch_bounds__(256) void head_kernel(
    const float* __restrict__ acc,   // (Bc, L, 512)
    const float* __restrict__ ng, const float* __restrict__ nb,
    const float* __restrict__ w1, const float* __restrict__ b1,
    const float* __restrict__ w2, const float* __restrict__ b2,
    float* __restrict__ out)         // (Bc, 4) chunk base
{
    const int b = blockIdx.x, t = threadIdx.x;
    __shared__ float4 sm4[256];
    __shared__ float sp[512];
    __shared__ float sh2[256];
    __shared__ float sh[128];
    __shared__ float red1[4], red2[4];
    const float* base = acc + (size_t)b*SEQ*512;

    {   // pooling: 128 float4 columns x 2 L-halves
        const int c4 = t & 127, lh = t >> 7;
        float4 m = make_float4(-3.4e38f, -3.4e38f, -3.4e38f, -3.4e38f);
        for (int l = lh*50; l < lh*50 + 50; ++l){
            float4 v = ((const float4*)(base + (size_t)l*512))[c4];
            m.x = fmaxf(m.x, v.x); m.y = fmaxf(m.y, v.y);
            m.z = fmaxf(m.z, v.z); m.w = fmaxf(m.w, v.w);
        }
        sm4[t] = m;
    }
    __syncthreads();
    if (t < 128){
        float4 a = sm4[t], c = sm4[t + 128];
        ((float4*)sp)[t] = make_float4(fmaxf(a.x,c.x), fmaxf(a.y,c.y),
                                       fmaxf(a.z,c.z), fmaxf(a.w,c.w));
    }
    __syncthreads();

    float s1 = 0.f, s2 = 0.f;
    for (int o = t; o < 512; o += 256){ float v = sp[o]; s1 += v; s2 += v*v; }
    #pragma unroll
    for (int off = 32; off > 0; off >>= 1){ s1 += __shfl_xor(s1, off); s2 += __shfl_xor(s2, off); }
    const int wv = t >> 6, lane = t & 63;
    if (lane == 0){ red1[wv] = s1; red2[wv] = s2; }
    __syncthreads();
    if (t == 0){
        float a = 0.f, c = 0.f;
        for (int i = 0; i < 4; ++i){ a += red1[i]; c += red2[i]; }
        float mean = a * (1.f/512.f);
        float var = c * (1.f/512.f) - mean*mean;
        red1[0] = mean; red2[0] = rsqrtf(var + 1e-5f);
    }
    __syncthreads();
    const float mean = red1[0], rstd = red2[0];
    for (int o = t; o < 512; o += 256) sp[o] = (sp[o]-mean)*rstd*ng[o] + nb[o];
    __syncthreads();

    {   // fc1: output o = t&127, half = t>>7 sums 256 terms via 64 float4
        const int o = t & 127, half = t >> 7;
        const float4* wrow = (const float4*)(w1 + (size_t)o*512 + half*256);
        const float4* sp4 = (const float4*)sp + half*64;
        float s = 0.f;
        #pragma unroll 8
        for (int j = 0; j < 64; ++j){
            float4 a = sp4[j], wq = wrow[j];
            s += a.x*wq.x + a.y*wq.y + a.z*wq.z + a.w*wq.w;
        }
        sh2[t] = s;
    }
    __syncthreads();
    if (t < 128) sh[t] = fmaxf(sh2[t] + sh2[t + 128] + b1[t], 0.f);
    __syncthreads();
    if (t < 4){
        float a = b2[t];
        for (int j = 0; j < 128; ++j) a += sh[j]*w2[t*128 + j];
        out[b*4 + t] = a;
    }
}

// ---------------------------------------------------------------------------
extern "C" void kernel_launch(void* const* d_in, const int* in_sizes, int n_in,
                              void* d_out, int out_size, void* d_ws, size_t ws_size,
                              hipStream_t stream)
{
    (void)in_sizes; (void)n_in; (void)out_size;
    const float* x        = (const float*)d_in[0];
    const float* fe_w     = (const float*)d_in[1];
    const float* fe_b     = (const float*)d_in[2];
    const float* fe_ln_g  = (const float*)d_in[3];
    const float* fe_ln_b  = (const float*)d_in[4];
    const float* emb_ln_g = (const float*)d_in[5];
    const float* emb_ln_b = (const float*)d_in[6];
    const float* conv1_w  = (const float*)d_in[7];
    const float* conv1_b  = (const float*)d_in[8];
    const float* conv2_w  = (const float*)d_in[9];
    const float* conv2_b  = (const float*)d_in[10];
    const float* mf_in_w  = (const float*)d_in[11];
    const float* mf_conv_w= (const float*)d_in[12];
    const float* mf_conv_b= (const float*)d_in[13];
    const float* mf_xproj = (const float*)d_in[14];
    const float* mf_dt_w  = (const float*)d_in[15];
    const float* mf_dt_b  = (const float*)d_in[16];
    const float* mf_Alog  = (const float*)d_in[17];
    const float* mf_D     = (const float*)d_in[18];
    const float* mf_out_w = (const float*)d_in[19];
    const float* mb_in_w  = (const float*)d_in[20];
    const float* mb_conv_w= (const float*)d_in[21];
    const float* mb_conv_b= (const float*)d_in[22];
    const float* mb_xproj = (const float*)d_in[23];
    const float* mb_dt_w  = (const float*)d_in[24];
    const float* mb_dt_b  = (const float*)d_in[25];
    const float* mb_Alog  = (const float*)d_in[26];
    const float* mb_D     = (const float*)d_in[27];
    const float* mb_out_w = (const float*)d_in[28];
    const float* norm_g   = (const float*)d_in[29];
    const float* norm_b   = (const float*)d_in[30];
    const float* fc1_w    = (const float*)d_in[31];
    const float* fc1_b    = (const float*)d_in[32];
    const float* fc2_w    = (const float*)d_in[33];
    const float* fc2_b    = (const float*)d_in[34];
    float* out = (float*)d_out;

    // ---- fixed workspace region ----
    char* p = (char*)d_ws;
    bf16_t* w_inf  = (bf16_t*)p; p += (size_t)2048*512*sizeof(bf16_t);
    bf16_t* w_inb  = (bf16_t*)p; p += (size_t)2048*512*sizeof(bf16_t);
    bf16_t* w_outf = (bf16_t*)p; p += (size_t)512*1024*sizeof(bf16_t);
    bf16_t* w_outb = (bf16_t*)p; p += (size_t)512*1024*sizeof(bf16_t);
    bf16_t* w_xpf  = (bf16_t*)p; p += (size_t)64*1024*sizeof(bf16_t);
    bf16_t* w_xpb  = (bf16_t*)p; p += (size_t)48*1024*sizeof(bf16_t);
    bf16_t* W1p    = (bf16_t*)p; p += (size_t)128*96*sizeof(bf16_t);
    bf16_t* W2p    = (bf16_t*)p; p += (size_t)256*384*sizeof(bf16_t);
    bf16_t* F0pad  = (bf16_t*)p; p += (size_t)BSZ*102*32*sizeof(bf16_t);
    bf16_t* F1pad  = (bf16_t*)p; p += (size_t)BSZ*102*128*sizeof(bf16_t);
    bf16_t* comb_all = (bf16_t*)p; p += (size_t)BSZ*SEQ*512*sizeof(bf16_t);
    const size_t fixed_bytes = (size_t)(p - (char*)d_ws);

    // ---- chunk region ----
    const size_t per_b = (size_t)SEQ * (2048*4 + 1024*2 + 64*4 + 512*4);
    const size_t budget = (ws_size > fixed_bytes) ? (ws_size - fixed_bytes) : 0;
    int Bc = BSZ;
    while (Bc > 64 && (size_t)Bc * per_b > budget) Bc >>= 1;   // Bc in {512,256,128,64}
    const int nch = BSZ / Bc;
    const int M = Bc * SEQ;

    float*  xz   = (float*)p;                p += (size_t)M*2048*sizeof(float);
    bf16_t* ybf  = (bf16_t*)p;               p += (size_t)M*1024*sizeof(bf16_t);
    float*  xdb  = (float*)p;                p += (size_t)M*64*sizeof(float);
    float*  accb = (float*)p;

    // ---- weight conversions + conv-weight rearrange ----
    cvt_bf16_kernel<<<(2048*512+255)/256, 256, 0, stream>>>(mf_in_w,  w_inf,  2048*512);
    cvt_bf16_kernel<<<(2048*512+255)/256, 256, 0, stream>>>(mb_in_w,  w_inb,  2048*512);
    cvt_bf16_kernel<<<(512*1024+255)/256, 256, 0, stream>>>(mf_out_w, w_outf, 512*1024);
    cvt_bf16_kernel<<<(512*1024+255)/256, 256, 0, stream>>>(mb_out_w, w_outb, 512*1024);
    cvt_bf16_kernel<<<(64*1024+255)/256,  256, 0, stream>>>(mf_xproj, w_xpf,  64*1024);
    cvt_bf16_kernel<<<(48*1024+255)/256,  256, 0, stream>>>(mb_xproj, w_xpb,  48*1024);
    prep_convw_kernel<<<(256*384+255)/256, 256, 0, stream>>>(conv1_w, conv2_w, W1p, W2p);

    // ---- front-end: id-embed + F0pad build, then conv stack as two GEMMs ----
    fe0_kernel<<<BSZ, 256, 0, stream>>>(x, fe_w, fe_b, fe_ln_g, fe_ln_b,
        emb_ln_g, emb_ln_b, comb_all, F0pad, F1pad);
    gemm_conv_kernel<<<dim3(1, 1, BSZ), 256, 0, stream>>>(
        F0pad, 32, 102*32, W1p, 96, 128, conv1_b, F1pad, 128, 102, 1, 0, SEQ);
    gemm_conv_kernel<<<dim3(1, 2, BSZ), 256, 0, stream>>>(
        F1pad, 128, 102*128, W2p, 384, 256, conv2_b, comb_all, 512, 100, 0, 256, SEQ);

    const int gm128 = M / 128;

    for (int c = 0; c < nch; ++c){
        const size_t b0 = (size_t)c * Bc;
        const bf16_t* comb = comb_all + b0*SEQ*512;

        // ---- forward mamba (d_state=16, d_conv=4) ----
        gemm_bf16_kernel<<<dim3(gm128, 16), 256, 0, stream>>>(comb, 512, M, w_inf, 512, 2048, xz, 2048, 0);
        conv_silu_kernel<4, false><<<Bc*DI/256, 256, 0, stream>>>(xz, mf_conv_w, mf_conv_b, ybf);
        gemm_bf16_x_kernel<<<gm128, 256, 0, stream>>>(ybf, w_xpf, 1024, 64, xdb);
        scan_kernel<16, false><<<Bc*4, 256, 0, stream>>>(xz, xdb, mf_dt_w, mf_dt_b, mf_Alog, mf_D, ybf);
        gemm_bf16_kernel<<<dim3(gm128, 4), 256, 0, stream>>>(ybf, 1024, M, w_outf, 1024, 512, accb, 512, 0);

        // ---- backward mamba (d_state=8, d_conv=2), time-reversed in place ----
        gemm_bf16_kernel<<<dim3(gm128, 16), 256, 0, stream>>>(comb, 512, M, w_inb, 512, 2048, xz, 2048, 0);
        conv_silu_kernel<2, true><<<Bc*DI/256, 256, 0, stream>>>(xz, mb_conv_w, mb_conv_b, ybf);
        gemm_bf16_x_kernel<<<gm128, 256, 0, stream>>>(ybf, w_xpb, 1024, 48, xdb);
        scan_kernel<8, true><<<Bc*4, 256, 0, stream>>>(xz, xdb, mb_dt_w, mb_dt_b, mb_Alog, mb_D, ybf);
        gemm_bf16_kernel<<<dim3(gm128, 4), 256, 0, stream>>>(ybf, 1024, M, w_outb, 1024, 512, accb, 512, 1);

        head_kernel<<<Bc, 256, 0, stream>>>(accb, norm_g, norm_b, fc1_w, fc1_b, fc2_w, fc2_b,
                                            out + b0*4);
    }
}

// Round 7
// 2073.247 us; speedup vs baseline: 3.2327x; 1.0932x over previous
//
#include <hip/hip_runtime.h>
#include <cstddef>
#include <cstdint>

#define BSZ 512
#define SEQ 100
#define DI 1024

typedef __bf16 bf16_t;
typedef __attribute__((ext_vector_type(8))) __bf16 bf16x8;
typedef __attribute__((ext_vector_type(4))) float f32x4;

__device__ __forceinline__ float sigmoidf_(float v){ return 1.f/(1.f + __expf(-v)); }
__device__ __forceinline__ float siluf_(float v){ return v * sigmoidf_(v); }
__device__ __forceinline__ float softplusf_(float v){ return (v > 20.f) ? v : __logf(1.f + __expf(v)); }

// ---------------------------------------------------------------------------
// fp32 -> bf16 converter (weights), once per call
// ---------------------------------------------------------------------------
__global__ __launch_bounds__(256) void cvt_bf16_kernel(
    const float* __restrict__ src, bf16_t* __restrict__ dst, int n)
{
    int i = blockIdx.x*256 + threadIdx.x;
    if (i < n) dst[i] = (bf16_t)src[i];
}

// ---------------------------------------------------------------------------
// Conv-weight rearrange for conv-as-GEMM:
//   W1p[o, k*32 + c]  = conv1_w[o, c, k]  (c<22, else 0)   o<128, K'=96
//   W2p[o, k*128 + c] = conv2_w[o, c, k]                   o<256, K'=384
// ---------------------------------------------------------------------------
__global__ __launch_bounds__(256) void prep_convw_kernel(
    const float* __restrict__ c1w, const float* __restrict__ c2w,
    bf16_t* __restrict__ W1p, bf16_t* __restrict__ W2p)
{
    int i = blockIdx.x*256 + threadIdx.x;
    if (i < 128*96){
        int o = i / 96, kk = i - o*96, k = kk >> 5, c = kk & 31;
        W1p[i] = (c < 22) ? (bf16_t)c1w[(o*22 + c)*3 + k] : (bf16_t)0.f;
    }
    if (i < 256*384){
        int o = i / 384, kk = i - o*384, k = kk >> 7, c = kk & 127;
        W2p[i] = (bf16_t)c2w[(o*128 + c)*3 + k];
    }
}

// ---------------------------------------------------------------------------
// FE0: id-embed (2 LayerNorms) -> comb[...,0:256] (bf16); build F0pad bf16
// [b,102,32]; zero F1pad boundary rows. One block per batch element.
// ---------------------------------------------------------------------------
__global__ __launch_bounds__(256) void fe0_kernel(
    const float* __restrict__ x,                     // (512, 100, 23)
    const float* __restrict__ fe_w, const float* __restrict__ fe_b,
    const float* __restrict__ g1, const float* __restrict__ b1,
    const float* __restrict__ g2, const float* __restrict__ b2,
    bf16_t* __restrict__ comb,                       // (512, 100, 512) bf16
    bf16_t* __restrict__ F0pad,                      // (512, 102, 32) bf16
    bf16_t* __restrict__ F1pad)                      // (512, 102, 128) bf16
{
    const int b = blockIdx.x;
    const int t = threadIdx.x;
    const int wv = t >> 6, lane = t & 63;

    float few[4], feb[4], lg1[4], lb1[4], lg2[4], lb2[4];
    #pragma unroll
    for (int q = 0; q < 4; ++q){
        int j = lane + 64*q;
        few[q] = fe_w[j]; feb[q] = fe_b[j];
        lg1[q] = g1[j];  lb1[q] = b1[j];
        lg2[q] = g2[j];  lb2[q] = b2[j];
    }
    for (int l = wv; l < SEQ; l += 4){
        float m = fabsf(x[(size_t)(b*SEQ + l)*23]);
        float e[4];
        float s1 = 0.f, s2 = 0.f;
        #pragma unroll
        for (int q = 0; q < 4; ++q){ e[q] = m*few[q] + feb[q]; s1 += e[q]; s2 += e[q]*e[q]; }
        #pragma unroll
        for (int off = 32; off > 0; off >>= 1){ s1 += __shfl_xor(s1, off); s2 += __shfl_xor(s2, off); }
        float mean = s1 * (1.f/256.f);
        float rstd = rsqrtf(s2*(1.f/256.f) - mean*mean + 1e-5f);
        s1 = 0.f; s2 = 0.f;
        #pragma unroll
        for (int q = 0; q < 4; ++q){
            e[q] = fmaxf((e[q]-mean)*rstd*lg1[q] + lb1[q], 0.f);
            s1 += e[q]; s2 += e[q]*e[q];
        }
        #pragma unroll
        for (int off = 32; off > 0; off >>= 1){ s1 += __shfl_xor(s1, off); s2 += __shfl_xor(s2, off); }
        mean = s1 * (1.f/256.f);
        rstd = rsqrtf(s2*(1.f/256.f) - mean*mean + 1e-5f);
        #pragma unroll
        for (int q = 0; q < 4; ++q){
            float v = fmaxf((e[q]-mean)*rstd*lg2[q] + lb2[q], 0.f);
            comb[(size_t)(b*SEQ + l)*512 + lane + 64*q] = (bf16_t)v;
        }
    }

    for (int idx = t; idx < 102*32; idx += 256){
        int r = idx >> 5, c = idx & 31;
        float v = 0.f;
        if (r >= 1 && r <= SEQ && c < 22) v = x[(size_t)(b*SEQ + r - 1)*23 + 1 + c];
        F0pad[(size_t)(b*102 + r)*32 + c] = (bf16_t)v;
    }
    if (t < 128) F1pad[(size_t)(b*102 + 0)*128 + t] = (bf16_t)0.f;
    else F1pad[(size_t)(b*102 + 101)*128 + (t - 128)] = (bf16_t)0.f;
}

// ---------------------------------------------------------------------------
// Conv-as-GEMM (z-batched): C[m,n] = relu(sum_k A_z[m*lda + k]*W[n,k] + bias[n])
// ---------------------------------------------------------------------------
__global__ __launch_bounds__(256) void gemm_conv_kernel(
    const bf16_t* __restrict__ Abase, int lda, int Az,
    const bf16_t* __restrict__ W, int K, int N,
    const float* __restrict__ bias,
    bf16_t* __restrict__ Cbase, int ldc, int Cb, int coff, int noff, int Mtot)
{
    __shared__ bf16_t As[128*32];
    __shared__ bf16_t Ws[128*32];
    const bf16_t* A = Abase + (size_t)blockIdx.z * Az;
    const int t = threadIdx.x;
    const int lane = t & 63, w = t >> 6;
    const int n0 = blockIdx.y * 128;
    const int rsub = lane >> 2, csub = lane & 3;
    const int col = lane & 15, quad = lane >> 4;
    const int wOffM = (w & 1) * 64, wOffN = (w >> 1) * 64;

    f32x4 acc[4][4];
    #pragma unroll
    for (int i = 0; i < 4; ++i)
        #pragma unroll
        for (int j = 0; j < 4; ++j)
            acc[i][j] = (f32x4){0.f, 0.f, 0.f, 0.f};

    for (int k0 = 0; k0 < K; k0 += 32){
        __syncthreads();
        #pragma unroll
        for (int q = 0; q < 2; ++q){
            const int rt = w*32 + q*16 + rsub;
            const int lq = csub ^ ((rt >> 1) & 3);
            int ra = (rt < Mtot) ? rt : (Mtot - 1);
            const bf16_t* ga = A + (size_t)ra*lda + k0 + lq*8;
            __builtin_amdgcn_global_load_lds(
                (const __attribute__((address_space(1))) void*)ga,
                (__attribute__((address_space(3))) void*)&As[(w*32 + q*16)*32], 16, 0, 0);
            const bf16_t* gw = W + (size_t)(n0 + rt)*K + k0 + lq*8;
            __builtin_amdgcn_global_load_lds(
                (const __attribute__((address_space(1))) void*)gw,
                (__attribute__((address_space(3))) void*)&Ws[(w*32 + q*16)*32], 16, 0, 0);
        }
        __syncthreads();

        bf16x8 af[4], bfv[4];
        #pragma unroll
        for (int i = 0; i < 4; ++i){
            const int ra = wOffM + i*16 + col;
            af[i]  = *(const bf16x8*)&As[ra*32 + (quad ^ ((ra >> 1) & 3))*8];
            const int rb = wOffN + i*16 + col;
            bfv[i] = *(const bf16x8*)&Ws[rb*32 + (quad ^ ((rb >> 1) & 3))*8];
        }
        #pragma unroll
        for (int i = 0; i < 4; ++i)
            #pragma unroll
            for (int j = 0; j < 4; ++j)
                acc[i][j] = __builtin_amdgcn_mfma_f32_16x16x32_bf16(af[i], bfv[j], acc[i][j], 0, 0, 0);
    }

    #pragma unroll
    for (int i = 0; i < 4; ++i){
        const int gmb = wOffM + i*16 + quad*4;
        #pragma unroll
        for (int j = 0; j < 4; ++j){
            const int gn = n0 + wOffN + j*16 + col;
            const float bb = bias[gn];
            #pragma unroll
            for (int r = 0; r < 4; ++r){
                const int gm = gmb + r;
                if (gm < Mtot){
                    float v = fmaxf(acc[i][j][r] + bb, 0.f);
                    Cbase[((size_t)blockIdx.z*Cb + coff + gm)*ldc + noff + gn] = (bf16_t)v;
                }
            }
        }
    }
}

// ---------------------------------------------------------------------------
// In-proj bf16 MFMA GEMM: N=2048; columns [0,1024) -> xf (fp32),
// columns [1024,2048) -> zbf (bf16). 128x128 tile, BK=32, swizzled staging.
// ---------------------------------------------------------------------------
__global__ __launch_bounds__(256) void gemm_in_kernel(
    const bf16_t* __restrict__ A, int lda, int Mtot,
    const bf16_t* __restrict__ W, int K,
    float* __restrict__ xf, bf16_t* __restrict__ zbf)
{
    __shared__ bf16_t As[128*32];
    __shared__ bf16_t Ws[128*32];
    const int t = threadIdx.x;
    const int lane = t & 63, w = t >> 6;
    const int m0 = blockIdx.x * 128, n0 = blockIdx.y * 128;
    const int rsub = lane >> 2, csub = lane & 3;
    const int col = lane & 15, quad = lane >> 4;
    const int wOffM = (w & 1) * 64, wOffN = (w >> 1) * 64;

    f32x4 acc[4][4];
    #pragma unroll
    for (int i = 0; i < 4; ++i)
        #pragma unroll
        for (int j = 0; j < 4; ++j)
            acc[i][j] = (f32x4){0.f, 0.f, 0.f, 0.f};

    for (int k0 = 0; k0 < K; k0 += 32){
        __syncthreads();
        #pragma unroll
        for (int q = 0; q < 2; ++q){
            const int rt = w*32 + q*16 + rsub;
            const int lq = csub ^ ((rt >> 1) & 3);
            int ra = m0 + rt; ra = (ra < Mtot) ? ra : (Mtot - 1);
            const bf16_t* ga = A + (size_t)ra*lda + k0 + lq*8;
            __builtin_amdgcn_global_load_lds(
                (const __attribute__((address_space(1))) void*)ga,
                (__attribute__((address_space(3))) void*)&As[(w*32 + q*16)*32], 16, 0, 0);
            const bf16_t* gw = W + (size_t)(n0 + rt)*K + k0 + lq*8;
            __builtin_amdgcn_global_load_lds(
                (const __attribute__((address_space(1))) void*)gw,
                (__attribute__((address_space(3))) void*)&Ws[(w*32 + q*16)*32], 16, 0, 0);
        }
        __syncthreads();

        bf16x8 af[4], bfv[4];
        #pragma unroll
        for (int i = 0; i < 4; ++i){
            const int ra = wOffM + i*16 + col;
            af[i]  = *(const bf16x8*)&As[ra*32 + (quad ^ ((ra >> 1) & 3))*8];
            const int rb = wOffN + i*16 + col;
            bfv[i] = *(const bf16x8*)&Ws[rb*32 + (quad ^ ((rb >> 1) & 3))*8];
        }
        #pragma unroll
        for (int i = 0; i < 4; ++i)
            #pragma unroll
            for (int j = 0; j < 4; ++j)
                acc[i][j] = __builtin_amdgcn_mfma_f32_16x16x32_bf16(af[i], bfv[j], acc[i][j], 0, 0, 0);
    }

    #pragma unroll
    for (int i = 0; i < 4; ++i){
        const int gmb = m0 + wOffM + i*16 + quad*4;
        #pragma unroll
        for (int j = 0; j < 4; ++j){
            const int gn = n0 + wOffN + j*16 + col;
            #pragma unroll
            for (int r = 0; r < 4; ++r){
                const int gm = gmb + r;
                if (gm < Mtot){
                    float v = acc[i][j][r];
                    if (gn < 1024) xf[(size_t)gm*1024 + gn] = v;
                    else zbf[(size_t)gm*1024 + (gn - 1024)] = (bf16_t)v;
                }
            }
        }
    }
}

// ---------------------------------------------------------------------------
// Out-proj bf16 MFMA GEMM: C fp32 (ldc), optional accumulate.
// ---------------------------------------------------------------------------
__global__ __launch_bounds__(256) void gemm_bf16_kernel(
    const bf16_t* __restrict__ A, int lda, int Mtot,
    const bf16_t* __restrict__ W, int K, int N,
    float* __restrict__ C, int ldc, int accumulate)
{
    __shared__ bf16_t As[128*32];
    __shared__ bf16_t Ws[128*32];
    const int t = threadIdx.x;
    const int lane = t & 63, w = t >> 6;
    const int m0 = blockIdx.x * 128, n0 = blockIdx.y * 128;
    const int rsub = lane >> 2, csub = lane & 3;
    const int col = lane & 15, quad = lane >> 4;
    const int wOffM = (w & 1) * 64, wOffN = (w >> 1) * 64;

    f32x4 acc[4][4];
    #pragma unroll
    for (int i = 0; i < 4; ++i)
        #pragma unroll
        for (int j = 0; j < 4; ++j)
            acc[i][j] = (f32x4){0.f, 0.f, 0.f, 0.f};

    for (int k0 = 0; k0 < K; k0 += 32){
        __syncthreads();
        #pragma unroll
        for (int q = 0; q < 2; ++q){
            const int rt = w*32 + q*16 + rsub;
            const int lq = csub ^ ((rt >> 1) & 3);
            int ra = m0 + rt; ra = (ra < Mtot) ? ra : (Mtot - 1);
            const bf16_t* ga = A + (size_t)ra*lda + k0 + lq*8;
            __builtin_amdgcn_global_load_lds(
                (const __attribute__((address_space(1))) void*)ga,
                (__attribute__((address_space(3))) void*)&As[(w*32 + q*16)*32], 16, 0, 0);
            const bf16_t* gw = W + (size_t)(n0 + rt)*K + k0 + lq*8;
            __builtin_amdgcn_global_load_lds(
                (const __attribute__((address_space(1))) void*)gw,
                (__attribute__((address_space(3))) void*)&Ws[(w*32 + q*16)*32], 16, 0, 0);
        }
        __syncthreads();

        bf16x8 af[4], bfv[4];
        #pragma unroll
        for (int i = 0; i < 4; ++i){
            const int ra = wOffM + i*16 + col;
            af[i]  = *(const bf16x8*)&As[ra*32 + (quad ^ ((ra >> 1) & 3))*8];
            const int rb = wOffN + i*16 + col;
            bfv[i] = *(const bf16x8*)&Ws[rb*32 + (quad ^ ((rb >> 1) & 3))*8];
        }
        #pragma unroll
        for (int i = 0; i < 4; ++i)
            #pragma unroll
            for (int j = 0; j < 4; ++j)
                acc[i][j] = __builtin_amdgcn_mfma_f32_16x16x32_bf16(af[i], bfv[j], acc[i][j], 0, 0, 0);
    }

    #pragma unroll
    for (int i = 0; i < 4; ++i){
        const int gmb = m0 + wOffM + i*16 + quad*4;
        #pragma unroll
        for (int j = 0; j < 4; ++j){
            const int gn = n0 + wOffN + j*16 + col;
            #pragma unroll
            for (int r = 0; r < 4; ++r){
                const int gm = gmb + r;
                if (gm < Mtot){
                    float v = acc[i][j][r];
                    size_t off = (size_t)gm*ldc + gn;
                    if (accumulate) v += C[off];
                    C[off] = v;
                }
            }
        }
    }
}

// ---------------------------------------------------------------------------
// bf16 MFMA GEMM, x-proj: C[m,n] = sum_k A[m,k]*W[n,k], N<=64, ldc=64.
// 128x64 tile, BK=32; requires M%128==0.
// ---------------------------------------------------------------------------
__global__ __launch_bounds__(256) void gemm_bf16_x_kernel(
    const bf16_t* __restrict__ A, const bf16_t* __restrict__ W,
    int K, int N, float* __restrict__ C)
{
    __shared__ bf16_t As[128*32];
    __shared__ bf16_t Ws[64*32];
    const int t = threadIdx.x;
    const int lane = t & 63, w = t >> 6;
    const int m0 = blockIdx.x * 128;
    const int rsub = lane >> 2, csub = lane & 3;
    const int col = lane & 15, quad = lane >> 4;

    f32x4 acc[2][4];
    #pragma unroll
    for (int i = 0; i < 2; ++i)
        #pragma unroll
        for (int j = 0; j < 4; ++j)
            acc[i][j] = (f32x4){0.f, 0.f, 0.f, 0.f};

    for (int k0 = 0; k0 < K; k0 += 32){
        __syncthreads();
        #pragma unroll
        for (int q = 0; q < 2; ++q){
            const int rt = q*64 + w*16 + rsub;
            const int lq = csub ^ ((rt >> 1) & 3);
            const bf16_t* ga = A + (size_t)(m0 + rt)*K + k0 + lq*8;
            __builtin_amdgcn_global_load_lds(
                (const __attribute__((address_space(1))) void*)ga,
                (__attribute__((address_space(3))) void*)&As[(q*64 + w*16)*32], 16, 0, 0);
        }
        {
            const int rt = w*16 + rsub;
            const int lq = csub ^ ((rt >> 1) & 3);
            int rw = (rt < N) ? rt : (N - 1);
            const bf16_t* gw = W + (size_t)rw*K + k0 + lq*8;
            __builtin_amdgcn_global_load_lds(
                (const __attribute__((address_space(1))) void*)gw,
                (__attribute__((address_space(3))) void*)&Ws[(w*16)*32], 16, 0, 0);
        }
        __syncthreads();

        bf16x8 af[2], bfv[4];
        #pragma unroll
        for (int i = 0; i < 2; ++i){
            const int ra = w*32 + i*16 + col;
            af[i]  = *(const bf16x8*)&As[ra*32 + (quad ^ ((ra >> 1) & 3))*8];
        }
        #pragma unroll
        for (int j = 0; j < 4; ++j){
            const int rb = j*16 + col;
            bfv[j] = *(const bf16x8*)&Ws[rb*32 + (quad ^ ((rb >> 1) & 3))*8];
        }
        #pragma unroll
        for (int i = 0; i < 2; ++i)
            #pragma unroll
            for (int j = 0; j < 4; ++j)
                acc[i][j] = __builtin_amdgcn_mfma_f32_16x16x32_bf16(af[i], bfv[j], acc[i][j], 0, 0, 0);
    }

    #pragma unroll
    for (int i = 0; i < 2; ++i){
        const int gmb = m0 + w*32 + i*16 + quad*4;
        #pragma unroll
        for (int j = 0; j < 4; ++j){
            const int gn = j*16 + col;
            if (gn < N){
                #pragma unroll
                for (int r = 0; r < 4; ++r)
                    C[(size_t)(gmb + r)*64 + gn] = acc[i][j][r];
            }
        }
    }
}

// ---------------------------------------------------------------------------
// dt projection: dt[m,d] = softplus(xdb[m,:32]·dt_w[d,:] + dt_b[d]) -> bf16.
// Grid (M/16, 8), block 256 = 128 d-channels x 2 m-slots (8 rows each).
// ---------------------------------------------------------------------------
__global__ __launch_bounds__(256) void dt_kernel(
    const float* __restrict__ xdb,   // (M, 64), dtin = cols 0..31
    const float* __restrict__ dt_w,  // (1024, 32)
    const float* __restrict__ dt_b,  // (1024)
    bf16_t* __restrict__ dtb)        // (M, 1024)
{
    const int d = blockIdx.y*128 + (threadIdx.x & 127);
    const int mslot = threadIdx.x >> 7;
    const int m0 = blockIdx.x * 16;
    __shared__ float sd[16*32];
    for (int i = threadIdx.x; i < 16*32; i += 256){
        int r = i >> 5, c = i & 31;
        sd[i] = xdb[(size_t)(m0 + r)*64 + c];
    }
    float w[32];
    #pragma unroll
    for (int r = 0; r < 32; ++r) w[r] = dt_w[d*32 + r];
    const float db = dt_b[d];
    __syncthreads();
    #pragma unroll
    for (int i = 0; i < 8; ++i){
        const int row = mslot + i*2;
        const float* rp = &sd[row*32];
        float a = db;
        #pragma unroll
        for (int r = 0; r < 32; ++r) a += w[r]*rp[r];
        dtb[(size_t)(m0 + row)*1024 + d] = (bf16_t)softplusf_(a);
    }
}

// ---------------------------------------------------------------------------
// Depthwise causal conv + bias + silu, in place on xf (M,1024 fp32), plus a
// bf16 copy for the x-proj. Batched 10 timesteps per group.
// ---------------------------------------------------------------------------
template<int DC, bool REV>
__global__ __launch_bounds__(256) void conv_silu_kernel(
    float* __restrict__ xf, const float* __restrict__ cw, const float* __restrict__ cb,
    bf16_t* __restrict__ xbf)            // (Bc*L, 1024) bf16
{
    const int gid = blockIdx.x*256 + threadIdx.x;   // Bc*DI threads
    const int b = gid >> 10, d = gid & 1023;
    float w[DC];
    #pragma unroll
    for (int k = 0; k < DC; ++k) w[k] = cw[d*DC + k];
    const float bias = cb[d];
    float hist[DC-1];
    #pragma unroll
    for (int k = 0; k < DC-1; ++k) hist[k] = 0.f;
    float* base = xf + (size_t)b*SEQ*1024 + d;
    bf16_t* bbase = xbf + (size_t)b*SEQ*1024 + d;
    const int step = REV ? -1 : 1;
    int l = REV ? (SEQ-1) : 0;
    for (int t0 = 0; t0 < SEQ; t0 += 10){
        float v[10];
        #pragma unroll
        for (int i = 0; i < 10; ++i) v[i] = base[(size_t)(l + step*i)*1024];
        float o[10];
        #pragma unroll
        for (int i = 0; i < 10; ++i){
            float a = bias + w[DC-1]*v[i];
            #pragma unroll
            for (int j = 1; j < DC; ++j) a += w[DC-1-j]*hist[j-1];
            #pragma unroll
            for (int j = DC-2; j >= 1; --j) hist[j] = hist[j-1];
            hist[0] = v[i];
            o[i] = siluf_(a);
        }
        #pragma unroll
        for (int i = 0; i < 10; ++i){
            base[(size_t)(l + step*i)*1024] = o[i];
            bbase[(size_t)(l + step*i)*1024] = (bf16_t)o[i];
        }
        l += step*10;
    }
}

// ---------------------------------------------------------------------------
// Selective scan. dt precomputed (bf16), B/C slab in LDS, x fp32, z bf16;
// loads batched 10 timesteps deep. Writes y bf16 to ybf.
// ---------------------------------------------------------------------------
template<int DS, bool REV>
__global__ __launch_bounds__(256) void scan_kernel(
    const float* __restrict__ xf,        // (Bc*L, 1024) fp32
    const bf16_t* __restrict__ zbf,      // (Bc*L, 1024) bf16
    const bf16_t* __restrict__ dtb,      // (Bc*L, 1024) bf16
    const float* __restrict__ xdb,       // (Bc*L, 64): [32:+DS]=B, [32+DS:+DS]=C
    const float* __restrict__ Alog,      // (1024, DS)
    const float* __restrict__ Dp,        // (1024)
    bf16_t* __restrict__ ybf)            // (Bc*L, 1024) bf16
{
    const int b = blockIdx.x >> 2;
    const int d = ((blockIdx.x & 3) << 8) + threadIdx.x;

    __shared__ float sx[SEQ*64];         // 25.6 KB
    {
        const float4* src = (const float4*)(xdb + (size_t)b*SEQ*64);
        float4* dst = (float4*)sx;
        for (int i = threadIdx.x; i < SEQ*16; i += 256) dst[i] = src[i];
    }

    const float Dd = Dp[d];
    float Av[DS], h[DS];
    #pragma unroll
    for (int s = 0; s < DS; ++s){ Av[s] = -__expf(Alog[d*DS + s]); h[s] = 0.f; }

    __syncthreads();

    const float*  xbase = xf  + (size_t)b*SEQ*1024 + d;
    const bf16_t* zbase = zbf + (size_t)b*SEQ*1024 + d;
    const bf16_t* tbase = dtb + (size_t)b*SEQ*1024 + d;
    bf16_t* ybase = ybf + (size_t)b*SEQ*1024 + d;
    const int step = REV ? -1 : 1;
    int l = REV ? (SEQ-1) : 0;

    for (int t0 = 0; t0 < SEQ; t0 += 10){
        float xr[10], zr[10], tr[10];
        #pragma unroll
        for (int i = 0; i < 10; ++i){
            const size_t li = (size_t)(l + step*i);
            xr[i] = xbase[li*1024];
            zr[i] = (float)zbase[li*1024];
            tr[i] = (float)tbase[li*1024];
        }
        #pragma unroll
        for (int i = 0; i < 10; ++i){
            const int li = l + step*i;
            const float4* sxl4 = (const float4*)&sx[li*64];
            const float dtv = tr[i];
            const float dtx = dtv * xr[i];
            float yv = 0.f;
            #pragma unroll
            for (int s4 = 0; s4 < DS/4; ++s4){
                float4 Bv = sxl4[8 + s4];
                float4 Cv = sxl4[8 + DS/4 + s4];
                h[s4*4+0] = __expf(dtv*Av[s4*4+0])*h[s4*4+0] + dtx*Bv.x;
                h[s4*4+1] = __expf(dtv*Av[s4*4+1])*h[s4*4+1] + dtx*Bv.y;
                h[s4*4+2] = __expf(dtv*Av[s4*4+2])*h[s4*4+2] + dtx*Bv.z;
                h[s4*4+3] = __expf(dtv*Av[s4*4+3])*h[s4*4+3] + dtx*Bv.w;
                yv += h[s4*4+0]*Cv.x + h[s4*4+1]*Cv.y + h[s4*4+2]*Cv.z + h[s4*4+3]*Cv.w;
            }
            yv += xr[i]*Dd;
            yv *= siluf_(zr[i]);
            ybase[(size_t)li*1024] = (bf16_t)yv;
        }
        l += step*10;
    }
}

// ---------------------------------------------------------------------------
// Head: max-pool over L, LN(512), fc1(512->128)+relu, fc2(128->4)
// ---------------------------------------------------------------------------
__global__ __launch_bounds__(256) void head_kernel(
    const float* __restrict__ acc,   // (Bc, L, 512)
    const float* __restrict__ ng, const float* __restrict__ nb,
    const float* __restrict__ w1, const float* __restrict__ b1,
    const float* __restrict__ w2, const float* __restrict__ b2,
    float* __restrict__ out)         // (Bc, 4) chunk base
{
    const int b = blockIdx.x, t = threadIdx.x;
    __shared__ float4 sm4[256];
    __shared__ float sp[512];
    __shared__ float sh2[256];
    __shared__ float sh[128];
    __shared__ float red1[4], red2[4];
    const float* base = acc + (size_t)b*SEQ*512;

    {
        const int c4 = t & 127, lh = t >> 7;
        float4 m = make_float4(-3.4e38f, -3.4e38f, -3.4e38f, -3.4e38f);
        for (int l = lh*50; l < lh*50 + 50; ++l){
            float4 v = ((const float4*)(base + (size_t)l*512))[c4];
            m.x = fmaxf(m.x, v.x); m.y = fmaxf(m.y, v.y);
            m.z = fmaxf(m.z, v.z); m.w = fmaxf(m.w, v.w);
        }
        sm4[t] = m;
    }
    __syncthreads();
    if (t < 128){
        float4 a = sm4[t], c = sm4[t + 128];
        ((float4*)sp)[t] = make_float4(fmaxf(a.x,c.x), fmaxf(a.y,c.y),
                                       fmaxf(a.z,c.z), fmaxf(a.w,c.w));
    }
    __syncthreads();

    float s1 = 0.f, s2 = 0.f;
    for (int o = t; o < 512; o += 256){ float v = sp[o]; s1 += v; s2 += v*v; }
    #pragma unroll
    for (int off = 32; off > 0; off >>= 1){ s1 += __shfl_xor(s1, off); s2 += __shfl_xor(s2, off); }
    const int wv = t >> 6, lane = t & 63;
    if (lane == 0){ red1[wv] = s1; red2[wv] = s2; }
    __syncthreads();
    if (t == 0){
        float a = 0.f, c = 0.f;
        for (int i = 0; i < 4; ++i){ a += red1[i]; c += red2[i]; }
        float mean = a * (1.f/512.f);
        float var = c * (1.f/512.f) - mean*mean;
        red1[0] = mean; red2[0] = rsqrtf(var + 1e-5f);
    }
    __syncthreads();
    const float mean = red1[0], rstd = red2[0];
    for (int o = t; o < 512; o += 256) sp[o] = (sp[o]-mean)*rstd*ng[o] + nb[o];
    __syncthreads();

    {
        const int o = t & 127, half = t >> 7;
        const float4* wrow = (const float4*)(w1 + (size_t)o*512 + half*256);
        const float4* sp4 = (const float4*)sp + half*64;
        float s = 0.f;
        #pragma unroll 8
        for (int j = 0; j < 64; ++j){
            float4 a = sp4[j], wq = wrow[j];
            s += a.x*wq.x + a.y*wq.y + a.z*wq.z + a.w*wq.w;
        }
        sh2[t] = s;
    }
    __syncthreads();
    if (t < 128) sh[t] = fmaxf(sh2[t] + sh2[t + 128] + b1[t], 0.f);
    __syncthreads();
    if (t < 4){
        float a = b2[t];
        for (int j = 0; j < 128; ++j) a += sh[j]*w2[t*128 + j];
        out[b*4 + t] = a;
    }
}

// ---------------------------------------------------------------------------
extern "C" void kernel_launch(void* const* d_in, const int* in_sizes, int n_in,
                              void* d_out, int out_size, void* d_ws, size_t ws_size,
                              hipStream_t stream)
{
    (void)in_sizes; (void)n_in; (void)out_size;
    const float* x        = (const float*)d_in[0];
    const float* fe_w     = (const float*)d_in[1];
    const float* fe_b     = (const float*)d_in[2];
    const float* fe_ln_g  = (const float*)d_in[3];
    const float* fe_ln_b  = (const float*)d_in[4];
    const float* emb_ln_g = (const float*)d_in[5];
    const float* emb_ln_b = (const float*)d_in[6];
    const float* conv1_w  = (const float*)d_in[7];
    const float* conv1_b  = (const float*)d_in[8];
    const float* conv2_w  = (const float*)d_in[9];
    const float* conv2_b  = (const float*)d_in[10];
    const float* mf_in_w  = (const float*)d_in[11];
    const float* mf_conv_w= (const float*)d_in[12];
    const float* mf_conv_b= (const float*)d_in[13];
    const float* mf_xproj = (const float*)d_in[14];
    const float* mf_dt_w  = (const float*)d_in[15];
    const float* mf_dt_b  = (const float*)d_in[16];
    const float* mf_Alog  = (const float*)d_in[17];
    const float* mf_D     = (const float*)d_in[18];
    const float* mf_out_w = (const float*)d_in[19];
    const float* mb_in_w  = (const float*)d_in[20];
    const float* mb_conv_w= (const float*)d_in[21];
    const float* mb_conv_b= (const float*)d_in[22];
    const float* mb_xproj = (const float*)d_in[23];
    const float* mb_dt_w  = (const float*)d_in[24];
    const float* mb_dt_b  = (const float*)d_in[25];
    const float* mb_Alog  = (const float*)d_in[26];
    const float* mb_D     = (const float*)d_in[27];
    const float* mb_out_w = (const float*)d_in[28];
    const float* norm_g   = (const float*)d_in[29];
    const float* norm_b   = (const float*)d_in[30];
    const float* fc1_w    = (const float*)d_in[31];
    const float* fc1_b    = (const float*)d_in[32];
    const float* fc2_w    = (const float*)d_in[33];
    const float* fc2_b    = (const float*)d_in[34];
    float* out = (float*)d_out;

    // ---- fixed workspace region ----
    char* p = (char*)d_ws;
    bf16_t* w_inf  = (bf16_t*)p; p += (size_t)2048*512*sizeof(bf16_t);
    bf16_t* w_inb  = (bf16_t*)p; p += (size_t)2048*512*sizeof(bf16_t);
    bf16_t* w_outf = (bf16_t*)p; p += (size_t)512*1024*sizeof(bf16_t);
    bf16_t* w_outb = (bf16_t*)p; p += (size_t)512*1024*sizeof(bf16_t);
    bf16_t* w_xpf  = (bf16_t*)p; p += (size_t)64*1024*sizeof(bf16_t);
    bf16_t* w_xpb  = (bf16_t*)p; p += (size_t)48*1024*sizeof(bf16_t);
    bf16_t* W1p    = (bf16_t*)p; p += (size_t)128*96*sizeof(bf16_t);
    bf16_t* W2p    = (bf16_t*)p; p += (size_t)256*384*sizeof(bf16_t);
    bf16_t* comb_all = (bf16_t*)p; p += (size_t)BSZ*SEQ*512*sizeof(bf16_t);
    const size_t fixed_bytes = (size_t)(p - (char*)d_ws);

    // ---- chunk region (F0pad/F1pad alias its start; dead before chunk loop) ----
    // per-batch: xf f32 409.6K + zbf 204.8K + ybf 204.8K + xdb 25.6K
    //          + dtb 204.8K + accb 204.8K = 1,254,400 B
    const size_t per_b = (size_t)SEQ * (1024*4 + 1024*2 + 1024*2 + 64*4 + 1024*2 + 512*4);
    const size_t budget = (ws_size > fixed_bytes) ? (ws_size - fixed_bytes) : 0;
    int Bc = BSZ;
    while (Bc > 64 && (size_t)Bc * per_b > budget) Bc >>= 1;   // Bc in {512,256,128,64}
    const int nch = BSZ / Bc;
    const int M = Bc * SEQ;

    bf16_t* F0pad = (bf16_t*)p;   // aliases xf region (pre-loop only)
    bf16_t* F1pad = F0pad + (size_t)BSZ*102*32;
    float*  xf   = (float*)p;                p += (size_t)M*1024*sizeof(float);
    bf16_t* zbf  = (bf16_t*)p;               p += (size_t)M*1024*sizeof(bf16_t);
    bf16_t* ybf  = (bf16_t*)p;               p += (size_t)M*1024*sizeof(bf16_t);
    float*  xdb  = (float*)p;                p += (size_t)M*64*sizeof(float);
    bf16_t* dtb  = (bf16_t*)p;               p += (size_t)M*1024*sizeof(bf16_t);
    float*  accb = (float*)p;

    // ---- weight conversions + conv-weight rearrange ----
    cvt_bf16_kernel<<<(2048*512+255)/256, 256, 0, stream>>>(mf_in_w,  w_inf,  2048*512);
    cvt_bf16_kernel<<<(2048*512+255)/256, 256, 0, stream>>>(mb_in_w,  w_inb,  2048*512);
    cvt_bf16_kernel<<<(512*1024+255)/256, 256, 0, stream>>>(mf_out_w, w_outf, 512*1024);
    cvt_bf16_kernel<<<(512*1024+255)/256, 256, 0, stream>>>(mb_out_w, w_outb, 512*1024);
    cvt_bf16_kernel<<<(64*1024+255)/256,  256, 0, stream>>>(mf_xproj, w_xpf,  64*1024);
    cvt_bf16_kernel<<<(48*1024+255)/256,  256, 0, stream>>>(mb_xproj, w_xpb,  48*1024);
    prep_convw_kernel<<<(256*384+255)/256, 256, 0, stream>>>(conv1_w, conv2_w, W1p, W2p);

    // ---- front-end ----
    fe0_kernel<<<BSZ, 256, 0, stream>>>(x, fe_w, fe_b, fe_ln_g, fe_ln_b,
        emb_ln_g, emb_ln_b, comb_all, F0pad, F1pad);
    gemm_conv_kernel<<<dim3(1, 1, BSZ), 256, 0, stream>>>(
        F0pad, 32, 102*32, W1p, 96, 128, conv1_b, F1pad, 128, 102, 1, 0, SEQ);
    gemm_conv_kernel<<<dim3(1, 2, BSZ), 256, 0, stream>>>(
        F1pad, 128, 102*128, W2p, 384, 256, conv2_b, comb_all, 512, 100, 0, 256, SEQ);

    const int gm128 = M / 128;

    for (int c = 0; c < nch; ++c){
        const size_t b0 = (size_t)c * Bc;
        const bf16_t* comb = comb_all + b0*SEQ*512;

        // ---- forward mamba (d_state=16, d_conv=4) ----
        gemm_in_kernel<<<dim3(gm128, 16), 256, 0, stream>>>(comb, 512, M, w_inf, 512, xf, zbf);
        conv_silu_kernel<4, false><<<Bc*DI/256, 256, 0, stream>>>(xf, mf_conv_w, mf_conv_b, ybf);
        gemm_bf16_x_kernel<<<gm128, 256, 0, stream>>>(ybf, w_xpf, 1024, 64, xdb);
        dt_kernel<<<dim3(M/16, 8), 256, 0, stream>>>(xdb, mf_dt_w, mf_dt_b, dtb);
        scan_kernel<16, false><<<Bc*4, 256, 0, stream>>>(xf, zbf, dtb, xdb, mf_Alog, mf_D, ybf);
        gemm_bf16_kernel<<<dim3(gm128, 4), 256, 0, stream>>>(ybf, 1024, M, w_outf, 1024, 512, accb, 512, 0);

        // ---- backward mamba (d_state=8, d_conv=2), time-reversed in place ----
        gemm_in_kernel<<<dim3(gm128, 16), 256, 0, stream>>>(comb, 512, M, w_inb, 512, xf, zbf);
        conv_silu_kernel<2, true><<<Bc*DI/256, 256, 0, stream>>>(xf, mb_conv_w, mb_conv_b, ybf);
        gemm_bf16_x_kernel<<<gm128, 256, 0, stream>>>(ybf, w_xpb, 1024, 48, xdb);
        dt_kernel<<<dim3(M/16, 8), 256, 0, stream>>>(xdb, mb_dt_w, mb_dt_b, dtb);
        scan_kernel<8, true><<<Bc*4, 256, 0, stream>>>(xf, zbf, dtb, xdb, mb_Alog, mb_D, ybf);
        gemm_bf16_kernel<<<dim3(gm128, 4), 256, 0, stream>>>(ybf, 1024, M, w_outb, 1024, 512, accb, 512, 1);

        head_kernel<<<Bc, 256, 0, stream>>>(accb, norm_g, norm_b, fc1_w, fc1_b, fc2_w, fc2_b,
                                            out + b0*4);
    }
}

// Round 8
// 1918.214 us; speedup vs baseline: 3.4940x; 1.0808x over previous
//
#include <hip/hip_runtime.h>
#include <cstddef>
#include <cstdint>

#define BSZ 512
#define SEQ 100
#define DI 1024

typedef __bf16 bf16_t;
typedef __attribute__((ext_vector_type(8))) __bf16 bf16x8;
typedef __attribute__((ext_vector_type(4))) float f32x4;

__device__ __forceinline__ float sigmoidf_(float v){ return 1.f/(1.f + __expf(-v)); }
__device__ __forceinline__ float siluf_(float v){ return v * sigmoidf_(v); }
__device__ __forceinline__ float softplusf_(float v){ return (v > 20.f) ? v : __logf(1.f + __expf(v)); }

// ---------------------------------------------------------------------------
// fp32 -> bf16 converter (weights), once per call
// ---------------------------------------------------------------------------
__global__ __launch_bounds__(256) void cvt_bf16_kernel(
    const float* __restrict__ src, bf16_t* __restrict__ dst, int n)
{
    int i = blockIdx.x*256 + threadIdx.x;
    if (i < n) dst[i] = (bf16_t)src[i];
}

// ---------------------------------------------------------------------------
// Conv-weight rearrange for conv-as-GEMM.
// ---------------------------------------------------------------------------
__global__ __launch_bounds__(256) void prep_convw_kernel(
    const float* __restrict__ c1w, const float* __restrict__ c2w,
    bf16_t* __restrict__ W1p, bf16_t* __restrict__ W2p)
{
    int i = blockIdx.x*256 + threadIdx.x;
    if (i < 128*96){
        int o = i / 96, kk = i - o*96, k = kk >> 5, c = kk & 31;
        W1p[i] = (c < 22) ? (bf16_t)c1w[(o*22 + c)*3 + k] : (bf16_t)0.f;
    }
    if (i < 256*384){
        int o = i / 384, kk = i - o*384, k = kk >> 7, c = kk & 127;
        W2p[i] = (bf16_t)c2w[(o*128 + c)*3 + k];
    }
}

// ---------------------------------------------------------------------------
// FE0: id-embed (2 LN) -> comb[...,0:256]; build F0pad; zero F1pad boundary.
// ---------------------------------------------------------------------------
__global__ __launch_bounds__(256) void fe0_kernel(
    const float* __restrict__ x,
    const float* __restrict__ fe_w, const float* __restrict__ fe_b,
    const float* __restrict__ g1, const float* __restrict__ b1,
    const float* __restrict__ g2, const float* __restrict__ b2,
    bf16_t* __restrict__ comb, bf16_t* __restrict__ F0pad, bf16_t* __restrict__ F1pad)
{
    const int b = blockIdx.x;
    const int t = threadIdx.x;
    const int wv = t >> 6, lane = t & 63;

    float few[4], feb[4], lg1[4], lb1[4], lg2[4], lb2[4];
    #pragma unroll
    for (int q = 0; q < 4; ++q){
        int j = lane + 64*q;
        few[q] = fe_w[j]; feb[q] = fe_b[j];
        lg1[q] = g1[j];  lb1[q] = b1[j];
        lg2[q] = g2[j];  lb2[q] = b2[j];
    }
    for (int l = wv; l < SEQ; l += 4){
        float m = fabsf(x[(size_t)(b*SEQ + l)*23]);
        float e[4];
        float s1 = 0.f, s2 = 0.f;
        #pragma unroll
        for (int q = 0; q < 4; ++q){ e[q] = m*few[q] + feb[q]; s1 += e[q]; s2 += e[q]*e[q]; }
        #pragma unroll
        for (int off = 32; off > 0; off >>= 1){ s1 += __shfl_xor(s1, off); s2 += __shfl_xor(s2, off); }
        float mean = s1 * (1.f/256.f);
        float rstd = rsqrtf(s2*(1.f/256.f) - mean*mean + 1e-5f);
        s1 = 0.f; s2 = 0.f;
        #pragma unroll
        for (int q = 0; q < 4; ++q){
            e[q] = fmaxf((e[q]-mean)*rstd*lg1[q] + lb1[q], 0.f);
            s1 += e[q]; s2 += e[q]*e[q];
        }
        #pragma unroll
        for (int off = 32; off > 0; off >>= 1){ s1 += __shfl_xor(s1, off); s2 += __shfl_xor(s2, off); }
        mean = s1 * (1.f/256.f);
        rstd = rsqrtf(s2*(1.f/256.f) - mean*mean + 1e-5f);
        #pragma unroll
        for (int q = 0; q < 4; ++q){
            float v = fmaxf((e[q]-mean)*rstd*lg2[q] + lb2[q], 0.f);
            comb[(size_t)(b*SEQ + l)*512 + lane + 64*q] = (bf16_t)v;
        }
    }

    for (int idx = t; idx < 102*32; idx += 256){
        int r = idx >> 5, c = idx & 31;
        float v = 0.f;
        if (r >= 1 && r <= SEQ && c < 22) v = x[(size_t)(b*SEQ + r - 1)*23 + 1 + c];
        F0pad[(size_t)(b*102 + r)*32 + c] = (bf16_t)v;
    }
    if (t < 128) F1pad[(size_t)(b*102 + 0)*128 + t] = (bf16_t)0.f;
    else F1pad[(size_t)(b*102 + 101)*128 + (t - 128)] = (bf16_t)0.f;
}

// ---------------------------------------------------------------------------
// Conv-as-GEMM (z-batched): C[m,n] = relu(sum_k A_z[m*lda + k]*W[n,k] + bias[n])
// ---------------------------------------------------------------------------
__global__ __launch_bounds__(256) void gemm_conv_kernel(
    const bf16_t* __restrict__ Abase, int lda, int Az,
    const bf16_t* __restrict__ W, int K, int N,
    const float* __restrict__ bias,
    bf16_t* __restrict__ Cbase, int ldc, int Cb, int coff, int noff, int Mtot)
{
    __shared__ bf16_t As[128*32];
    __shared__ bf16_t Ws[128*32];
    const bf16_t* A = Abase + (size_t)blockIdx.z * Az;
    const int t = threadIdx.x;
    const int lane = t & 63, w = t >> 6;
    const int n0 = blockIdx.y * 128;
    const int rsub = lane >> 2, csub = lane & 3;
    const int col = lane & 15, quad = lane >> 4;
    const int wOffM = (w & 1) * 64, wOffN = (w >> 1) * 64;

    f32x4 acc[4][4];
    #pragma unroll
    for (int i = 0; i < 4; ++i)
        #pragma unroll
        for (int j = 0; j < 4; ++j)
            acc[i][j] = (f32x4){0.f, 0.f, 0.f, 0.f};

    for (int k0 = 0; k0 < K; k0 += 32){
        __syncthreads();
        #pragma unroll
        for (int q = 0; q < 2; ++q){
            const int rt = w*32 + q*16 + rsub;
            const int lq = csub ^ ((rt >> 1) & 3);
            int ra = (rt < Mtot) ? rt : (Mtot - 1);
            const bf16_t* ga = A + (size_t)ra*lda + k0 + lq*8;
            __builtin_amdgcn_global_load_lds(
                (const __attribute__((address_space(1))) void*)ga,
                (__attribute__((address_space(3))) void*)&As[(w*32 + q*16)*32], 16, 0, 0);
            const bf16_t* gw = W + (size_t)(n0 + rt)*K + k0 + lq*8;
            __builtin_amdgcn_global_load_lds(
                (const __attribute__((address_space(1))) void*)gw,
                (__attribute__((address_space(3))) void*)&Ws[(w*32 + q*16)*32], 16, 0, 0);
        }
        __syncthreads();

        bf16x8 af[4], bfv[4];
        #pragma unroll
        for (int i = 0; i < 4; ++i){
            const int ra = wOffM + i*16 + col;
            af[i]  = *(const bf16x8*)&As[ra*32 + (quad ^ ((ra >> 1) & 3))*8];
            const int rb = wOffN + i*16 + col;
            bfv[i] = *(const bf16x8*)&Ws[rb*32 + (quad ^ ((rb >> 1) & 3))*8];
        }
        #pragma unroll
        for (int i = 0; i < 4; ++i)
            #pragma unroll
            for (int j = 0; j < 4; ++j)
                acc[i][j] = __builtin_amdgcn_mfma_f32_16x16x32_bf16(af[i], bfv[j], acc[i][j], 0, 0, 0);
    }

    #pragma unroll
    for (int i = 0; i < 4; ++i){
        const int gmb = wOffM + i*16 + quad*4;
        #pragma unroll
        for (int j = 0; j < 4; ++j){
            const int gn = n0 + wOffN + j*16 + col;
            const float bb = bias[gn];
            #pragma unroll
            for (int r = 0; r < 4; ++r){
                const int gm = gmb + r;
                if (gm < Mtot){
                    float v = fmaxf(acc[i][j][r] + bb, 0.f);
                    Cbase[((size_t)blockIdx.z*Cb + coff + gm)*ldc + noff + gn] = (bf16_t)v;
                }
            }
        }
    }
}

// ---------------------------------------------------------------------------
// In-proj bf16 MFMA GEMM: N=2048; cols [0,1024) -> xbf (bf16, pre-conv x),
// cols [1024,2048) -> zbf (bf16). 128x128 tile, BK=32, swizzled staging.
// ---------------------------------------------------------------------------
__global__ __launch_bounds__(256) void gemm_in_kernel(
    const bf16_t* __restrict__ A, int lda, int Mtot,
    const bf16_t* __restrict__ W, int K,
    bf16_t* __restrict__ xbf, bf16_t* __restrict__ zbf)
{
    __shared__ bf16_t As[128*32];
    __shared__ bf16_t Ws[128*32];
    const int t = threadIdx.x;
    const int lane = t & 63, w = t >> 6;
    const int m0 = blockIdx.x * 128, n0 = blockIdx.y * 128;
    const int rsub = lane >> 2, csub = lane & 3;
    const int col = lane & 15, quad = lane >> 4;
    const int wOffM = (w & 1) * 64, wOffN = (w >> 1) * 64;

    f32x4 acc[4][4];
    #pragma unroll
    for (int i = 0; i < 4; ++i)
        #pragma unroll
        for (int j = 0; j < 4; ++j)
            acc[i][j] = (f32x4){0.f, 0.f, 0.f, 0.f};

    for (int k0 = 0; k0 < K; k0 += 32){
        __syncthreads();
        #pragma unroll
        for (int q = 0; q < 2; ++q){
            const int rt = w*32 + q*16 + rsub;
            const int lq = csub ^ ((rt >> 1) & 3);
            int ra = m0 + rt; ra = (ra < Mtot) ? ra : (Mtot - 1);
            const bf16_t* ga = A + (size_t)ra*lda + k0 + lq*8;
            __builtin_amdgcn_global_load_lds(
                (const __attribute__((address_space(1))) void*)ga,
                (__attribute__((address_space(3))) void*)&As[(w*32 + q*16)*32], 16, 0, 0);
            const bf16_t* gw = W + (size_t)(n0 + rt)*K + k0 + lq*8;
            __builtin_amdgcn_global_load_lds(
                (const __attribute__((address_space(1))) void*)gw,
                (__attribute__((address_space(3))) void*)&Ws[(w*32 + q*16)*32], 16, 0, 0);
        }
        __syncthreads();

        bf16x8 af[4], bfv[4];
        #pragma unroll
        for (int i = 0; i < 4; ++i){
            const int ra = wOffM + i*16 + col;
            af[i]  = *(const bf16x8*)&As[ra*32 + (quad ^ ((ra >> 1) & 3))*8];
            const int rb = wOffN + i*16 + col;
            bfv[i] = *(const bf16x8*)&Ws[rb*32 + (quad ^ ((rb >> 1) & 3))*8];
        }
        #pragma unroll
        for (int i = 0; i < 4; ++i)
            #pragma unroll
            for (int j = 0; j < 4; ++j)
                acc[i][j] = __builtin_amdgcn_mfma_f32_16x16x32_bf16(af[i], bfv[j], acc[i][j], 0, 0, 0);
    }

    #pragma unroll
    for (int i = 0; i < 4; ++i){
        const int gmb = m0 + wOffM + i*16 + quad*4;
        #pragma unroll
        for (int j = 0; j < 4; ++j){
            const int gn = n0 + wOffN + j*16 + col;
            #pragma unroll
            for (int r = 0; r < 4; ++r){
                const int gm = gmb + r;
                if (gm < Mtot){
                    float v = acc[i][j][r];
                    if (gn < 1024) xbf[(size_t)gm*1024 + gn] = (bf16_t)v;
                    else zbf[(size_t)gm*1024 + (gn - 1024)] = (bf16_t)v;
                }
            }
        }
    }
}

// ---------------------------------------------------------------------------
// Out-proj bf16 MFMA GEMM: C fp32 (ldc), optional accumulate.
// ---------------------------------------------------------------------------
__global__ __launch_bounds__(256) void gemm_bf16_kernel(
    const bf16_t* __restrict__ A, int lda, int Mtot,
    const bf16_t* __restrict__ W, int K, int N,
    float* __restrict__ C, int ldc, int accumulate)
{
    __shared__ bf16_t As[128*32];
    __shared__ bf16_t Ws[128*32];
    const int t = threadIdx.x;
    const int lane = t & 63, w = t >> 6;
    const int m0 = blockIdx.x * 128, n0 = blockIdx.y * 128;
    const int rsub = lane >> 2, csub = lane & 3;
    const int col = lane & 15, quad = lane >> 4;
    const int wOffM = (w & 1) * 64, wOffN = (w >> 1) * 64;

    f32x4 acc[4][4];
    #pragma unroll
    for (int i = 0; i < 4; ++i)
        #pragma unroll
        for (int j = 0; j < 4; ++j)
            acc[i][j] = (f32x4){0.f, 0.f, 0.f, 0.f};

    for (int k0 = 0; k0 < K; k0 += 32){
        __syncthreads();
        #pragma unroll
        for (int q = 0; q < 2; ++q){
            const int rt = w*32 + q*16 + rsub;
            const int lq = csub ^ ((rt >> 1) & 3);
            int ra = m0 + rt; ra = (ra < Mtot) ? ra : (Mtot - 1);
            const bf16_t* ga = A + (size_t)ra*lda + k0 + lq*8;
            __builtin_amdgcn_global_load_lds(
                (const __attribute__((address_space(1))) void*)ga,
                (__attribute__((address_space(3))) void*)&As[(w*32 + q*16)*32], 16, 0, 0);
            const bf16_t* gw = W + (size_t)(n0 + rt)*K + k0 + lq*8;
            __builtin_amdgcn_global_load_lds(
                (const __attribute__((address_space(1))) void*)gw,
                (__attribute__((address_space(3))) void*)&Ws[(w*32 + q*16)*32], 16, 0, 0);
        }
        __syncthreads();

        bf16x8 af[4], bfv[4];
        #pragma unroll
        for (int i = 0; i < 4; ++i){
            const int ra = wOffM + i*16 + col;
            af[i]  = *(const bf16x8*)&As[ra*32 + (quad ^ ((ra >> 1) & 3))*8];
            const int rb = wOffN + i*16 + col;
            bfv[i] = *(const bf16x8*)&Ws[rb*32 + (quad ^ ((rb >> 1) & 3))*8];
        }
        #pragma unroll
        for (int i = 0; i < 4; ++i)
            #pragma unroll
            for (int j = 0; j < 4; ++j)
                acc[i][j] = __builtin_amdgcn_mfma_f32_16x16x32_bf16(af[i], bfv[j], acc[i][j], 0, 0, 0);
    }

    #pragma unroll
    for (int i = 0; i < 4; ++i){
        const int gmb = m0 + wOffM + i*16 + quad*4;
        #pragma unroll
        for (int j = 0; j < 4; ++j){
            const int gn = n0 + wOffN + j*16 + col;
            #pragma unroll
            for (int r = 0; r < 4; ++r){
                const int gm = gmb + r;
                if (gm < Mtot){
                    float v = acc[i][j][r];
                    size_t off = (size_t)gm*ldc + gn;
                    if (accumulate) v += C[off];
                    C[off] = v;
                }
            }
        }
    }
}

// ---------------------------------------------------------------------------
// bf16 MFMA GEMM, x-proj: N<=64, ldc=64, 128x64 tile, M%128==0.
// ---------------------------------------------------------------------------
__global__ __launch_bounds__(256) void gemm_bf16_x_kernel(
    const bf16_t* __restrict__ A, const bf16_t* __restrict__ W,
    int K, int N, float* __restrict__ C)
{
    __shared__ bf16_t As[128*32];
    __shared__ bf16_t Ws[64*32];
    const int t = threadIdx.x;
    const int lane = t & 63, w = t >> 6;
    const int m0 = blockIdx.x * 128;
    const int rsub = lane >> 2, csub = lane & 3;
    const int col = lane & 15, quad = lane >> 4;

    f32x4 acc[2][4];
    #pragma unroll
    for (int i = 0; i < 2; ++i)
        #pragma unroll
        for (int j = 0; j < 4; ++j)
            acc[i][j] = (f32x4){0.f, 0.f, 0.f, 0.f};

    for (int k0 = 0; k0 < K; k0 += 32){
        __syncthreads();
        #pragma unroll
        for (int q = 0; q < 2; ++q){
            const int rt = q*64 + w*16 + rsub;
            const int lq = csub ^ ((rt >> 1) & 3);
            const bf16_t* ga = A + (size_t)(m0 + rt)*K + k0 + lq*8;
            __builtin_amdgcn_global_load_lds(
                (const __attribute__((address_space(1))) void*)ga,
                (__attribute__((address_space(3))) void*)&As[(q*64 + w*16)*32], 16, 0, 0);
        }
        {
            const int rt = w*16 + rsub;
            const int lq = csub ^ ((rt >> 1) & 3);
            int rw = (rt < N) ? rt : (N - 1);
            const bf16_t* gw = W + (size_t)rw*K + k0 + lq*8;
            __builtin_amdgcn_global_load_lds(
                (const __attribute__((address_space(1))) void*)gw,
                (__attribute__((address_space(3))) void*)&Ws[(w*16)*32], 16, 0, 0);
        }
        __syncthreads();

        bf16x8 af[2], bfv[4];
        #pragma unroll
        for (int i = 0; i < 2; ++i){
            const int ra = w*32 + i*16 + col;
            af[i]  = *(const bf16x8*)&As[ra*32 + (quad ^ ((ra >> 1) & 3))*8];
        }
        #pragma unroll
        for (int j = 0; j < 4; ++j){
            const int rb = j*16 + col;
            bfv[j] = *(const bf16x8*)&Ws[rb*32 + (quad ^ ((rb >> 1) & 3))*8];
        }
        #pragma unroll
        for (int i = 0; i < 2; ++i)
            #pragma unroll
            for (int j = 0; j < 4; ++j)
                acc[i][j] = __builtin_amdgcn_mfma_f32_16x16x32_bf16(af[i], bfv[j], acc[i][j], 0, 0, 0);
    }

    #pragma unroll
    for (int i = 0; i < 2; ++i){
        const int gmb = m0 + w*32 + i*16 + quad*4;
        #pragma unroll
        for (int j = 0; j < 4; ++j){
            const int gn = j*16 + col;
            if (gn < N){
                #pragma unroll
                for (int r = 0; r < 4; ++r)
                    C[(size_t)(gmb + r)*64 + gn] = acc[i][j][r];
            }
        }
    }
}

// ---------------------------------------------------------------------------
// dt projection: dt[m,d] = softplus(xdb[m,:32]·dt_w[d,:] + dt_b[d]) -> bf16.
// ---------------------------------------------------------------------------
__global__ __launch_bounds__(256) void dt_kernel(
    const float* __restrict__ xdb,   // (M, 64)
    const float* __restrict__ dt_w,  // (1024, 32)
    const float* __restrict__ dt_b,  // (1024)
    bf16_t* __restrict__ dtb)        // (M, 1024)
{
    const int d = blockIdx.y*128 + (threadIdx.x & 127);
    const int mslot = threadIdx.x >> 7;
    const int m0 = blockIdx.x * 16;
    __shared__ float sd[16*32];
    for (int i = threadIdx.x; i < 16*32; i += 256){
        int r = i >> 5, c = i & 31;
        sd[i] = xdb[(size_t)(m0 + r)*64 + c];
    }
    float w[32];
    #pragma unroll
    for (int r = 0; r < 32; ++r) w[r] = dt_w[d*32 + r];
    const float db = dt_b[d];
    __syncthreads();
    #pragma unroll
    for (int i = 0; i < 8; ++i){
        const int row = mslot + i*2;
        const float* rp = &sd[row*32];
        float a = db;
        #pragma unroll
        for (int r = 0; r < 32; ++r) a += w[r]*rp[r];
        dtb[(size_t)(m0 + row)*1024 + d] = (bf16_t)softplusf_(a);
    }
}

// ---------------------------------------------------------------------------
// Depthwise causal conv + bias + silu, IN PLACE on bf16 x (M,1024).
// Per-thread rolling history; batched 10 timesteps per group.
// ---------------------------------------------------------------------------
template<int DC, bool REV>
__global__ __launch_bounds__(256) void conv_silu_kernel(
    bf16_t* __restrict__ xb, const float* __restrict__ cw, const float* __restrict__ cb)
{
    const int gid = blockIdx.x*256 + threadIdx.x;   // Bc*DI threads
    const int b = gid >> 10, d = gid & 1023;
    float w[DC];
    #pragma unroll
    for (int k = 0; k < DC; ++k) w[k] = cw[d*DC + k];
    const float bias = cb[d];
    float hist[DC-1];
    #pragma unroll
    for (int k = 0; k < DC-1; ++k) hist[k] = 0.f;
    bf16_t* base = xb + (size_t)b*SEQ*1024 + d;
    const int step = REV ? -1 : 1;
    int l = REV ? (SEQ-1) : 0;
    for (int t0 = 0; t0 < SEQ; t0 += 10){
        float v[10];
        #pragma unroll
        for (int i = 0; i < 10; ++i) v[i] = (float)base[(size_t)(l + step*i)*1024];
        float o[10];
        #pragma unroll
        for (int i = 0; i < 10; ++i){
            float a = bias + w[DC-1]*v[i];
            #pragma unroll
            for (int j = 1; j < DC; ++j) a += w[DC-1-j]*hist[j-1];
            #pragma unroll
            for (int j = DC-2; j >= 1; --j) hist[j] = hist[j-1];
            hist[0] = v[i];
            o[i] = siluf_(a);
        }
        #pragma unroll
        for (int i = 0; i < 10; ++i)
            base[(size_t)(l + step*i)*1024] = (bf16_t)o[i];
        l += step*10;
    }
}

// ---------------------------------------------------------------------------
// Selective scan. dt precomputed (bf16); B/C slab (only) in LDS; x read from
// the bf16 xy buffer and y written back IN PLACE (thread-local addresses).
// Structured-A fast path: A[d][s] = (s+1)*A[d][0] (detected per-thread) ->
// dA_s = r^(s+1) with one exp per step instead of DS exps. General exp
// fallback preserved.
// ---------------------------------------------------------------------------
template<int DS, bool REV>
__global__ __launch_bounds__(256) void scan_kernel(
    bf16_t* __restrict__ xy,             // (Bc*L, 1024) bf16: x in, y out (in place)
    const bf16_t* __restrict__ zbf,      // (Bc*L, 1024) bf16
    const bf16_t* __restrict__ dtb,      // (Bc*L, 1024) bf16
    const float* __restrict__ xdb,       // (Bc*L, 64): [32:+DS]=B, [32+DS:+DS]=C
    const float* __restrict__ Alog,      // (1024, DS)
    const float* __restrict__ Dp)        // (1024)
{
    const int b = blockIdx.x >> 2;
    const int d = ((blockIdx.x & 3) << 8) + threadIdx.x;

    __shared__ float sx[SEQ*2*DS];       // B/C only: 12.8 KB (DS=16) / 6.4 KB (DS=8)
    {
        constexpr int F4PR = DS/2;       // float4 per row of B/C
        const float4* src = (const float4*)(xdb + (size_t)b*SEQ*64);
        float4* dst = (float4*)sx;
        for (int i = threadIdx.x; i < SEQ*F4PR; i += 256){
            int row = i / F4PR, c = i - row*F4PR;
            dst[i] = src[row*16 + 8 + c];
        }
    }

    const float Dd = Dp[d];
    float Av[DS], h[DS];
    #pragma unroll
    for (int s = 0; s < DS; ++s){ Av[s] = -__expf(Alog[d*DS + s]); h[s] = 0.f; }
    bool structured = true;
    #pragma unroll
    for (int s = 1; s < DS; ++s)
        structured = structured && (fabsf(Av[s] - (float)(s+1)*Av[0]) <= 1e-4f*(float)(s+1));

    __syncthreads();

    bf16_t* xybase = xy + (size_t)b*SEQ*1024 + d;
    const bf16_t* zbase = zbf + (size_t)b*SEQ*1024 + d;
    const bf16_t* tbase = dtb + (size_t)b*SEQ*1024 + d;
    const int step = REV ? -1 : 1;
    const float A0 = Av[0];

    if (structured){
        int l = REV ? (SEQ-1) : 0;
        for (int t0 = 0; t0 < SEQ; t0 += 10){
            float xr[10], zr[10], tr[10];
            #pragma unroll
            for (int i = 0; i < 10; ++i){
                const size_t li = (size_t)(l + step*i);
                xr[i] = (float)xybase[li*1024];
                zr[i] = (float)zbase[li*1024];
                tr[i] = (float)tbase[li*1024];
            }
            #pragma unroll
            for (int i = 0; i < 10; ++i){
                const int li = l + step*i;
                const float4* sxl4 = (const float4*)&sx[li*2*DS];
                const float dtv = tr[i];
                const float dtx = dtv * xr[i];
                const float r = __expf(dtv*A0);
                float rp = r;
                float yv = 0.f;
                #pragma unroll
                for (int s4 = 0; s4 < DS/4; ++s4){
                    float4 Bv = sxl4[s4];
                    float4 Cv = sxl4[DS/4 + s4];
                    h[s4*4+0] = rp*h[s4*4+0] + dtx*Bv.x; yv += h[s4*4+0]*Cv.x; rp *= r;
                    h[s4*4+1] = rp*h[s4*4+1] + dtx*Bv.y; yv += h[s4*4+1]*Cv.y; rp *= r;
                    h[s4*4+2] = rp*h[s4*4+2] + dtx*Bv.z; yv += h[s4*4+2]*Cv.z; rp *= r;
                    h[s4*4+3] = rp*h[s4*4+3] + dtx*Bv.w; yv += h[s4*4+3]*Cv.w; rp *= r;
                }
                yv += xr[i]*Dd;
                yv *= siluf_(zr[i]);
                xybase[(size_t)li*1024] = (bf16_t)yv;
            }
            l += step*10;
        }
    } else {
        int l = REV ? (SEQ-1) : 0;
        for (int t0 = 0; t0 < SEQ; t0 += 10){
            float xr[10], zr[10], tr[10];
            #pragma unroll
            for (int i = 0; i < 10; ++i){
                const size_t li = (size_t)(l + step*i);
                xr[i] = (float)xybase[li*1024];
                zr[i] = (float)zbase[li*1024];
                tr[i] = (float)tbase[li*1024];
            }
            #pragma unroll
            for (int i = 0; i < 10; ++i){
                const int li = l + step*i;
                const float4* sxl4 = (const float4*)&sx[li*2*DS];
                const float dtv = tr[i];
                const float dtx = dtv * xr[i];
                float yv = 0.f;
                #pragma unroll
                for (int s4 = 0; s4 < DS/4; ++s4){
                    float4 Bv = sxl4[s4];
                    float4 Cv = sxl4[DS/4 + s4];
                    h[s4*4+0] = __expf(dtv*Av[s4*4+0])*h[s4*4+0] + dtx*Bv.x; yv += h[s4*4+0]*Cv.x;
                    h[s4*4+1] = __expf(dtv*Av[s4*4+1])*h[s4*4+1] + dtx*Bv.y; yv += h[s4*4+1]*Cv.y;
                    h[s4*4+2] = __expf(dtv*Av[s4*4+2])*h[s4*4+2] + dtx*Bv.z; yv += h[s4*4+2]*Cv.z;
                    h[s4*4+3] = __expf(dtv*Av[s4*4+3])*h[s4*4+3] + dtx*Bv.w; yv += h[s4*4+3]*Cv.w;
                }
                yv += xr[i]*Dd;
                yv *= siluf_(zr[i]);
                xybase[(size_t)li*1024] = (bf16_t)yv;
            }
            l += step*10;
        }
    }
}

// ---------------------------------------------------------------------------
// Head: max-pool over L, LN(512), fc1(512->128)+relu, fc2(128->4)
// ---------------------------------------------------------------------------
__global__ __launch_bounds__(256) void head_kernel(
    const float* __restrict__ acc,   // (Bc, L, 512)
    const float* __restrict__ ng, const float* __restrict__ nb,
    const float* __restrict__ w1, const float* __restrict__ b1,
    const float* __restrict__ w2, const float* __restrict__ b2,
    float* __restrict__ out)         // (Bc, 4) chunk base
{
    const int b = blockIdx.x, t = threadIdx.x;
    __shared__ float4 sm4[256];
    __shared__ float sp[512];
    __shared__ float sh2[256];
    __shared__ float sh[128];
    __shared__ float red1[4], red2[4];
    const float* base = acc + (size_t)b*SEQ*512;

    {
        const int c4 = t & 127, lh = t >> 7;
        float4 m = make_float4(-3.4e38f, -3.4e38f, -3.4e38f, -3.4e38f);
        for (int l = lh*50; l < lh*50 + 50; ++l){
            float4 v = ((const float4*)(base + (size_t)l*512))[c4];
            m.x = fmaxf(m.x, v.x); m.y = fmaxf(m.y, v.y);
            m.z = fmaxf(m.z, v.z); m.w = fmaxf(m.w, v.w);
        }
        sm4[t] = m;
    }
    __syncthreads();
    if (t < 128){
        float4 a = sm4[t], c = sm4[t + 128];
        ((float4*)sp)[t] = make_float4(fmaxf(a.x,c.x), fmaxf(a.y,c.y),
                                       fmaxf(a.z,c.z), fmaxf(a.w,c.w));
    }
    __syncthreads();

    float s1 = 0.f, s2 = 0.f;
    for (int o = t; o < 512; o += 256){ float v = sp[o]; s1 += v; s2 += v*v; }
    #pragma unroll
    for (int off = 32; off > 0; off >>= 1){ s1 += __shfl_xor(s1, off); s2 += __shfl_xor(s2, off); }
    const int wv = t >> 6, lane = t & 63;
    if (lane == 0){ red1[wv] = s1; red2[wv] = s2; }
    __syncthreads();
    if (t == 0){
        float a = 0.f, c = 0.f;
        for (int i = 0; i < 4; ++i){ a += red1[i]; c += red2[i]; }
        float mean = a * (1.f/512.f);
        float var = c * (1.f/512.f) - mean*mean;
        red1[0] = mean; red2[0] = rsqrtf(var + 1e-5f);
    }
    __syncthreads();
    const float mean = red1[0], rstd = red2[0];
    for (int o = t; o < 512; o += 256) sp[o] = (sp[o]-mean)*rstd*ng[o] + nb[o];
    __syncthreads();

    {
        const int o = t & 127, half = t >> 7;
        const float4* wrow = (const float4*)(w1 + (size_t)o*512 + half*256);
        const float4* sp4 = (const float4*)sp + half*64;
        float s = 0.f;
        #pragma unroll 8
        for (int j = 0; j < 64; ++j){
            float4 a = sp4[j], wq = wrow[j];
            s += a.x*wq.x + a.y*wq.y + a.z*wq.z + a.w*wq.w;
        }
        sh2[t] = s;
    }
    __syncthreads();
    if (t < 128) sh[t] = fmaxf(sh2[t] + sh2[t + 128] + b1[t], 0.f);
    __syncthreads();
    if (t < 4){
        float a = b2[t];
        for (int j = 0; j < 128; ++j) a += sh[j]*w2[t*128 + j];
        out[b*4 + t] = a;
    }
}

// ---------------------------------------------------------------------------
extern "C" void kernel_launch(void* const* d_in, const int* in_sizes, int n_in,
                              void* d_out, int out_size, void* d_ws, size_t ws_size,
                              hipStream_t stream)
{
    (void)in_sizes; (void)n_in; (void)out_size;
    const float* x        = (const float*)d_in[0];
    const float* fe_w     = (const float*)d_in[1];
    const float* fe_b     = (const float*)d_in[2];
    const float* fe_ln_g  = (const float*)d_in[3];
    const float* fe_ln_b  = (const float*)d_in[4];
    const float* emb_ln_g = (const float*)d_in[5];
    const float* emb_ln_b = (const float*)d_in[6];
    const float* conv1_w  = (const float*)d_in[7];
    const float* conv1_b  = (const float*)d_in[8];
    const float* conv2_w  = (const float*)d_in[9];
    const float* conv2_b  = (const float*)d_in[10];
    const float* mf_in_w  = (const float*)d_in[11];
    const float* mf_conv_w= (const float*)d_in[12];
    const float* mf_conv_b= (const float*)d_in[13];
    const float* mf_xproj = (const float*)d_in[14];
    const float* mf_dt_w  = (const float*)d_in[15];
    const float* mf_dt_b  = (const float*)d_in[16];
    const float* mf_Alog  = (const float*)d_in[17];
    const float* mf_D     = (const float*)d_in[18];
    const float* mf_out_w = (const float*)d_in[19];
    const float* mb_in_w  = (const float*)d_in[20];
    const float* mb_conv_w= (const float*)d_in[21];
    const float* mb_conv_b= (const float*)d_in[22];
    const float* mb_xproj = (const float*)d_in[23];
    const float* mb_dt_w  = (const float*)d_in[24];
    const float* mb_dt_b  = (const float*)d_in[25];
    const float* mb_Alog  = (const float*)d_in[26];
    const float* mb_D     = (const float*)d_in[27];
    const float* mb_out_w = (const float*)d_in[28];
    const float* norm_g   = (const float*)d_in[29];
    const float* norm_b   = (const float*)d_in[30];
    const float* fc1_w    = (const float*)d_in[31];
    const float* fc1_b    = (const float*)d_in[32];
    const float* fc2_w    = (const float*)d_in[33];
    const float* fc2_b    = (const float*)d_in[34];
    float* out = (float*)d_out;

    // ---- fixed workspace region ----
    char* p = (char*)d_ws;
    bf16_t* w_inf  = (bf16_t*)p; p += (size_t)2048*512*sizeof(bf16_t);
    bf16_t* w_inb  = (bf16_t*)p; p += (size_t)2048*512*sizeof(bf16_t);
    bf16_t* w_outf = (bf16_t*)p; p += (size_t)512*1024*sizeof(bf16_t);
    bf16_t* w_outb = (bf16_t*)p; p += (size_t)512*1024*sizeof(bf16_t);
    bf16_t* w_xpf  = (bf16_t*)p; p += (size_t)64*1024*sizeof(bf16_t);
    bf16_t* w_xpb  = (bf16_t*)p; p += (size_t)48*1024*sizeof(bf16_t);
    bf16_t* W1p    = (bf16_t*)p; p += (size_t)128*96*sizeof(bf16_t);
    bf16_t* W2p    = (bf16_t*)p; p += (size_t)256*384*sizeof(bf16_t);
    bf16_t* comb_all = (bf16_t*)p; p += (size_t)BSZ*SEQ*512*sizeof(bf16_t);
    const size_t fixed_bytes = (size_t)(p - (char*)d_ws);

    // ---- chunk region (F0pad/F1pad alias its start; dead before chunk loop) ----
    // per-batch: xy 204.8K + zbf 204.8K + xdb 25.6K + dtb 204.8K + accb 204.8K
    //          = 844,800 B
    const size_t per_b = (size_t)SEQ * (1024*2 + 1024*2 + 64*4 + 1024*2 + 512*4);
    const size_t budget = (ws_size > fixed_bytes) ? (ws_size - fixed_bytes) : 0;
    int Bc = BSZ;
    while (Bc > 64 && (size_t)Bc * per_b > budget) Bc >>= 1;   // Bc in {512,256,128,64}
    const int nch = BSZ / Bc;
    const int M = Bc * SEQ;

    bf16_t* F0pad = (bf16_t*)p;   // aliases chunk region (pre-loop only)
    bf16_t* F1pad = F0pad + (size_t)BSZ*102*32;
    bf16_t* xy   = (bf16_t*)p;               p += (size_t)M*1024*sizeof(bf16_t);
    bf16_t* zbf  = (bf16_t*)p;               p += (size_t)M*1024*sizeof(bf16_t);
    float*  xdb  = (float*)p;                p += (size_t)M*64*sizeof(float);
    bf16_t* dtb  = (bf16_t*)p;               p += (size_t)M*1024*sizeof(bf16_t);
    float*  accb = (float*)p;

    // ---- weight conversions + conv-weight rearrange ----
    cvt_bf16_kernel<<<(2048*512+255)/256, 256, 0, stream>>>(mf_in_w,  w_inf,  2048*512);
    cvt_bf16_kernel<<<(2048*512+255)/256, 256, 0, stream>>>(mb_in_w,  w_inb,  2048*512);
    cvt_bf16_kernel<<<(512*1024+255)/256, 256, 0, stream>>>(mf_out_w, w_outf, 512*1024);
    cvt_bf16_kernel<<<(512*1024+255)/256, 256, 0, stream>>>(mb_out_w, w_outb, 512*1024);
    cvt_bf16_kernel<<<(64*1024+255)/256,  256, 0, stream>>>(mf_xproj, w_xpf,  64*1024);
    cvt_bf16_kernel<<<(48*1024+255)/256,  256, 0, stream>>>(mb_xproj, w_xpb,  48*1024);
    prep_convw_kernel<<<(256*384+255)/256, 256, 0, stream>>>(conv1_w, conv2_w, W1p, W2p);

    // ---- front-end ----
    fe0_kernel<<<BSZ, 256, 0, stream>>>(x, fe_w, fe_b, fe_ln_g, fe_ln_b,
        emb_ln_g, emb_ln_b, comb_all, F0pad, F1pad);
    gemm_conv_kernel<<<dim3(1, 1, BSZ), 256, 0, stream>>>(
        F0pad, 32, 102*32, W1p, 96, 128, conv1_b, F1pad, 128, 102, 1, 0, SEQ);
    gemm_conv_kernel<<<dim3(1, 2, BSZ), 256, 0, stream>>>(
        F1pad, 128, 102*128, W2p, 384, 256, conv2_b, comb_all, 512, 100, 0, 256, SEQ);

    const int gm128 = M / 128;

    for (int c = 0; c < nch; ++c){
        const size_t b0 = (size_t)c * Bc;
        const bf16_t* comb = comb_all + b0*SEQ*512;

        // ---- forward mamba (d_state=16, d_conv=4) ----
        gemm_in_kernel<<<dim3(gm128, 16), 256, 0, stream>>>(comb, 512, M, w_inf, 512, xy, zbf);
        conv_silu_kernel<4, false><<<Bc*DI/256, 256, 0, stream>>>(xy, mf_conv_w, mf_conv_b);
        gemm_bf16_x_kernel<<<gm128, 256, 0, stream>>>(xy, w_xpf, 1024, 64, xdb);
        dt_kernel<<<dim3(M/16, 8), 256, 0, stream>>>(xdb, mf_dt_w, mf_dt_b, dtb);
        scan_kernel<16, false><<<Bc*4, 256, 0, stream>>>(xy, zbf, dtb, xdb, mf_Alog, mf_D);
        gemm_bf16_kernel<<<dim3(gm128, 4), 256, 0, stream>>>(xy, 1024, M, w_outf, 1024, 512, accb, 512, 0);

        // ---- backward mamba (d_state=8, d_conv=2), time-reversed in place ----
        gemm_in_kernel<<<dim3(gm128, 16), 256, 0, stream>>>(comb, 512, M, w_inb, 512, xy, zbf);
        conv_silu_kernel<2, true><<<Bc*DI/256, 256, 0, stream>>>(xy, mb_conv_w, mb_conv_b);
        gemm_bf16_x_kernel<<<gm128, 256, 0, stream>>>(xy, w_xpb, 1024, 48, xdb);
        dt_kernel<<<dim3(M/16, 8), 256, 0, stream>>>(xdb, mb_dt_w, mb_dt_b, dtb);
        scan_kernel<8, true><<<Bc*4, 256, 0, stream>>>(xy, zbf, dtb, xdb, mb_Alog, mb_D);
        gemm_bf16_kernel<<<dim3(gm128, 4), 256, 0, stream>>>(xy, 1024, M, w_outb, 1024, 512, accb, 512, 1);

        head_kernel<<<Bc, 256, 0, stream>>>(accb, norm_g, norm_b, fc1_w, fc1_b, fc2_w, fc2_b,
                                            out + b0*4);
    }
}

// Round 9
// 1598.155 us; speedup vs baseline: 4.1937x; 1.2003x over previous
//
#include <hip/hip_runtime.h>
#include <cstddef>
#include <cstdint>

#define BSZ 512
#define SEQ 100

typedef __bf16 bf16_t;
typedef __attribute__((ext_vector_type(8))) __bf16 bf16x8;
typedef __attribute__((ext_vector_type(4))) float f32x4;

__device__ __forceinline__ float sigmoidf_(float v){ return 1.f/(1.f + __expf(-v)); }
__device__ __forceinline__ float siluf_(float v){ return v * sigmoidf_(v); }
__device__ __forceinline__ float softplusf_(float v){ return (v > 20.f) ? v : __logf(1.f + __expf(v)); }

// ---------------------------------------------------------------------------
__global__ __launch_bounds__(256) void cvt_bf16_kernel(
    const float* __restrict__ src, bf16_t* __restrict__ dst, int n)
{
    int i = blockIdx.x*256 + threadIdx.x;
    if (i < n) dst[i] = (bf16_t)src[i];
}

// W_out_comb[o, k] = k<1024 ? mf_out[o,k] : mb_out[o,k-1024]   (512, 2048)
__global__ __launch_bounds__(256) void prep_outw_kernel(
    const float* __restrict__ of, const float* __restrict__ ob, bf16_t* __restrict__ W)
{
    int i = blockIdx.x*256 + threadIdx.x;
    if (i < 512*2048){
        int o = i >> 11, k = i & 2047;
        W[i] = (bf16_t)((k < 1024) ? of[o*1024 + k] : ob[o*1024 + (k - 1024)]);
    }
}

__global__ __launch_bounds__(256) void prep_convw_kernel(
    const float* __restrict__ c1w, const float* __restrict__ c2w,
    bf16_t* __restrict__ W1p, bf16_t* __restrict__ W2p)
{
    int i = blockIdx.x*256 + threadIdx.x;
    if (i < 128*96){
        int o = i / 96, kk = i - o*96, k = kk >> 5, c = kk & 31;
        W1p[i] = (c < 22) ? (bf16_t)c1w[(o*22 + c)*3 + k] : (bf16_t)0.f;
    }
    if (i < 256*384){
        int o = i / 384, kk = i - o*384, k = kk >> 7, c = kk & 127;
        W2p[i] = (bf16_t)c2w[(o*128 + c)*3 + k];
    }
}

// ---------------------------------------------------------------------------
// FE0: id-embed (2 LN) -> comb[...,0:256]; build F0pad; zero F1pad boundary.
// ---------------------------------------------------------------------------
__global__ __launch_bounds__(256) void fe0_kernel(
    const float* __restrict__ x,
    const float* __restrict__ fe_w, const float* __restrict__ fe_b,
    const float* __restrict__ g1, const float* __restrict__ b1,
    const float* __restrict__ g2, const float* __restrict__ b2,
    bf16_t* __restrict__ comb, bf16_t* __restrict__ F0pad, bf16_t* __restrict__ F1pad)
{
    const int b = blockIdx.x;
    const int t = threadIdx.x;
    const int wv = t >> 6, lane = t & 63;

    float few[4], feb[4], lg1[4], lb1[4], lg2[4], lb2[4];
    #pragma unroll
    for (int q = 0; q < 4; ++q){
        int j = lane + 64*q;
        few[q] = fe_w[j]; feb[q] = fe_b[j];
        lg1[q] = g1[j];  lb1[q] = b1[j];
        lg2[q] = g2[j];  lb2[q] = b2[j];
    }
    for (int l = wv; l < SEQ; l += 4){
        float m = fabsf(x[(size_t)(b*SEQ + l)*23]);
        float e[4];
        float s1 = 0.f, s2 = 0.f;
        #pragma unroll
        for (int q = 0; q < 4; ++q){ e[q] = m*few[q] + feb[q]; s1 += e[q]; s2 += e[q]*e[q]; }
        #pragma unroll
        for (int off = 32; off > 0; off >>= 1){ s1 += __shfl_xor(s1, off); s2 += __shfl_xor(s2, off); }
        float mean = s1 * (1.f/256.f);
        float rstd = rsqrtf(s2*(1.f/256.f) - mean*mean + 1e-5f);
        s1 = 0.f; s2 = 0.f;
        #pragma unroll
        for (int q = 0; q < 4; ++q){
            e[q] = fmaxf((e[q]-mean)*rstd*lg1[q] + lb1[q], 0.f);
            s1 += e[q]; s2 += e[q]*e[q];
        }
        #pragma unroll
        for (int off = 32; off > 0; off >>= 1){ s1 += __shfl_xor(s1, off); s2 += __shfl_xor(s2, off); }
        mean = s1 * (1.f/256.f);
        rstd = rsqrtf(s2*(1.f/256.f) - mean*mean + 1e-5f);
        #pragma unroll
        for (int q = 0; q < 4; ++q){
            float v = fmaxf((e[q]-mean)*rstd*lg2[q] + lb2[q], 0.f);
            comb[(size_t)(b*SEQ + l)*512 + lane + 64*q] = (bf16_t)v;
        }
    }

    for (int idx = t; idx < 102*32; idx += 256){
        int r = idx >> 5, c = idx & 31;
        float v = 0.f;
        if (r >= 1 && r <= SEQ && c < 22) v = x[(size_t)(b*SEQ + r - 1)*23 + 1 + c];
        F0pad[(size_t)(b*102 + r)*32 + c] = (bf16_t)v;
    }
    if (t < 128) F1pad[(size_t)(b*102 + 0)*128 + t] = (bf16_t)0.f;
    else F1pad[(size_t)(b*102 + 101)*128 + (t - 128)] = (bf16_t)0.f;
}

// ---------------------------------------------------------------------------
// Conv-as-GEMM (z-batched): C[m,n] = relu(sum_k A_z[m*lda + k]*W[n,k] + bias[n])
// ---------------------------------------------------------------------------
__global__ __launch_bounds__(256) void gemm_conv_kernel(
    const bf16_t* __restrict__ Abase, int lda, int Az,
    const bf16_t* __restrict__ W, int K, int N,
    const float* __restrict__ bias,
    bf16_t* __restrict__ Cbase, int ldc, int Cb, int coff, int noff, int Mtot)
{
    __shared__ bf16_t As[128*32];
    __shared__ bf16_t Ws[128*32];
    const bf16_t* A = Abase + (size_t)blockIdx.z * Az;
    const int t = threadIdx.x;
    const int lane = t & 63, w = t >> 6;
    const int n0 = blockIdx.y * 128;
    const int rsub = lane >> 2, csub = lane & 3;
    const int col = lane & 15, quad = lane >> 4;
    const int wOffM = (w & 1) * 64, wOffN = (w >> 1) * 64;

    f32x4 acc[4][4];
    #pragma unroll
    for (int i = 0; i < 4; ++i)
        #pragma unroll
        for (int j = 0; j < 4; ++j)
            acc[i][j] = (f32x4){0.f, 0.f, 0.f, 0.f};

    for (int k0 = 0; k0 < K; k0 += 32){
        __syncthreads();
        #pragma unroll
        for (int q = 0; q < 2; ++q){
            const int rt = w*32 + q*16 + rsub;
            const int lq = csub ^ ((rt >> 1) & 3);
            int ra = (rt < Mtot) ? rt : (Mtot - 1);
            const bf16_t* ga = A + (size_t)ra*lda + k0 + lq*8;
            __builtin_amdgcn_global_load_lds(
                (const __attribute__((address_space(1))) void*)ga,
                (__attribute__((address_space(3))) void*)&As[(w*32 + q*16)*32], 16, 0, 0);
            const bf16_t* gw = W + (size_t)(n0 + rt)*K + k0 + lq*8;
            __builtin_amdgcn_global_load_lds(
                (const __attribute__((address_space(1))) void*)gw,
                (__attribute__((address_space(3))) void*)&Ws[(w*32 + q*16)*32], 16, 0, 0);
        }
        __syncthreads();

        bf16x8 af[4], bfv[4];
        #pragma unroll
        for (int i = 0; i < 4; ++i){
            const int ra = wOffM + i*16 + col;
            af[i]  = *(const bf16x8*)&As[ra*32 + (quad ^ ((ra >> 1) & 3))*8];
            const int rb = wOffN + i*16 + col;
            bfv[i] = *(const bf16x8*)&Ws[rb*32 + (quad ^ ((rb >> 1) & 3))*8];
        }
        #pragma unroll
        for (int i = 0; i < 4; ++i)
            #pragma unroll
            for (int j = 0; j < 4; ++j)
                acc[i][j] = __builtin_amdgcn_mfma_f32_16x16x32_bf16(af[i], bfv[j], acc[i][j], 0, 0, 0);
    }

    #pragma unroll
    for (int i = 0; i < 4; ++i){
        const int gmb = wOffM + i*16 + quad*4;
        #pragma unroll
        for (int j = 0; j < 4; ++j){
            const int gn = n0 + wOffN + j*16 + col;
            const float bb = bias[gn];
            #pragma unroll
            for (int r = 0; r < 4; ++r){
                const int gm = gmb + r;
                if (gm < Mtot){
                    float v = fmaxf(acc[i][j][r] + bb, 0.f);
                    Cbase[((size_t)blockIdx.z*Cb + coff + gm)*ldc + noff + gn] = (bf16_t)v;
                }
            }
        }
    }
}

// ---------------------------------------------------------------------------
// Merged in-proj GEMM: A=comb (M,512), W=[mf_in; mb_in] (4096,512).
// Column routing: gn -> half = gn>>11, within = gn&2047;
//   within<1024 -> xy[:, half*1024+within]; else z[:, half*1024+within-1024].
// ---------------------------------------------------------------------------
__global__ __launch_bounds__(256) void gemm_in_kernel(
    const bf16_t* __restrict__ A, int lda, int Mtot,
    const bf16_t* __restrict__ W, int K,
    bf16_t* __restrict__ xy, bf16_t* __restrict__ z)
{
    __shared__ bf16_t As[128*32];
    __shared__ bf16_t Ws[128*32];
    const int t = threadIdx.x;
    const int lane = t & 63, w = t >> 6;
    const int m0 = blockIdx.x * 128, n0 = blockIdx.y * 128;
    const int rsub = lane >> 2, csub = lane & 3;
    const int col = lane & 15, quad = lane >> 4;
    const int wOffM = (w & 1) * 64, wOffN = (w >> 1) * 64;

    f32x4 acc[4][4];
    #pragma unroll
    for (int i = 0; i < 4; ++i)
        #pragma unroll
        for (int j = 0; j < 4; ++j)
            acc[i][j] = (f32x4){0.f, 0.f, 0.f, 0.f};

    for (int k0 = 0; k0 < K; k0 += 32){
        __syncthreads();
        #pragma unroll
        for (int q = 0; q < 2; ++q){
            const int rt = w*32 + q*16 + rsub;
            const int lq = csub ^ ((rt >> 1) & 3);
            int ra = m0 + rt; ra = (ra < Mtot) ? ra : (Mtot - 1);
            const bf16_t* ga = A + (size_t)ra*lda + k0 + lq*8;
            __builtin_amdgcn_global_load_lds(
                (const __attribute__((address_space(1))) void*)ga,
                (__attribute__((address_space(3))) void*)&As[(w*32 + q*16)*32], 16, 0, 0);
            const bf16_t* gw = W + (size_t)(n0 + rt)*K + k0 + lq*8;
            __builtin_amdgcn_global_load_lds(
                (const __attribute__((address_space(1))) void*)gw,
                (__attribute__((address_space(3))) void*)&Ws[(w*32 + q*16)*32], 16, 0, 0);
        }
        __syncthreads();

        bf16x8 af[4], bfv[4];
        #pragma unroll
        for (int i = 0; i < 4; ++i){
            const int ra = wOffM + i*16 + col;
            af[i]  = *(const bf16x8*)&As[ra*32 + (quad ^ ((ra >> 1) & 3))*8];
            const int rb = wOffN + i*16 + col;
            bfv[i] = *(const bf16x8*)&Ws[rb*32 + (quad ^ ((rb >> 1) & 3))*8];
        }
        #pragma unroll
        for (int i = 0; i < 4; ++i)
            #pragma unroll
            for (int j = 0; j < 4; ++j)
                acc[i][j] = __builtin_amdgcn_mfma_f32_16x16x32_bf16(af[i], bfv[j], acc[i][j], 0, 0, 0);
    }

    #pragma unroll
    for (int i = 0; i < 4; ++i){
        const int gmb = m0 + wOffM + i*16 + quad*4;
        #pragma unroll
        for (int j = 0; j < 4; ++j){
            const int gn = n0 + wOffN + j*16 + col;
            const int half = gn >> 11, within = gn & 2047;
            const size_t colx = (size_t)(half*1024 + (within & 1023));
            bf16_t* dst = (within < 1024) ? xy : z;
            #pragma unroll
            for (int r = 0; r < 4; ++r){
                const int gm = gmb + r;
                if (gm < Mtot)
                    dst[(size_t)gm*2048 + colx] = (bf16_t)acc[i][j][r];
            }
        }
    }
}

// ---------------------------------------------------------------------------
// Merged out-proj GEMM: A=[y_f|y_b] (M,2048), W=[Wf|Wb] K-concat (512,2048),
// C fp32 (M,512). No accumulate needed.
// ---------------------------------------------------------------------------
__global__ __launch_bounds__(256) void gemm_out_kernel(
    const bf16_t* __restrict__ A, int Mtot,
    const bf16_t* __restrict__ W,
    float* __restrict__ C)
{
    __shared__ bf16_t As[128*32];
    __shared__ bf16_t Ws[128*32];
    const int t = threadIdx.x;
    const int lane = t & 63, w = t >> 6;
    const int m0 = blockIdx.x * 128, n0 = blockIdx.y * 128;
    const int rsub = lane >> 2, csub = lane & 3;
    const int col = lane & 15, quad = lane >> 4;
    const int wOffM = (w & 1) * 64, wOffN = (w >> 1) * 64;
    const int K = 2048;

    f32x4 acc[4][4];
    #pragma unroll
    for (int i = 0; i < 4; ++i)
        #pragma unroll
        for (int j = 0; j < 4; ++j)
            acc[i][j] = (f32x4){0.f, 0.f, 0.f, 0.f};

    for (int k0 = 0; k0 < K; k0 += 32){
        __syncthreads();
        #pragma unroll
        for (int q = 0; q < 2; ++q){
            const int rt = w*32 + q*16 + rsub;
            const int lq = csub ^ ((rt >> 1) & 3);
            int ra = m0 + rt; ra = (ra < Mtot) ? ra : (Mtot - 1);
            const bf16_t* ga = A + (size_t)ra*K + k0 + lq*8;
            __builtin_amdgcn_global_load_lds(
                (const __attribute__((address_space(1))) void*)ga,
                (__attribute__((address_space(3))) void*)&As[(w*32 + q*16)*32], 16, 0, 0);
            const bf16_t* gw = W + (size_t)(n0 + rt)*K + k0 + lq*8;
            __builtin_amdgcn_global_load_lds(
                (const __attribute__((address_space(1))) void*)gw,
                (__attribute__((address_space(3))) void*)&Ws[(w*32 + q*16)*32], 16, 0, 0);
        }
        __syncthreads();

        bf16x8 af[4], bfv[4];
        #pragma unroll
        for (int i = 0; i < 4; ++i){
            const int ra = wOffM + i*16 + col;
            af[i]  = *(const bf16x8*)&As[ra*32 + (quad ^ ((ra >> 1) & 3))*8];
            const int rb = wOffN + i*16 + col;
            bfv[i] = *(const bf16x8*)&Ws[rb*32 + (quad ^ ((rb >> 1) & 3))*8];
        }
        #pragma unroll
        for (int i = 0; i < 4; ++i)
            #pragma unroll
            for (int j = 0; j < 4; ++j)
                acc[i][j] = __builtin_amdgcn_mfma_f32_16x16x32_bf16(af[i], bfv[j], acc[i][j], 0, 0, 0);
    }

    #pragma unroll
    for (int i = 0; i < 4; ++i){
        const int gmb = m0 + wOffM + i*16 + quad*4;
        #pragma unroll
        for (int j = 0; j < 4; ++j){
            const int gn = n0 + wOffN + j*16 + col;
            #pragma unroll
            for (int r = 0; r < 4; ++r){
                const int gm = gmb + r;
                if (gm < Mtot)
                    C[(size_t)gm*512 + gn] = acc[i][j][r];
            }
        }
    }
}

// ---------------------------------------------------------------------------
// Merged x-proj GEMM: blockIdx.y=0 -> fwd (A cols 0-1023, Wf, N=64, C cols 0-63)
//                     blockIdx.y=1 -> bwd (A cols 1024+, Wb, N=48, C cols 64-111)
// A lda=2048, K=1024; C (M,128) fp32; 128x64 tile.
// ---------------------------------------------------------------------------
__global__ __launch_bounds__(256) void gemm_x_kernel(
    const bf16_t* __restrict__ xy,
    const bf16_t* __restrict__ Wf, const bf16_t* __restrict__ Wb,
    float* __restrict__ C)
{
    __shared__ bf16_t As[128*32];
    __shared__ bf16_t Ws[64*32];
    const int half = blockIdx.y;
    const bf16_t* A = xy + half*1024;
    const bf16_t* W = half ? Wb : Wf;
    const int N = half ? 48 : 64;
    const int t = threadIdx.x;
    const int lane = t & 63, w = t >> 6;
    const int m0 = blockIdx.x * 128;
    const int rsub = lane >> 2, csub = lane & 3;
    const int col = lane & 15, quad = lane >> 4;

    f32x4 acc[2][4];
    #pragma unroll
    for (int i = 0; i < 2; ++i)
        #pragma unroll
        for (int j = 0; j < 4; ++j)
            acc[i][j] = (f32x4){0.f, 0.f, 0.f, 0.f};

    for (int k0 = 0; k0 < 1024; k0 += 32){
        __syncthreads();
        #pragma unroll
        for (int q = 0; q < 2; ++q){
            const int rt = q*64 + w*16 + rsub;
            const int lq = csub ^ ((rt >> 1) & 3);
            const bf16_t* ga = A + (size_t)(m0 + rt)*2048 + k0 + lq*8;
            __builtin_amdgcn_global_load_lds(
                (const __attribute__((address_space(1))) void*)ga,
                (__attribute__((address_space(3))) void*)&As[(q*64 + w*16)*32], 16, 0, 0);
        }
        {
            const int rt = w*16 + rsub;
            const int lq = csub ^ ((rt >> 1) & 3);
            int rw = (rt < N) ? rt : (N - 1);
            const bf16_t* gw = W + (size_t)rw*1024 + k0 + lq*8;
            __builtin_amdgcn_global_load_lds(
                (const __attribute__((address_space(1))) void*)gw,
                (__attribute__((address_space(3))) void*)&Ws[(w*16)*32], 16, 0, 0);
        }
        __syncthreads();

        bf16x8 af[2], bfv[4];
        #pragma unroll
        for (int i = 0; i < 2; ++i){
            const int ra = w*32 + i*16 + col;
            af[i]  = *(const bf16x8*)&As[ra*32 + (quad ^ ((ra >> 1) & 3))*8];
        }
        #pragma unroll
        for (int j = 0; j < 4; ++j){
            const int rb = j*16 + col;
            bfv[j] = *(const bf16x8*)&Ws[rb*32 + (quad ^ ((rb >> 1) & 3))*8];
        }
        #pragma unroll
        for (int i = 0; i < 2; ++i)
            #pragma unroll
            for (int j = 0; j < 4; ++j)
                acc[i][j] = __builtin_amdgcn_mfma_f32_16x16x32_bf16(af[i], bfv[j], acc[i][j], 0, 0, 0);
    }

    #pragma unroll
    for (int i = 0; i < 2; ++i){
        const int gmb = m0 + w*32 + i*16 + quad*4;
        #pragma unroll
        for (int j = 0; j < 4; ++j){
            const int gn = j*16 + col;
            if (gn < N){
                #pragma unroll
                for (int r = 0; r < 4; ++r)
                    C[(size_t)(gmb + r)*128 + half*64 + gn] = acc[i][j][r];
            }
        }
    }
}

// ---------------------------------------------------------------------------
// Merged dt projection: grid (M/16, 16); blockIdx.y<8 -> fwd, else bwd.
// dtb (M, 2048): cols [0,1024)=fwd, [1024,2048)=bwd.
// ---------------------------------------------------------------------------
__global__ __launch_bounds__(256) void dt_kernel(
    const float* __restrict__ xdb,   // (M, 128): fwd dtin cols 0-31, bwd cols 64-95
    const float* __restrict__ dtwf, const float* __restrict__ dtbf,
    const float* __restrict__ dtwb, const float* __restrict__ dtbb,
    bf16_t* __restrict__ dtb)        // (M, 2048)
{
    const int half = blockIdx.y >> 3;
    const int d = (blockIdx.y & 7)*128 + (threadIdx.x & 127);
    const int mslot = threadIdx.x >> 7;
    const int m0 = blockIdx.x * 16;
    __shared__ float sd[16*32];
    for (int i = threadIdx.x; i < 16*32; i += 256){
        int r = i >> 5, c = i & 31;
        sd[i] = xdb[(size_t)(m0 + r)*128 + half*64 + c];
    }
    const float* dw = half ? dtwb : dtwf;
    float w[32];
    #pragma unroll
    for (int r = 0; r < 32; ++r) w[r] = dw[d*32 + r];
    const float db = half ? dtbb[d] : dtbf[d];
    __syncthreads();
    #pragma unroll
    for (int i = 0; i < 8; ++i){
        const int row = mslot + i*2;
        const float* rp = &sd[row*32];
        float a = db;
        #pragma unroll
        for (int r = 0; r < 32; ++r) a += w[r]*rp[r];
        dtb[(size_t)(m0 + row)*2048 + half*1024 + d] = (bf16_t)softplusf_(a);
    }
}

// ---------------------------------------------------------------------------
// Merged depthwise conv + bias + silu, IN PLACE on xy (M,2048):
// cols 0-1023 fwd (k=4, causal), cols 1024-2047 bwd (k=2, anti-causal).
// ---------------------------------------------------------------------------
template<int DC, bool REV>
__device__ __forceinline__ void conv_dev(bf16_t* base, const float* wsrc, float bias)
{
    float w[DC];
    #pragma unroll
    for (int k = 0; k < DC; ++k) w[k] = wsrc[k];
    float hist[DC-1];
    #pragma unroll
    for (int k = 0; k < DC-1; ++k) hist[k] = 0.f;
    const int step = REV ? -1 : 1;
    int l = REV ? (SEQ-1) : 0;
    for (int t0 = 0; t0 < SEQ; t0 += 10){
        float v[10];
        #pragma unroll
        for (int i = 0; i < 10; ++i) v[i] = (float)base[(size_t)(l + step*i)*2048];
        float o[10];
        #pragma unroll
        for (int i = 0; i < 10; ++i){
            float a = bias + w[DC-1]*v[i];
            #pragma unroll
            for (int j = 1; j < DC; ++j) a += w[DC-1-j]*hist[j-1];
            #pragma unroll
            for (int j = DC-2; j >= 1; --j) hist[j] = hist[j-1];
            hist[0] = v[i];
            o[i] = siluf_(a);
        }
        #pragma unroll
        for (int i = 0; i < 10; ++i)
            base[(size_t)(l + step*i)*2048] = (bf16_t)o[i];
        l += step*10;
    }
}

__global__ __launch_bounds__(256) void conv_silu_kernel(
    bf16_t* __restrict__ xy,
    const float* __restrict__ cwf, const float* __restrict__ cbf,
    const float* __restrict__ cwb, const float* __restrict__ cbb)
{
    const int gid = blockIdx.x*256 + threadIdx.x;   // Bc*2048 threads
    const int b = gid >> 11, d2 = gid & 2047;
    const int half = d2 >> 10, d = d2 & 1023;
    bf16_t* base = xy + (size_t)b*SEQ*2048 + d2;
    if (half == 0) conv_dev<4, false>(base, cwf + d*4, cbf[d]);
    else           conv_dev<2, true >(base, cwb + d*2, cbb[d]);
}

// ---------------------------------------------------------------------------
// Merged selective scan: grid Bc*8; sub<4 -> fwd (DS=16), else bwd (DS=8).
// x read from xy and y written back in place; z, dt bf16; B/C slab in LDS.
// Structured-A fast path (A[d][s]=(s+1)*A[d][0]) with general fallback.
// ---------------------------------------------------------------------------
template<int DS, bool REV>
__device__ __forceinline__ void scan_dev(
    bf16_t* __restrict__ xybase, const bf16_t* __restrict__ zbase,
    const bf16_t* __restrict__ tbase, const float* __restrict__ sx,
    const float* __restrict__ Arow, float Dd)
{
    float Av[DS], h[DS];
    #pragma unroll
    for (int s = 0; s < DS; ++s){ Av[s] = -__expf(Arow[s]); h[s] = 0.f; }
    bool structured = true;
    #pragma unroll
    for (int s = 1; s < DS; ++s)
        structured = structured && (fabsf(Av[s] - (float)(s+1)*Av[0]) <= 1e-4f*(float)(s+1));
    const float A0 = Av[0];
    const int step = REV ? -1 : 1;

    if (structured){
        int l = REV ? (SEQ-1) : 0;
        for (int t0 = 0; t0 < SEQ; t0 += 10){
            float xr[10], zr[10], tr[10];
            #pragma unroll
            for (int i = 0; i < 10; ++i){
                const size_t li = (size_t)(l + step*i);
                xr[i] = (float)xybase[li*2048];
                zr[i] = (float)zbase[li*2048];
                tr[i] = (float)tbase[li*2048];
            }
            #pragma unroll
            for (int i = 0; i < 10; ++i){
                const int li = l + step*i;
                const float4* sxl4 = (const float4*)&sx[li*2*DS];
                const float dtv = tr[i];
                const float dtx = dtv * xr[i];
                const float r = __expf(dtv*A0);
                float rp = r;
                float yv = 0.f;
                #pragma unroll
                for (int s4 = 0; s4 < DS/4; ++s4){
                    float4 Bv = sxl4[s4];
                    float4 Cv = sxl4[DS/4 + s4];
                    h[s4*4+0] = rp*h[s4*4+0] + dtx*Bv.x; yv += h[s4*4+0]*Cv.x; rp *= r;
                    h[s4*4+1] = rp*h[s4*4+1] + dtx*Bv.y; yv += h[s4*4+1]*Cv.y; rp *= r;
                    h[s4*4+2] = rp*h[s4*4+2] + dtx*Bv.z; yv += h[s4*4+2]*Cv.z; rp *= r;
                    h[s4*4+3] = rp*h[s4*4+3] + dtx*Bv.w; yv += h[s4*4+3]*Cv.w; rp *= r;
                }
                yv += xr[i]*Dd;
                yv *= siluf_(zr[i]);
                xybase[(size_t)li*2048] = (bf16_t)yv;
            }
            l += step*10;
        }
    } else {
        int l = REV ? (SEQ-1) : 0;
        for (int t0 = 0; t0 < SEQ; t0 += 10){
            float xr[10], zr[10], tr[10];
            #pragma unroll
            for (int i = 0; i < 10; ++i){
                const size_t li = (size_t)(l + step*i);
                xr[i] = (float)xybase[li*2048];
                zr[i] = (float)zbase[li*2048];
                tr[i] = (float)tbase[li*2048];
            }
            #pragma unroll
            for (int i = 0; i < 10; ++i){
                const int li = l + step*i;
                const float4* sxl4 = (const float4*)&sx[li*2*DS];
                const float dtv = tr[i];
                const float dtx = dtv * xr[i];
                float yv = 0.f;
                #pragma unroll
                for (int s4 = 0; s4 < DS/4; ++s4){
                    float4 Bv = sxl4[s4];
                    float4 Cv = sxl4[DS/4 + s4];
                    h[s4*4+0] = __expf(dtv*Av[s4*4+0])*h[s4*4+0] + dtx*Bv.x; yv += h[s4*4+0]*Cv.x;
                    h[s4*4+1] = __expf(dtv*Av[s4*4+1])*h[s4*4+1] + dtx*Bv.y; yv += h[s4*4+1]*Cv.y;
                    h[s4*4+2] = __expf(dtv*Av[s4*4+2])*h[s4*4+2] + dtx*Bv.z; yv += h[s4*4+2]*Cv.z;
                    h[s4*4+3] = __expf(dtv*Av[s4*4+3])*h[s4*4+3] + dtx*Bv.w; yv += h[s4*4+3]*Cv.w;
                }
                yv += xr[i]*Dd;
                yv *= siluf_(zr[i]);
                xybase[(size_t)li*2048] = (bf16_t)yv;
            }
            l += step*10;
        }
    }
}

__global__ __launch_bounds__(256) void scan_kernel(
    bf16_t* __restrict__ xy, const bf16_t* __restrict__ z,
    const bf16_t* __restrict__ dtb, const float* __restrict__ xdb, // (M,128)
    const float* __restrict__ Alogf, const float* __restrict__ Dpf,
    const float* __restrict__ Alogb, const float* __restrict__ Dpb)
{
    const int b = blockIdx.x >> 3, s8 = blockIdx.x & 7;
    __shared__ float sx[SEQ*32];    // fwd: 32 floats/row (B16+C16); bwd: 16/row
    const float4* src = (const float4*)(xdb + (size_t)b*SEQ*128);
    float4* dst = (float4*)sx;

    if (s8 < 4){
        for (int i = threadIdx.x; i < SEQ*8; i += 256){
            int row = i >> 3, c = i & 7;
            dst[row*8 + c] = src[row*32 + 8 + c];     // fwd B/C: floats 32..63
        }
        const int d = (s8 << 8) + threadIdx.x;        // 0..1023
        __syncthreads();
        scan_dev<16, false>(
            xy  + (size_t)b*SEQ*2048 + d,
            z   + (size_t)b*SEQ*2048 + d,
            dtb + (size_t)b*SEQ*2048 + d,
            sx, Alogf + d*16, Dpf[d]);
    } else {
        for (int i = threadIdx.x; i < SEQ*4; i += 256){
            int row = i >> 2, c = i & 3;
            dst[row*4 + c] = src[row*32 + 24 + c];    // bwd B/C: floats 96..111
        }
        const int d = ((s8 - 4) << 8) + threadIdx.x;
        __syncthreads();
        scan_dev<8, true>(
            xy  + (size_t)b*SEQ*2048 + 1024 + d,
            z   + (size_t)b*SEQ*2048 + 1024 + d,
            dtb + (size_t)b*SEQ*2048 + 1024 + d,
            sx, Alogb + d*8, Dpb[d]);
    }
}

// ---------------------------------------------------------------------------
// Head: max-pool over L, LN(512), fc1(512->128)+relu, fc2(128->4)
// ---------------------------------------------------------------------------
__global__ __launch_bounds__(256) void head_kernel(
    const float* __restrict__ acc,   // (Bc, L, 512)
    const float* __restrict__ ng, const float* __restrict__ nb,
    const float* __restrict__ w1, const float* __restrict__ b1,
    const float* __restrict__ w2, const float* __restrict__ b2,
    float* __restrict__ out)         // (Bc, 4) chunk base
{
    const int b = blockIdx.x, t = threadIdx.x;
    __shared__ float4 sm4[256];
    __shared__ float sp[512];
    __shared__ float sh2[256];
    __shared__ float sh[128];
    __shared__ float red1[4], red2[4];
    const float* base = acc + (size_t)b*SEQ*512;

    {
        const int c4 = t & 127, lh = t >> 7;
        float4 m = make_float4(-3.4e38f, -3.4e38f, -3.4e38f, -3.4e38f);
        for (int l = lh*50; l < lh*50 + 50; ++l){
            float4 v = ((const float4*)(base + (size_t)l*512))[c4];
            m.x = fmaxf(m.x, v.x); m.y = fmaxf(m.y, v.y);
            m.z = fmaxf(m.z, v.z); m.w = fmaxf(m.w, v.w);
        }
        sm4[t] = m;
    }
    __syncthreads();
    if (t < 128){
        float4 a = sm4[t], c = sm4[t + 128];
        ((float4*)sp)[t] = make_float4(fmaxf(a.x,c.x), fmaxf(a.y,c.y),
                                       fmaxf(a.z,c.z), fmaxf(a.w,c.w));
    }
    __syncthreads();

    float s1 = 0.f, s2 = 0.f;
    for (int o = t; o < 512; o += 256){ float v = sp[o]; s1 += v; s2 += v*v; }
    #pragma unroll
    for (int off = 32; off > 0; off >>= 1){ s1 += __shfl_xor(s1, off); s2 += __shfl_xor(s2, off); }
    const int wv = t >> 6, lane = t & 63;
    if (lane == 0){ red1[wv] = s1; red2[wv] = s2; }
    __syncthreads();
    if (t == 0){
        float a = 0.f, c = 0.f;
        for (int i = 0; i < 4; ++i){ a += red1[i]; c += red2[i]; }
        float mean = a * (1.f/512.f);
        float var = c * (1.f/512.f) - mean*mean;
        red1[0] = mean; red2[0] = rsqrtf(var + 1e-5f);
    }
    __syncthreads();
    const float mean = red1[0], rstd = red2[0];
    for (int o = t; o < 512; o += 256) sp[o] = (sp[o]-mean)*rstd*ng[o] + nb[o];
    __syncthreads();

    {
        const int o = t & 127, half = t >> 7;
        const float4* wrow = (const float4*)(w1 + (size_t)o*512 + half*256);
        const float4* sp4 = (const float4*)sp + half*64;
        float s = 0.f;
        #pragma unroll 8
        for (int j = 0; j < 64; ++j){
            float4 a = sp4[j], wq = wrow[j];
            s += a.x*wq.x + a.y*wq.y + a.z*wq.z + a.w*wq.w;
        }
        sh2[t] = s;
    }
    __syncthreads();
    if (t < 128) sh[t] = fmaxf(sh2[t] + sh2[t + 128] + b1[t], 0.f);
    __syncthreads();
    if (t < 4){
        float a = b2[t];
        for (int j = 0; j < 128; ++j) a += sh[j]*w2[t*128 + j];
        out[b*4 + t] = a;
    }
}

// ---------------------------------------------------------------------------
extern "C" void kernel_launch(void* const* d_in, const int* in_sizes, int n_in,
                              void* d_out, int out_size, void* d_ws, size_t ws_size,
                              hipStream_t stream)
{
    (void)in_sizes; (void)n_in; (void)out_size;
    const float* x        = (const float*)d_in[0];
    const float* fe_w     = (const float*)d_in[1];
    const float* fe_b     = (const float*)d_in[2];
    const float* fe_ln_g  = (const float*)d_in[3];
    const float* fe_ln_b  = (const float*)d_in[4];
    const float* emb_ln_g = (const float*)d_in[5];
    const float* emb_ln_b = (const float*)d_in[6];
    const float* conv1_w  = (const float*)d_in[7];
    const float* conv1_b  = (const float*)d_in[8];
    const float* conv2_w  = (const float*)d_in[9];
    const float* conv2_b  = (const float*)d_in[10];
    const float* mf_in_w  = (const float*)d_in[11];
    const float* mf_conv_w= (const float*)d_in[12];
    const float* mf_conv_b= (const float*)d_in[13];
    const float* mf_xproj = (const float*)d_in[14];
    const float* mf_dt_w  = (const float*)d_in[15];
    const float* mf_dt_b  = (const float*)d_in[16];
    const float* mf_Alog  = (const float*)d_in[17];
    const float* mf_D     = (const float*)d_in[18];
    const float* mf_out_w = (const float*)d_in[19];
    const float* mb_in_w  = (const float*)d_in[20];
    const float* mb_conv_w= (const float*)d_in[21];
    const float* mb_conv_b= (const float*)d_in[22];
    const float* mb_xproj = (const float*)d_in[23];
    const float* mb_dt_w  = (const float*)d_in[24];
    const float* mb_dt_b  = (const float*)d_in[25];
    const float* mb_Alog  = (const float*)d_in[26];
    const float* mb_D     = (const float*)d_in[27];
    const float* mb_out_w = (const float*)d_in[28];
    const float* norm_g   = (const float*)d_in[29];
    const float* norm_b   = (const float*)d_in[30];
    const float* fc1_w    = (const float*)d_in[31];
    const float* fc1_b    = (const float*)d_in[32];
    const float* fc2_w    = (const float*)d_in[33];
    const float* fc2_b    = (const float*)d_in[34];
    float* out = (float*)d_out;

    // ---- fixed workspace region ----
    char* p = (char*)d_ws;
    bf16_t* w_in   = (bf16_t*)p; p += (size_t)4096*512*sizeof(bf16_t);   // [mf; mb]
    bf16_t* w_out  = (bf16_t*)p; p += (size_t)512*2048*sizeof(bf16_t);   // K-concat
    bf16_t* w_xpf  = (bf16_t*)p; p += (size_t)64*1024*sizeof(bf16_t);
    bf16_t* w_xpb  = (bf16_t*)p; p += (size_t)48*1024*sizeof(bf16_t);
    bf16_t* W1p    = (bf16_t*)p; p += (size_t)128*96*sizeof(bf16_t);
    bf16_t* W2p    = (bf16_t*)p; p += (size_t)256*384*sizeof(bf16_t);
    bf16_t* comb_all = (bf16_t*)p; p += (size_t)BSZ*SEQ*512*sizeof(bf16_t);
    const size_t fixed_bytes = (size_t)(p - (char*)d_ws);

    // ---- chunk region ----
    // per-batch: xy (100*2048*2) + z (100*2048*2) + dtb (100*2048*2) + xdb (100*128*4)
    //          = 1,280,000 B. accb (100*512*4 = 204.8K) aliases dtb (dead after scan).
    const size_t per_b = (size_t)SEQ * (2048*2 + 2048*2 + 2048*2 + 128*4);
    const size_t budget = (ws_size > fixed_bytes) ? (ws_size - fixed_bytes) : 0;
    int Bc = BSZ;
    while (Bc > 64 && (size_t)Bc * per_b > budget) Bc >>= 1;   // Bc in {512,256,128,64}
    const int nch = BSZ / Bc;
    const int M = Bc * SEQ;

    bf16_t* F0pad = (bf16_t*)p;   // aliases chunk region (pre-loop only)
    bf16_t* F1pad = F0pad + (size_t)BSZ*102*32;
    bf16_t* xy   = (bf16_t*)p;               p += (size_t)M*2048*sizeof(bf16_t);
    bf16_t* z    = (bf16_t*)p;               p += (size_t)M*2048*sizeof(bf16_t);
    bf16_t* dtb  = (bf16_t*)p;               p += (size_t)M*2048*sizeof(bf16_t);
    float*  xdb  = (float*)p;
    float*  accb = (float*)dtb;              // alias: dtb dead when out-proj writes

    // ---- weight conversions / rearrange ----
    cvt_bf16_kernel<<<(2048*512+255)/256, 256, 0, stream>>>(mf_in_w, w_in, 2048*512);
    cvt_bf16_kernel<<<(2048*512+255)/256, 256, 0, stream>>>(mb_in_w, w_in + (size_t)2048*512, 2048*512);
    prep_outw_kernel<<<(512*2048+255)/256, 256, 0, stream>>>(mf_out_w, mb_out_w, w_out);
    cvt_bf16_kernel<<<(64*1024+255)/256,  256, 0, stream>>>(mf_xproj, w_xpf, 64*1024);
    cvt_bf16_kernel<<<(48*1024+255)/256,  256, 0, stream>>>(mb_xproj, w_xpb, 48*1024);
    prep_convw_kernel<<<(256*384+255)/256, 256, 0, stream>>>(conv1_w, conv2_w, W1p, W2p);

    // ---- front-end ----
    fe0_kernel<<<BSZ, 256, 0, stream>>>(x, fe_w, fe_b, fe_ln_g, fe_ln_b,
        emb_ln_g, emb_ln_b, comb_all, F0pad, F1pad);
    gemm_conv_kernel<<<dim3(1, 1, BSZ), 256, 0, stream>>>(
        F0pad, 32, 102*32, W1p, 96, 128, conv1_b, F1pad, 128, 102, 1, 0, SEQ);
    gemm_conv_kernel<<<dim3(1, 2, BSZ), 256, 0, stream>>>(
        F1pad, 128, 102*128, W2p, 384, 256, conv2_b, comb_all, 512, 100, 0, 256, SEQ);

    const int gm128 = M / 128;

    for (int c = 0; c < nch; ++c){
        const size_t b0 = (size_t)c * Bc;
        const bf16_t* comb = comb_all + b0*SEQ*512;

        gemm_in_kernel<<<dim3(gm128, 32), 256, 0, stream>>>(comb, 512, M, w_in, 512, xy, z);
        conv_silu_kernel<<<Bc*2048/256, 256, 0, stream>>>(xy, mf_conv_w, mf_conv_b,
                                                          mb_conv_w, mb_conv_b);
        gemm_x_kernel<<<dim3(gm128, 2), 256, 0, stream>>>(xy, w_xpf, w_xpb, xdb);
        dt_kernel<<<dim3(M/16, 16), 256, 0, stream>>>(xdb, mf_dt_w, mf_dt_b,
                                                      mb_dt_w, mb_dt_b, dtb);
        scan_kernel<<<Bc*8, 256, 0, stream>>>(xy, z, dtb, xdb,
                                              mf_Alog, mf_D, mb_Alog, mb_D);
        gemm_out_kernel<<<dim3(gm128, 4), 256, 0, stream>>>(xy, M, w_out, accb);
        head_kernel<<<Bc, 256, 0, stream>>>(accb, norm_g, norm_b, fc1_w, fc1_b,
                                            fc2_w, fc2_b, out + b0*4);
    }
}